// Round 21
// baseline (261.246 us; speedup 1.0000x reference)
//
#include <hip/hip_runtime.h>
#include <hip/hip_bf16.h>
#include <math.h>

// Qwen3Next GatedDeltaNet — round 20: (1) out-GEMM moved to gemm256 with
// z-split (Klen=512 x 8 partials, bf16) + add8; (2) prep2 split into preba
// (cast X + ba_gemm) and wtrans (W_qkvz transpose) for per-section profiling.

#define T_LEN 1024
#define HK_N 16
#define HV_N 32
#define NQKVZ 12288
#define CHUNK 64
#define NCHUNK 16

typedef __bf16 bf16x8 __attribute__((ext_vector_type(8)));
typedef float f32x4 __attribute__((ext_vector_type(4)));

__device__ __forceinline__ ushort4 pack4(const f32x4 v) {
  ushort4 o;
  o.x = __bfloat16_as_ushort(__float2bfloat16(v[0]));
  o.y = __bfloat16_as_ushort(__float2bfloat16(v[1]));
  o.z = __bfloat16_as_ushort(__float2bfloat16(v[2]));
  o.w = __bfloat16_as_ushort(__float2bfloat16(v[3]));
  return o;
}

// ---- 256x256 big-tile bf16 GEMM (z-partials): C[z] = A @ B^T over K-slice ---
// 512 thr = 8 waves (2M x 4N). BK=64. Double-buffered, 2-K-tile prefetch
// depth with counted vmcnt(8); reads register-resident before restage.
__global__ __launch_bounds__(512) void gemm256(const __hip_bfloat16* __restrict__ A,
                                               const __hip_bfloat16* __restrict__ B,
                                               __hip_bfloat16* __restrict__ C,
                                               int M, int N, int Klen, int ldk) {
  __shared__ __align__(16) __hip_bfloat16 As[2][256 * 64];
  __shared__ __align__(16) __hip_bfloat16 Bs[2][256 * 64];
  const int tid = threadIdx.x;
  const int wid = tid >> 6, lane = tid & 63;
  const int wr = wid >> 2, wc = wid & 3;
  const int m0 = blockIdx.y * 256, n0 = blockIdx.x * 256;
  const size_t kbase = (size_t)blockIdx.z * Klen;
  __hip_bfloat16* Cz = C + (size_t)blockIdx.z * M * N;
  const int lrow = lane & 15, lk = lane >> 4;
  const int rswz = (lrow & 7) * 8;
  f32x4 acc[8][4] = {};
  const int nk = Klen >> 6;

#define GST(b_, kt_) do {                                                       \
    _Pragma("unroll") for (int it = 0; it < 4; ++it) {                          \
      const int c_ = it * 512 + tid;                                            \
      const int row_ = c_ >> 3;                                                 \
      const int col8_ = ((c_ & 7) ^ (row_ & 7)) * 8;                            \
      __builtin_amdgcn_global_load_lds(                                         \
          (const __attribute__((address_space(1))) void*)                       \
              (A + (size_t)(m0 + row_) * ldk + kbase + ((kt_) << 6) + col8_),   \
          (__attribute__((address_space(3))) void*)(&As[b_][c_ * 8]), 16, 0, 0);\
    }                                                                           \
    _Pragma("unroll") for (int it = 0; it < 4; ++it) {                          \
      const int c_ = it * 512 + tid;                                            \
      const int row_ = c_ >> 3;                                                 \
      const int col8_ = ((c_ & 7) ^ (row_ & 7)) * 8;                            \
      __builtin_amdgcn_global_load_lds(                                         \
          (const __attribute__((address_space(1))) void*)                       \
              (B + (size_t)(n0 + row_) * ldk + kbase + ((kt_) << 6) + col8_),   \
          (__attribute__((address_space(3))) void*)(&Bs[b_][c_ * 8]), 16, 0, 0);\
    }                                                                           \
  } while (0)

  GST(0, 0);
  GST(1, 1);
  int cur = 0;
  for (int t = 0; t < nk; ++t) {
    if (t < nk - 1) asm volatile("s_waitcnt vmcnt(8)" ::: "memory");
    else            asm volatile("s_waitcnt vmcnt(0)" ::: "memory");
    __builtin_amdgcn_s_barrier();
    __builtin_amdgcn_sched_barrier(0);
    bf16x8 af[8], bfv[4];
#pragma unroll
    for (int m = 0; m < 8; ++m)
      af[m] = *reinterpret_cast<const bf16x8*>(
          &As[cur][(wr * 128 + m * 16 + lrow) * 64 + ((lk * 8) ^ rswz)]);
#pragma unroll
    for (int n = 0; n < 4; ++n)
      bfv[n] = *reinterpret_cast<const bf16x8*>(
          &Bs[cur][(wc * 64 + n * 16 + lrow) * 64 + ((lk * 8) ^ rswz)]);
    __builtin_amdgcn_s_setprio(1);
#pragma unroll
    for (int m = 0; m < 8; ++m)
#pragma unroll
      for (int n = 0; n < 4; ++n)
        acc[m][n] = __builtin_amdgcn_mfma_f32_16x16x32_bf16(af[m], bfv[n], acc[m][n], 0, 0, 0);
    __builtin_amdgcn_s_setprio(0);
#pragma unroll
    for (int m = 0; m < 8; ++m)
      af[m] = *reinterpret_cast<const bf16x8*>(
          &As[cur][(wr * 128 + m * 16 + lrow) * 64 + ((32 + lk * 8) ^ rswz)]);
#pragma unroll
    for (int n = 0; n < 4; ++n)
      bfv[n] = *reinterpret_cast<const bf16x8*>(
          &Bs[cur][(wc * 64 + n * 16 + lrow) * 64 + ((32 + lk * 8) ^ rswz)]);
    asm volatile("s_waitcnt lgkmcnt(0)" ::: "memory");
    __builtin_amdgcn_sched_barrier(0);
    __builtin_amdgcn_s_barrier();
    __builtin_amdgcn_sched_barrier(0);
    if (t + 2 < nk) GST(cur, t + 2);
    __builtin_amdgcn_s_setprio(1);
#pragma unroll
    for (int m = 0; m < 8; ++m)
#pragma unroll
      for (int n = 0; n < 4; ++n)
        acc[m][n] = __builtin_amdgcn_mfma_f32_16x16x32_bf16(af[m], bfv[n], acc[m][n], 0, 0, 0);
    __builtin_amdgcn_s_setprio(0);
    cur ^= 1;
  }
#undef GST
#pragma unroll
  for (int m = 0; m < 8; ++m)
#pragma unroll
    for (int n = 0; n < 4; ++n)
#pragma unroll
      for (int r = 0; r < 4; ++r)
        Cz[(size_t)(m0 + wr * 128 + m * 16 + lk * 4 + r) * N + n0 + wc * 64 + n * 16 + lrow] =
            __float2bfloat16(acc[m][n][r]);
}

// -------- out = sum of 8 bf16 K-slice partials (fp32 accumulate) -------------
__global__ void add8(const __hip_bfloat16* __restrict__ P, float* __restrict__ out, int n) {
  const int i = (blockIdx.x * 256 + threadIdx.x) * 4;
  if (i < n) {
    float s[4] = {0.f, 0.f, 0.f, 0.f};
#pragma unroll
    for (int z = 0; z < 8; ++z) {
      const ushort4 v = *reinterpret_cast<const ushort4*>(P + (size_t)z * n + i);
      s[0] += __bfloat162float(__ushort_as_bfloat16(v.x));
      s[1] += __bfloat162float(__ushort_as_bfloat16(v.y));
      s[2] += __bfloat162float(__ushort_as_bfloat16(v.z));
      s[3] += __bfloat162float(__ushort_as_bfloat16(v.w));
    }
    *reinterpret_cast<float4*>(out + i) = make_float4(s[0], s[1], s[2], s[3]);
  }
}

// --- preba: cast X -> bf16 (blocks 0..2047) + split-K ba GEMM (2048..2303) ---
__global__ __launch_bounds__(256) void preba(const float* __restrict__ X,
                                             __hip_bfloat16* __restrict__ Xb,
                                             const float* __restrict__ Wba,
                                             float* __restrict__ P) {
  __shared__ __align__(16) float Xs[16][512];
  const int bid = blockIdx.x;
  const int tid = threadIdx.x;
  if (bid < 2048) {
    const int i = (bid * 256 + tid) * 4;
    const float4 v = *reinterpret_cast<const float4*>(X + i);
    ushort4 o;
    o.x = __bfloat16_as_ushort(__float2bfloat16(v.x));
    o.y = __bfloat16_as_ushort(__float2bfloat16(v.y));
    o.z = __bfloat16_as_ushort(__float2bfloat16(v.z));
    o.w = __bfloat16_as_ushort(__float2bfloat16(v.w));
    *reinterpret_cast<ushort4*>((void*)(Xb + i)) = o;
  } else {
    const int b = bid - 2048;
    const int tt = b & 63, ks = b >> 6;
    const int c = tid & 63, r4 = tid >> 6;
    const float* xsrc = X + (size_t)(tt * 16) * 2048 + ks * 512;
#pragma unroll
    for (int u = 0; u < 8; ++u) {
      const int flat = (u * 256 + tid) * 4;
      const int r = flat >> 9, k = flat & 511;
      *reinterpret_cast<float4*>(&Xs[r][k]) =
          *reinterpret_cast<const float4*>(&xsrc[(size_t)r * 2048 + k]);
    }
    __syncthreads();
    float acc[4] = {};
    const float* wp = Wba + (size_t)(ks * 512) * 64 + c;
    for (int k = 0; k < 512; k += 8) {
      float w[8];
#pragma unroll
      for (int u = 0; u < 8; ++u) w[u] = wp[(size_t)(k + u) * 64];
#pragma unroll
      for (int u = 0; u < 8; ++u)
#pragma unroll
        for (int i = 0; i < 4; ++i)
          acc[i] = fmaf(Xs[r4 * 4 + i][k + u], w[u], acc[i]);
    }
    float* pp = P + ((size_t)ks * 1024 + tt * 16 + r4 * 4) * 64 + c;
#pragma unroll
    for (int i = 0; i < 4; ++i) pp[(size_t)i * 64] = acc[i];
  }
}

// --- wtrans: W_qkvz [2048, 12288] fp32 -> bf16 [12288, 2048], 64x64 tiles ----
__global__ __launch_bounds__(256) void wtrans(const float* __restrict__ Wq,
                                              __hip_bfloat16* __restrict__ Wqt) {
  __shared__ float tl[64][65];
  const int b = blockIdx.x;
  const int n0 = (b % 192) * 64, k0 = (b / 192) * 64;
  const int N = NQKVZ, K = 2048;
  const int tid = threadIdx.x;
  const int rc = tid & 15, rr = tid >> 4;
#pragma unroll
  for (int i = 0; i < 4; ++i) {
    const int k = rr + 16 * i;
    const float4 v = *reinterpret_cast<const float4*>(&Wq[(size_t)(k0 + k) * N + n0 + rc * 4]);
    tl[k][rc * 4 + 0] = v.x;
    tl[k][rc * 4 + 1] = v.y;
    tl[k][rc * 4 + 2] = v.z;
    tl[k][rc * 4 + 3] = v.w;
  }
  __syncthreads();
  const int wcx = tid & 7, wry = tid >> 3;
#pragma unroll
  for (int i = 0; i < 2; ++i) {
    const int n = wry + 32 * i;
    uint u[8];
#pragma unroll
    for (int j = 0; j < 8; ++j)
      u[j] = __bfloat16_as_ushort(__float2bfloat16(tl[wcx * 8 + j][n]));
    uint4 o;
    o.x = u[0] | (u[1] << 16);
    o.y = u[2] | (u[3] << 16);
    o.z = u[4] | (u[5] << 16);
    o.w = u[6] | (u[7] << 16);
    *reinterpret_cast<uint4*>((void*)&Wqt[(size_t)(n0 + n) * K + k0 + wcx * 8]) = o;
  }
}

// --- convs: conv_qk_norm (0..4095) + conv_v (4096..4607) + gb (4608..4735) ---
__global__ __launch_bounds__(256) void convs(const __hip_bfloat16* __restrict__ qkvz,
                                             const float* __restrict__ conv_w,
                                             float* __restrict__ QK,
                                             float* __restrict__ V,
                                             const float* __restrict__ P,
                                             const float* __restrict__ dt_bias,
                                             const float* __restrict__ A_log,
                                             float* __restrict__ gg,
                                             float* __restrict__ bet) {
  const int bid = blockIdx.x;
  const int tid = threadIdx.x;
  if (bid < 4096) {
    const int kh = bid & 15;
    const int t = (bid >> 4) * 4 + (tid >> 6);
    const int l = tid & 63;
    const int cols[4] = {kh * 768 + l, kh * 768 + l + 64,
                         kh * 768 + 128 + l, kh * 768 + 128 + l + 64};
    const int chs[4] = {kh * 128 + l, kh * 128 + l + 64,
                        2048 + kh * 128 + l, 2048 + kh * 128 + l + 64};
    float y[4];
#pragma unroll
    for (int j = 0; j < 4; ++j) {
      const float* wp = &conv_w[chs[j] * 4];
      float acc = 0.f;
#pragma unroll
      for (int s = 0; s < 4; ++s) {
        const int tt = t - 3 + s;
        if (tt >= 0)
          acc = fmaf(__bfloat162float(qkvz[(size_t)tt * NQKVZ + cols[j]]), wp[s], acc);
      }
      y[j] = acc / (1.f + expf(-acc));  // silu
    }
    float sq = y[0] * y[0] + y[1] * y[1];
    float sk = y[2] * y[2] + y[3] * y[3];
#pragma unroll
    for (int off = 32; off; off >>= 1) {
      sq += __shfl_xor(sq, off);
      sk += __shfl_xor(sk, off);
    }
    const float rq = rsqrtf(sq + 1e-6f) * 0.08838834764831845f;  // * DK^-0.5
    const float rk = rsqrtf(sk + 1e-6f);
    const size_t qb = (size_t)t * 4096 + kh * 128;
    QK[qb + l] = y[0] * rq;
    QK[qb + l + 64] = y[1] * rq;
    QK[qb + 2048 + l] = y[2] * rk;
    QK[qb + 2048 + l + 64] = y[3] * rk;
  } else if (bid < 4608) {
    const int b = bid - 4096;
    const int c2 = (b & 15) * 256 + tid;
    const int vh = c2 >> 7;
    const int col = (vh >> 1) * 768 + 256 + (vh & 1) * 128 + (c2 & 127);
    const int t0 = (b >> 4) * 32;
    const float4 w = *reinterpret_cast<const float4*>(&conv_w[(4096 + c2) * 4]);
    float x0, x1, x2;
    if (t0 == 0) {
      x0 = 0.f; x1 = 0.f; x2 = 0.f;
    } else {
      x0 = __bfloat162float(qkvz[(size_t)(t0 - 3) * NQKVZ + col]);
      x1 = __bfloat162float(qkvz[(size_t)(t0 - 2) * NQKVZ + col]);
      x2 = __bfloat162float(qkvz[(size_t)(t0 - 1) * NQKVZ + col]);
    }
#pragma unroll 4
    for (int tt = 0; tt < 32; ++tt) {
      const int t = t0 + tt;
      const float x3 = __bfloat162float(qkvz[(size_t)t * NQKVZ + col]);
      float acc = x0 * w.x;
      acc = fmaf(x1, w.y, acc);
      acc = fmaf(x2, w.z, acc);
      acc = fmaf(x3, w.w, acc);
      V[(size_t)t * 4096 + c2] = acc / (1.f + expf(-acc));
      x0 = x1; x1 = x2; x2 = x3;
    }
  } else {
    const int idx = (bid - 4608) * 256 + tid;  // t*32 + vh
    const int t = idx >> 5, vh = idx & 31;
    const int cb = (vh >> 1) * 4 + (vh & 1);
    float b = 0.f, a = 0.f;
#pragma unroll
    for (int s = 0; s < 4; ++s) {
      b += P[((size_t)s * 1024 + t) * 64 + cb];
      a += P[((size_t)s * 1024 + t) * 64 + cb + 2];
    }
    const float x = a + dt_bias[vh];
    const float sp = (x > 20.f) ? x : log1pf(expf(x));
    gg[idx] = -expf(A_log[vh]) * sp;
    bet[idx] = 1.f / (1.f + expf(-b));
  }
}

// ---------------- phase 1: per (chunk, v-head) intra-chunk precompute --------
__global__ __launch_bounds__(256, 2) void phase1(
    const float* __restrict__ QK, const float* __restrict__ V,
    const float* __restrict__ g, const float* __restrict__ bet,
    __hip_bfloat16* __restrict__ Ub, __hip_bfloat16* __restrict__ Wb,
    __hip_bfloat16* __restrict__ KTb, __hip_bfloat16* __restrict__ Qgb,
    __hip_bfloat16* __restrict__ Bb, float* __restrict__ gend) {
  const int vh = blockIdx.x, ch = blockIdx.y, kh = vh >> 1;
  const int tid = threadIdx.x;
  const int t0 = ch * CHUNK;
  __shared__ __align__(16) __hip_bfloat16 KbS[64][128];
  __shared__ __align__(16) __hip_bfloat16 QbS[64][128];
  __shared__ __align__(16) float Al[64][68];
  __shared__ float bs[64], gams[64], bets[64], lams[64];

  const int row = tid >> 2;
  const size_t hb = (size_t)ch * 32 + vh;
  {
    const int cc = (tid & 3) * 32;
    const float* ksrc = &QK[(size_t)(t0 + row) * 4096 + 2048 + kh * 128 + cc];
    const float* qsrc = &QK[(size_t)(t0 + row) * 4096 + kh * 128 + cc];
#pragma unroll
    for (int u = 0; u < 32; u += 4) {
      const float4 kv = *reinterpret_cast<const float4*>(ksrc + u);
      const float4 qv = *reinterpret_cast<const float4*>(qsrc + u);
      const int d0 = cc + u;
      const int sidx = (d0 & 7) | ((((d0 >> 3) ^ (row & 7)) & 15) << 3);
      ushort4 kk4, qq4;
      kk4.x = __bfloat16_as_ushort(__float2bfloat16(kv.x));
      kk4.y = __bfloat16_as_ushort(__float2bfloat16(kv.y));
      kk4.z = __bfloat16_as_ushort(__float2bfloat16(kv.z));
      kk4.w = __bfloat16_as_ushort(__float2bfloat16(kv.w));
      qq4.x = __bfloat16_as_ushort(__float2bfloat16(qv.x));
      qq4.y = __bfloat16_as_ushort(__float2bfloat16(qv.y));
      qq4.z = __bfloat16_as_ushort(__float2bfloat16(qv.z));
      qq4.w = __bfloat16_as_ushort(__float2bfloat16(qv.w));
      *reinterpret_cast<ushort4*>(&KbS[row][sidx]) = kk4;
      *reinterpret_cast<ushort4*>(&QbS[row][sidx]) = qq4;
    }
  }
  if (tid < 64) {
    float b = g[(size_t)(t0 + tid) * 32 + vh];
#pragma unroll
    for (int off = 1; off < 64; off <<= 1) {
      const float o = __shfl_up(b, off);
      if (tid >= off) b += o;
    }
    const float b63 = __shfl(b, 63);
    const float ga = expf(b);
    bs[tid] = b;
    gams[tid] = ga;
    lams[tid] = expf(b63 - b);
    bets[tid] = bet[(size_t)(t0 + tid) * 32 + vh];
    if (tid == 63) gend[ch * 32 + vh] = ga;
  }
  __syncthreads();
  {
    const int i = tid & 63;
    const float li = lams[i];
    __hip_bfloat16* kt = &KTb[hb * 128 * 64];
    const int dbase = (tid >> 6) * 32;
#pragma unroll
    for (int dd = 0; dd < 32; ++dd) {
      const int d = dbase + dd;
      const int sidx = (d & 7) | ((((d >> 3) ^ (i & 7)) & 15) << 3);
      kt[(size_t)d * 64 + (i ^ ((d & 7) << 3))] =
          __float2bfloat16(li * __bfloat162float(KbS[i][sidx]));
    }
  }
  {
    const float gai = gams[row];
    __hip_bfloat16* qg = &Qgb[(hb * 64 + row) * 128];
    const int cc = (tid & 3) * 32;
#pragma unroll
    for (int u = 0; u < 32; u += 4) {
      const int d0 = cc + u;
      const int sidx = (d0 & 7) | ((((d0 >> 3) ^ (row & 7)) & 15) << 3);
      ushort4 qq;
      qq.x = __bfloat16_as_ushort(__float2bfloat16(gai * __bfloat162float(QbS[row][sidx + 0])));
      qq.y = __bfloat16_as_ushort(__float2bfloat16(gai * __bfloat162float(QbS[row][sidx + 1])));
      qq.z = __bfloat16_as_ushort(__float2bfloat16(gai * __bfloat162float(QbS[row][sidx + 2])));
      qq.w = __bfloat16_as_ushort(__float2bfloat16(gai * __bfloat162float(QbS[row][sidx + 3])));
      *reinterpret_cast<ushort4*>(&qg[d0 ^ ((row & 7) << 3)]) = qq;
    }
  }
  {
    const int w = tid >> 6, lane = tid & 63;
    const int lrow = lane & 15, lk = lane >> 4;
    bf16x8 af[4], qf[4];
#pragma unroll
    for (int kk = 0; kk < 4; ++kk) {
      const int c = ((kk * 4 + lk) ^ (lrow & 7)) * 8;
      af[kk] = *reinterpret_cast<const bf16x8*>(&KbS[w * 16 + lrow][c]);
      qf[kk] = *reinterpret_cast<const bf16x8*>(&QbS[w * 16 + lrow][c]);
    }
#pragma unroll
    for (int n = 0; n < 4; ++n) {
      f32x4 aA = {}, aB = {};
#pragma unroll
      for (int kk = 0; kk < 4; ++kk) {
        const bf16x8 bf = *reinterpret_cast<const bf16x8*>(
            &KbS[n * 16 + lrow][((kk * 4 + lk) ^ (lrow & 7)) * 8]);
        aA = __builtin_amdgcn_mfma_f32_16x16x32_bf16(af[kk], bf, aA, 0, 0, 0);
        aB = __builtin_amdgcn_mfma_f32_16x16x32_bf16(qf[kk], bf, aB, 0, 0, 0);
      }
      __hip_bfloat16* Bout = &Bb[hb * 64 * 64];
#pragma unroll
      for (int r = 0; r < 4; ++r) {
        const int i = w * 16 + lk * 4 + r;
        const int j = n * 16 + lrow;
        const float dec = expf(bs[i] - bs[j]);
        Al[i][j] = (j < i) ? bets[i] * dec * aA[r] : 0.f;
        Bout[(size_t)i * 64 + (j ^ ((i & 7) << 3))] =
            __float2bfloat16((j <= i) ? dec * aB[r] : 0.f);
      }
    }
  }
  __syncthreads();
  {
    const int cc = tid;
    float x[64];
    const bool isV = cc < 128;
    const float* src = isV ? &V[(size_t)t0 * 4096 + vh * 128 + cc]
                           : &QK[(size_t)t0 * 4096 + 2048 + kh * 128 + (cc - 128)];
#pragma unroll
    for (int i = 0; i < 64; ++i) {
      const float sc = isV ? bets[i] : bets[i] * gams[i];
      x[i] = sc * src[(size_t)i * 4096];
    }
#pragma unroll
    for (int i = 1; i < 64; ++i) {
      float s0 = 0.f, s1 = 0.f, s2 = 0.f, s3 = 0.f;
      int j = 0;
#pragma unroll
      for (; j + 4 <= i; j += 4) {
        const float4 a = *reinterpret_cast<const float4*>(&Al[i][j]);
        s0 = fmaf(a.x, x[j], s0);
        s1 = fmaf(a.y, x[j + 1], s1);
        s2 = fmaf(a.z, x[j + 2], s2);
        s3 = fmaf(a.w, x[j + 3], s3);
      }
#pragma unroll
      for (; j < i; ++j) s0 = fmaf(Al[i][j], x[j], s0);
      x[i] -= (s0 + s1) + (s2 + s3);
    }
    if (isV) {
      __hip_bfloat16* dst = &Ub[hb * 64 * 128 + cc];
#pragma unroll
      for (int i = 0; i < 64; ++i) dst[(size_t)i * 128] = __float2bfloat16(x[i]);
    } else {
      const int d = cc - 128;
      __hip_bfloat16* dst = &Wb[hb * 64 * 128];
#pragma unroll
      for (int i = 0; i < 64; ++i)
        dst[(size_t)i * 128 + (d ^ ((i & 7) << 3))] = __float2bfloat16(-x[i]);
    }
  }
}

// ---------------- phaseB: serial MFMA state propagation ----------------------
__global__ __launch_bounds__(128) void phaseB(
    const __hip_bfloat16* __restrict__ Ug, const __hip_bfloat16* __restrict__ Wb,
    const __hip_bfloat16* __restrict__ KTb, const __hip_bfloat16* __restrict__ Qgb,
    const __hip_bfloat16* __restrict__ Bb, const float* __restrict__ gendg,
    float* __restrict__ Og) {
  const int vh = blockIdx.x, slice = blockIdx.y;
  const int tid = threadIdx.x, lane = tid & 63, w = tid >> 6;
  const int l15 = lane & 15, l4 = lane >> 4;
  const int cg = slice * 32 + w * 16;
  const int swz = (l15 & 7) << 3;

  __shared__ __hip_bfloat16 Wl[2][8192];
  __shared__ __hip_bfloat16 KTl[2][8192];
  __shared__ __hip_bfloat16 Qgl[2][8192];
  __shared__ __hip_bfloat16 Bl[2][4096];
  __shared__ __hip_bfloat16 Sop[2][2048];
  __shared__ __hip_bfloat16 dLs[2][1024];

  f32x4 accS[8] = {};
  for (int x = lane; x < 1024; x += 64) reinterpret_cast<uint*>(Sop[w])[x] = 0;

  float ubuf[4][4];
#define STAGE(b_, c_) do {                                                      \
    const size_t hb_ = ((size_t)(c_) * 32 + vh);                                \
    _Pragma("unroll") for (int it = 0; it < 8; ++it) {                          \
      __builtin_amdgcn_global_load_lds(                                         \
          (const __attribute__((address_space(1))) void*)(Wb + hb_ * 8192 + it * 1024 + tid * 8), \
          (__attribute__((address_space(3))) void*)(&Wl[b_][it * 1024 + tid * 8]), 16, 0, 0); \
      __builtin_amdgcn_global_load_lds(                                         \
          (const __attribute__((address_space(1))) void*)(KTb + hb_ * 8192 + it * 1024 + tid * 8), \
          (__attribute__((address_space(3))) void*)(&KTl[b_][it * 1024 + tid * 8]), 16, 0, 0); \
      __builtin_amdgcn_global_load_lds(                                         \
          (const __attribute__((address_space(1))) void*)(Qgb + hb_ * 8192 + it * 1024 + tid * 8), \
          (__attribute__((address_space(3))) void*)(&Qgl[b_][it * 1024 + tid * 8]), 16, 0, 0); \
      if (it < 4)                                                               \
        __builtin_amdgcn_global_load_lds(                                       \
            (const __attribute__((address_space(1))) void*)(Bb + hb_ * 4096 + it * 1024 + tid * 8), \
            (__attribute__((address_space(3))) void*)(&Bl[b_][it * 1024 + tid * 8]), 16, 0, 0); \
    }                                                                           \
  } while (0)
#define UPREF(c_) do {                                                          \
    const __hip_bfloat16* up_ = Ug + ((size_t)(c_) * 32 + vh) * 64 * 128 + cg + l15; \
    _Pragma("unroll") for (int m_ = 0; m_ < 4; ++m_)                            \
      _Pragma("unroll") for (int r_ = 0; r_ < 4; ++r_)                          \
        ubuf[m_][r_] = __bfloat162float(up_[(size_t)(m_ * 16 + l4 * 4 + r_) * 128]); \
  } while (0)

  STAGE(0, 0);
  UPREF(0);
  __syncthreads();
  int buf = 0;
  for (int ch = 0; ch < NCHUNK; ++ch) {
    if (ch + 1 < NCHUNK) STAGE(buf ^ 1, ch + 1);
    f32x4 acc_d[4];
#pragma unroll
    for (int m = 0; m < 4; ++m) {
      f32x4 t;
      t[0] = ubuf[m][0]; t[1] = ubuf[m][1]; t[2] = ubuf[m][2]; t[3] = ubuf[m][3];
      acc_d[m] = t;
    }
    if (ch + 1 < NCHUNK) UPREF(ch + 1);
    // op1: delta = U + (-W) @ S
#pragma unroll
    for (int t = 0; t < 4; ++t) {
      const bf16x8 bS = *reinterpret_cast<const bf16x8*>(
          &Sop[w][l15 * 128 + ((t * 32 + l4 * 8) ^ swz)]);
#pragma unroll
      for (int m = 0; m < 4; ++m) {
        const bf16x8 aW = *reinterpret_cast<const bf16x8*>(
            &Wl[buf][(m * 16 + l15) * 128 + ((t * 32 + l4 * 8) ^ swz)]);
        acc_d[m] = __builtin_amdgcn_mfma_f32_16x16x32_bf16(aW, bS, acc_d[m], 0, 0, 0);
      }
    }
#pragma unroll
    for (int m = 0; m < 4; ++m)
      *reinterpret_cast<ushort4*>(&dLs[w][l15 * 64 + ((m * 16 + l4 * 4) ^ swz)]) =
          pack4(acc_d[m]);
    // opO: o = γq @ S + B @ δ
    f32x4 acc_o[4] = {};
#pragma unroll
    for (int t = 0; t < 4; ++t) {
      const bf16x8 bS = *reinterpret_cast<const bf16x8*>(
          &Sop[w][l15 * 128 + ((t * 32 + l4 * 8) ^ swz)]);
#pragma unroll
      for (int m = 0; m < 4; ++m) {
        const bf16x8 aQ = *reinterpret_cast<const bf16x8*>(
            &Qgl[buf][(m * 16 + l15) * 128 + ((t * 32 + l4 * 8) ^ swz)]);
        acc_o[m] = __builtin_amdgcn_mfma_f32_16x16x32_bf16(aQ, bS, acc_o[m], 0, 0, 0);
      }
    }
#pragma unroll
    for (int t2 = 0; t2 < 2; ++t2) {
      const bf16x8 bD = *reinterpret_cast<const bf16x8*>(
          &dLs[w][l15 * 64 + ((t2 * 32 + l4 * 8) ^ swz)]);
#pragma unroll
      for (int m = 0; m < 4; ++m) {
        const bf16x8 aB = *reinterpret_cast<const bf16x8*>(
            &Bl[buf][(m * 16 + l15) * 64 + ((t2 * 32 + l4 * 8) ^ swz)]);
        acc_o[m] = __builtin_amdgcn_mfma_f32_16x16x32_bf16(aB, bD, acc_o[m], 0, 0, 0);
      }
    }
    float* ob = Og + (size_t)(ch * 64) * 4096 + (size_t)vh * 128 + cg + l15;
#pragma unroll
    for (int m = 0; m < 4; ++m)
#pragma unroll
      for (int r = 0; r < 4; ++r)
        ob[(size_t)(m * 16 + l4 * 4 + r) * 4096] = acc_o[m][r];
    // op3: S = ge*S + Kᵀλ @ δ
    const float ge = gendg[ch * 32 + vh];
#pragma unroll
    for (int f = 0; f < 8; ++f) {
      accS[f][0] *= ge; accS[f][1] *= ge; accS[f][2] *= ge; accS[f][3] *= ge;
    }
#pragma unroll
    for (int t2 = 0; t2 < 2; ++t2) {
      const bf16x8 bD = *reinterpret_cast<const bf16x8*>(
          &dLs[w][l15 * 64 + ((t2 * 32 + l4 * 8) ^ swz)]);
#pragma unroll
      for (int f = 0; f < 8; ++f) {
        const bf16x8 aK = *reinterpret_cast<const bf16x8*>(
            &KTl[buf][(f * 16 + l15) * 64 + ((t2 * 32 + l4 * 8) ^ swz)]);
        accS[f] = __builtin_amdgcn_mfma_f32_16x16x32_bf16(aK, bD, accS[f], 0, 0, 0);
      }
    }
#pragma unroll
    for (int f = 0; f < 8; ++f)
      *reinterpret_cast<ushort4*>(&Sop[w][l15 * 128 + ((f * 16 + l4 * 4) ^ swz)]) =
          pack4(accS[f]);
    __syncthreads();
    buf ^= 1;
  }
#undef STAGE
#undef UPREF
}

// --- gfuse: gate_norm (0..8191) + transpose W_out (8192..10239) --------------
__global__ __launch_bounds__(256) void gfuse(const float* __restrict__ O,
                                             const __hip_bfloat16* __restrict__ qkvz,
                                             const float* __restrict__ norm_w,
                                             __hip_bfloat16* __restrict__ G,
                                             const float* __restrict__ Wo,
                                             __hip_bfloat16* __restrict__ Wot) {
  __shared__ float tl[64][65];
  const int bid = blockIdx.x;
  const int tid = threadIdx.x;
  if (bid < 8192) {
    const int vh = (bid & 7) * 4 + (tid >> 6);
    const int t = bid >> 3, l = tid & 63;
    const size_t ob = (size_t)t * 4096 + vh * 128;
    const size_t zb = (size_t)t * NQKVZ + (vh >> 1) * 768 + 512 + (vh & 1) * 128;
    const float o0 = O[ob + l], o1 = O[ob + l + 64];
    const float z0 = __bfloat162float(qkvz[zb + l]);
    const float z1 = __bfloat162float(qkvz[zb + l + 64]);
    const float g0 = o0 * z0 / (1.f + expf(-z0));
    const float g1 = o1 * z1 / (1.f + expf(-z1));
    float ss = g0 * g0 + g1 * g1;
#pragma unroll
    for (int off = 32; off; off >>= 1) ss += __shfl_xor(ss, off);
    const float rr = rsqrtf(ss * (1.f / 128.f) + 1e-6f);
    G[ob + l] = __float2bfloat16(g0 * rr * norm_w[l]);
    G[ob + l + 64] = __float2bfloat16(g1 * rr * norm_w[l + 64]);
    return;
  }
  const int b = bid - 8192;
  const int n0 = (b & 31) * 64, k0 = (b >> 5) * 64;
  const int N = 2048, K = 4096;
  const int rc = tid & 15, rr2 = tid >> 4;
#pragma unroll
  for (int i = 0; i < 4; ++i) {
    const int k = rr2 + 16 * i;
    const float4 v = *reinterpret_cast<const float4*>(&Wo[(size_t)(k0 + k) * N + n0 + rc * 4]);
    tl[k][rc * 4 + 0] = v.x;
    tl[k][rc * 4 + 1] = v.y;
    tl[k][rc * 4 + 2] = v.z;
    tl[k][rc * 4 + 3] = v.w;
  }
  __syncthreads();
  const int wcx = tid & 7, wry = tid >> 3;
#pragma unroll
  for (int i = 0; i < 2; ++i) {
    const int n = wry + 32 * i;
    uint u[8];
#pragma unroll
    for (int j = 0; j < 8; ++j)
      u[j] = __bfloat16_as_ushort(__float2bfloat16(tl[wcx * 8 + j][n]));
    uint4 o;
    o.x = u[0] | (u[1] << 16);
    o.y = u[2] | (u[3] << 16);
    o.z = u[4] | (u[5] << 16);
    o.w = u[6] | (u[7] << 16);
    *reinterpret_cast<uint4*>((void*)&Wot[(size_t)(n0 + n) * K + k0 + wcx * 8]) = o;
  }
}

extern "C" void kernel_launch(void* const* d_in, const int* in_sizes, int n_in,
                              void* d_out, int out_size, void* d_ws, size_t ws_size,
                              hipStream_t stream) {
  const float* X = (const float*)d_in[0];
  const float* W_qkvz = (const float*)d_in[1];
  const float* W_ba = (const float*)d_in[2];
  const float* conv_w = (const float*)d_in[3];
  const float* dt_bias = (const float*)d_in[4];
  const float* A_log = (const float*)d_in[5];
  const float* norm_w = (const float*)d_in[6];
  const float* W_out = (const float*)d_in[7];
  float* out = (float*)d_out;

  float* ws = (float*)d_ws;
  float* qkvz = ws;                                // region sized 12,582,912 f (used as bf16)
  float* P = qkvz + (size_t)T_LEN * NQKVZ;         //    262,144 f (ba partials)
  float* QK = P + 262144;                          //  4,194,304 f
  float* V = QK + (size_t)T_LEN * 4096;            //  4,194,304 f
  float* U_f = V + (size_t)T_LEN * 4096;           //  4,194,304 f (bf16 U uses half)
  float* Wb_f = U_f + (size_t)NCHUNK * 32 * 64 * 128; // 2,097,152 f
  float* KT_f = Wb_f + 2097152;                    //  2,097,152 f
  float* Qg_f = KT_f + 2097152;                    //  2,097,152 f
  float* Bb_f = Qg_f + 2097152;                    //  1,048,576 f (bf16 x 2.10M)
  float* gg = Bb_f + 1048576;                      //     32,768 f
  float* bet = gg + 32768;                         //     32,768 f
  float* gend = bet + 32768;                       //        512 f

  __hip_bfloat16* qkvzb = (__hip_bfloat16*)qkvz;   // bf16 qkvz
  __hip_bfloat16* Ub = (__hip_bfloat16*)U_f;
  __hip_bfloat16* Wb = (__hip_bfloat16*)Wb_f;
  __hip_bfloat16* KTb = (__hip_bfloat16*)KT_f;
  __hip_bfloat16* Qgb = (__hip_bfloat16*)Qg_f;
  __hip_bfloat16* Bb = (__hip_bfloat16*)Bb_f;
  // lifetime aliases:
  __hip_bfloat16* Wqkvz_t = (__hip_bfloat16*)V;    // spans V+U+Wb+KT (dead after 1st gemm)
  __hip_bfloat16* Xb = (__hip_bfloat16*)Qg_f;      // dead after 1st gemm
  __hip_bfloat16* Gb = (__hip_bfloat16*)Bb_f;      // Bb dead after phaseB
  __hip_bfloat16* Wout_t = (__hip_bfloat16*)qkvz;  // qkvz dead after gfuse's gate part
  float* O = V;                                    // V dead after phase1
  __hip_bfloat16* Pout = (__hip_bfloat16*)U_f;     // U+Wb+KT dead after phaseB: 16.7M bf16 >= 16M

  preba<<<dim3(2048 + 256), 256, 0, stream>>>(X, Xb, W_ba, P);
  wtrans<<<dim3(6144), 256, 0, stream>>>(W_qkvz, Wqkvz_t);
  gemm256<<<dim3(NQKVZ / 256, T_LEN / 256, 1), 512, 0, stream>>>(
      Xb, Wqkvz_t, qkvzb, T_LEN, NQKVZ, 2048, 2048);
  convs<<<dim3(4096 + 512 + 128), 256, 0, stream>>>(qkvzb, conv_w, QK, V, P,
                                                    dt_bias, A_log, gg, bet);
  phase1<<<dim3(HV_N, NCHUNK), 256, 0, stream>>>(QK, V, gg, bet, Ub, Wb, KTb, Qgb, Bb, gend);
  phaseB<<<dim3(HV_N, 4), 128, 0, stream>>>(Ub, Wb, KTb, Qgb, Bb, gend, O);
  gfuse<<<dim3(8192 + 2048), 256, 0, stream>>>(O, qkvzb, norm_w, Gb, W_out, Wout_t);
  gemm256<<<dim3(2048 / 256, T_LEN / 256, 8), 512, 0, stream>>>(
      Gb, Wout_t, Pout, T_LEN, 2048, 512, 4096);
  add8<<<dim3(T_LEN * 2048 / 4 / 256), 256, 0, stream>>>(Pout, out, T_LEN * 2048);
}

// Round 22
// 257.606 us; speedup vs baseline: 1.0141x; 1.0141x over previous
//
#include <hip/hip_runtime.h>
#include <hip/hip_bf16.h>
#include <math.h>

// Qwen3Next GatedDeltaNet — round 21: revert out-GEMM to measured-best
// gemm_bf16<128> z=4 + add4 (round-20 config). gemm256 z=8 regressed on the
// short-K out-GEMM (prologue/epilogue + 2x partial traffic). Keep gemm256
// for qkvz and the preba/wtrans split.

#define T_LEN 1024
#define HK_N 16
#define HV_N 32
#define NQKVZ 12288
#define CHUNK 64
#define NCHUNK 16

typedef __bf16 bf16x8 __attribute__((ext_vector_type(8)));
typedef float f32x4 __attribute__((ext_vector_type(4)));

__device__ __forceinline__ ushort4 pack4(const f32x4 v) {
  ushort4 o;
  o.x = __bfloat16_as_ushort(__float2bfloat16(v[0]));
  o.y = __bfloat16_as_ushort(__float2bfloat16(v[1]));
  o.z = __bfloat16_as_ushort(__float2bfloat16(v[2]));
  o.w = __bfloat16_as_ushort(__float2bfloat16(v[3]));
  return o;
}

// ---- 256x256 big-tile bf16 GEMM: C = A @ B^T (used for qkvz) ---------------
__global__ __launch_bounds__(512) void gemm256(const __hip_bfloat16* __restrict__ A,
                                               const __hip_bfloat16* __restrict__ B,
                                               __hip_bfloat16* __restrict__ C,
                                               int M, int N, int Klen, int ldk) {
  __shared__ __align__(16) __hip_bfloat16 As[2][256 * 64];
  __shared__ __align__(16) __hip_bfloat16 Bs[2][256 * 64];
  const int tid = threadIdx.x;
  const int wid = tid >> 6, lane = tid & 63;
  const int wr = wid >> 2, wc = wid & 3;
  const int m0 = blockIdx.y * 256, n0 = blockIdx.x * 256;
  const size_t kbase = (size_t)blockIdx.z * Klen;
  __hip_bfloat16* Cz = C + (size_t)blockIdx.z * M * N;
  const int lrow = lane & 15, lk = lane >> 4;
  const int rswz = (lrow & 7) * 8;
  f32x4 acc[8][4] = {};
  const int nk = Klen >> 6;

#define GST(b_, kt_) do {                                                       \
    _Pragma("unroll") for (int it = 0; it < 4; ++it) {                          \
      const int c_ = it * 512 + tid;                                            \
      const int row_ = c_ >> 3;                                                 \
      const int col8_ = ((c_ & 7) ^ (row_ & 7)) * 8;                            \
      __builtin_amdgcn_global_load_lds(                                         \
          (const __attribute__((address_space(1))) void*)                       \
              (A + (size_t)(m0 + row_) * ldk + kbase + ((kt_) << 6) + col8_),   \
          (__attribute__((address_space(3))) void*)(&As[b_][c_ * 8]), 16, 0, 0);\
    }                                                                           \
    _Pragma("unroll") for (int it = 0; it < 4; ++it) {                          \
      const int c_ = it * 512 + tid;                                            \
      const int row_ = c_ >> 3;                                                 \
      const int col8_ = ((c_ & 7) ^ (row_ & 7)) * 8;                            \
      __builtin_amdgcn_global_load_lds(                                         \
          (const __attribute__((address_space(1))) void*)                       \
              (B + (size_t)(n0 + row_) * ldk + kbase + ((kt_) << 6) + col8_),   \
          (__attribute__((address_space(3))) void*)(&Bs[b_][c_ * 8]), 16, 0, 0);\
    }                                                                           \
  } while (0)

  GST(0, 0);
  GST(1, 1);
  int cur = 0;
  for (int t = 0; t < nk; ++t) {
    if (t < nk - 1) asm volatile("s_waitcnt vmcnt(8)" ::: "memory");
    else            asm volatile("s_waitcnt vmcnt(0)" ::: "memory");
    __builtin_amdgcn_s_barrier();
    __builtin_amdgcn_sched_barrier(0);
    bf16x8 af[8], bfv[4];
#pragma unroll
    for (int m = 0; m < 8; ++m)
      af[m] = *reinterpret_cast<const bf16x8*>(
          &As[cur][(wr * 128 + m * 16 + lrow) * 64 + ((lk * 8) ^ rswz)]);
#pragma unroll
    for (int n = 0; n < 4; ++n)
      bfv[n] = *reinterpret_cast<const bf16x8*>(
          &Bs[cur][(wc * 64 + n * 16 + lrow) * 64 + ((lk * 8) ^ rswz)]);
    __builtin_amdgcn_s_setprio(1);
#pragma unroll
    for (int m = 0; m < 8; ++m)
#pragma unroll
      for (int n = 0; n < 4; ++n)
        acc[m][n] = __builtin_amdgcn_mfma_f32_16x16x32_bf16(af[m], bfv[n], acc[m][n], 0, 0, 0);
    __builtin_amdgcn_s_setprio(0);
#pragma unroll
    for (int m = 0; m < 8; ++m)
      af[m] = *reinterpret_cast<const bf16x8*>(
          &As[cur][(wr * 128 + m * 16 + lrow) * 64 + ((32 + lk * 8) ^ rswz)]);
#pragma unroll
    for (int n = 0; n < 4; ++n)
      bfv[n] = *reinterpret_cast<const bf16x8*>(
          &Bs[cur][(wc * 64 + n * 16 + lrow) * 64 + ((32 + lk * 8) ^ rswz)]);
    asm volatile("s_waitcnt lgkmcnt(0)" ::: "memory");
    __builtin_amdgcn_sched_barrier(0);
    __builtin_amdgcn_s_barrier();
    __builtin_amdgcn_sched_barrier(0);
    if (t + 2 < nk) GST(cur, t + 2);
    __builtin_amdgcn_s_setprio(1);
#pragma unroll
    for (int m = 0; m < 8; ++m)
#pragma unroll
      for (int n = 0; n < 4; ++n)
        acc[m][n] = __builtin_amdgcn_mfma_f32_16x16x32_bf16(af[m], bfv[n], acc[m][n], 0, 0, 0);
    __builtin_amdgcn_s_setprio(0);
    cur ^= 1;
  }
#undef GST
#pragma unroll
  for (int m = 0; m < 8; ++m)
#pragma unroll
    for (int n = 0; n < 4; ++n)
#pragma unroll
      for (int r = 0; r < 4; ++r)
        Cz[(size_t)(m0 + wr * 128 + m * 16 + lk * 4 + r) * N + n0 + wc * 64 + n * 16 + lrow] =
            __float2bfloat16(acc[m][n][r]);
}

// ------- bf16 MFMA GEMM (128-tile, proven): C (z-partials, bf16) = A @ B^T ---
__global__ __launch_bounds__(256) void gemm_bf16(const __hip_bfloat16* __restrict__ A,
                                                 const __hip_bfloat16* __restrict__ B,
                                                 __hip_bfloat16* __restrict__ C,
                                                 int M, int N, int Klen, int ldk) {
  __shared__ __align__(16) __hip_bfloat16 As[2][128 * 64];
  __shared__ __align__(16) __hip_bfloat16 Bs[2][128 * 64];
  const int tid = threadIdx.x;
  const int wid = tid >> 6, lane = tid & 63;
  const int wr = wid >> 1, wc = wid & 1;
  const int m0 = blockIdx.y * 128, n0 = blockIdx.x * 128;
  const size_t kbase = (size_t)blockIdx.z * Klen;
  __hip_bfloat16* Cz = C + (size_t)blockIdx.z * M * N;
  const int lrow = lane & 15, lk = lane >> 4;
  const int rswz = (lrow & 7) * 8;
  f32x4 acc[4][4] = {};
  const int nk = Klen >> 6;

#define GSTAGE(b_, k0_) do {                                                    \
    _Pragma("unroll") for (int it = 0; it < 4; ++it) {                          \
      const int c_ = it * 256 + tid;                                            \
      const int row_ = c_ >> 3;                                                 \
      const int col8_ = ((c_ & 7) ^ (row_ & 7)) * 8;                            \
      __builtin_amdgcn_global_load_lds(                                         \
          (const __attribute__((address_space(1))) void*)                       \
              (A + (size_t)(m0 + row_) * ldk + kbase + (k0_) + col8_),          \
          (__attribute__((address_space(3))) void*)(&As[b_][it * 2048 + tid * 8]), 16, 0, 0); \
      __builtin_amdgcn_global_load_lds(                                         \
          (const __attribute__((address_space(1))) void*)                       \
              (B + (size_t)(n0 + row_) * ldk + kbase + (k0_) + col8_),          \
          (__attribute__((address_space(3))) void*)(&Bs[b_][it * 2048 + tid * 8]), 16, 0, 0); \
    }                                                                           \
  } while (0)

  GSTAGE(0, 0);
  int buf = 0;
  for (int k = 0; k < nk; ++k) {
    if (k + 1 < nk) {
      GSTAGE(buf ^ 1, (k + 1) << 6);
      asm volatile("s_waitcnt vmcnt(8)" ::: "memory");
    } else {
      asm volatile("s_waitcnt vmcnt(0)" ::: "memory");
    }
    __builtin_amdgcn_s_barrier();
    __builtin_amdgcn_sched_barrier(0);
#pragma unroll
    for (int kk = 0; kk < 2; ++kk) {
      bf16x8 af[4], bfv[4];
#pragma unroll
      for (int m = 0; m < 4; ++m)
        af[m] = *reinterpret_cast<const bf16x8*>(
            &As[buf][(wr * 64 + m * 16 + lrow) * 64 + ((kk * 32 + lk * 8) ^ rswz)]);
#pragma unroll
      for (int n = 0; n < 4; ++n)
        bfv[n] = *reinterpret_cast<const bf16x8*>(
            &Bs[buf][(wc * 64 + n * 16 + lrow) * 64 + ((kk * 32 + lk * 8) ^ rswz)]);
#pragma unroll
      for (int m = 0; m < 4; ++m)
#pragma unroll
        for (int n = 0; n < 4; ++n)
          acc[m][n] = __builtin_amdgcn_mfma_f32_16x16x32_bf16(af[m], bfv[n], acc[m][n], 0, 0, 0);
    }
    __builtin_amdgcn_sched_barrier(0);
    __builtin_amdgcn_s_barrier();
    buf ^= 1;
  }
#undef GSTAGE
#pragma unroll
  for (int m = 0; m < 4; ++m)
#pragma unroll
    for (int n = 0; n < 4; ++n)
#pragma unroll
      for (int r = 0; r < 4; ++r)
        Cz[(size_t)(m0 + wr * 64 + m * 16 + lk * 4 + r) * N + n0 + wc * 64 + n * 16 + lrow] =
            __float2bfloat16(acc[m][n][r]);
}

// -------- out = sum of 4 bf16 K-slice partials (fp32 accumulate) -------------
__global__ void add4(const __hip_bfloat16* __restrict__ P, float* __restrict__ out, int n) {
  const int i = (blockIdx.x * 256 + threadIdx.x) * 4;
  if (i < n) {
    float s[4] = {0.f, 0.f, 0.f, 0.f};
#pragma unroll
    for (int z = 0; z < 4; ++z) {
      const ushort4 v = *reinterpret_cast<const ushort4*>(P + (size_t)z * n + i);
      s[0] += __bfloat162float(__ushort_as_bfloat16(v.x));
      s[1] += __bfloat162float(__ushort_as_bfloat16(v.y));
      s[2] += __bfloat162float(__ushort_as_bfloat16(v.z));
      s[3] += __bfloat162float(__ushort_as_bfloat16(v.w));
    }
    *reinterpret_cast<float4*>(out + i) = make_float4(s[0], s[1], s[2], s[3]);
  }
}

// --- preba: cast X -> bf16 (blocks 0..2047) + split-K ba GEMM (2048..2303) ---
__global__ __launch_bounds__(256) void preba(const float* __restrict__ X,
                                             __hip_bfloat16* __restrict__ Xb,
                                             const float* __restrict__ Wba,
                                             float* __restrict__ P) {
  __shared__ __align__(16) float Xs[16][512];
  const int bid = blockIdx.x;
  const int tid = threadIdx.x;
  if (bid < 2048) {
    const int i = (bid * 256 + tid) * 4;
    const float4 v = *reinterpret_cast<const float4*>(X + i);
    ushort4 o;
    o.x = __bfloat16_as_ushort(__float2bfloat16(v.x));
    o.y = __bfloat16_as_ushort(__float2bfloat16(v.y));
    o.z = __bfloat16_as_ushort(__float2bfloat16(v.z));
    o.w = __bfloat16_as_ushort(__float2bfloat16(v.w));
    *reinterpret_cast<ushort4*>((void*)(Xb + i)) = o;
  } else {
    const int b = bid - 2048;
    const int tt = b & 63, ks = b >> 6;
    const int c = tid & 63, r4 = tid >> 6;
    const float* xsrc = X + (size_t)(tt * 16) * 2048 + ks * 512;
#pragma unroll
    for (int u = 0; u < 8; ++u) {
      const int flat = (u * 256 + tid) * 4;
      const int r = flat >> 9, k = flat & 511;
      *reinterpret_cast<float4*>(&Xs[r][k]) =
          *reinterpret_cast<const float4*>(&xsrc[(size_t)r * 2048 + k]);
    }
    __syncthreads();
    float acc[4] = {};
    const float* wp = Wba + (size_t)(ks * 512) * 64 + c;
    for (int k = 0; k < 512; k += 8) {
      float w[8];
#pragma unroll
      for (int u = 0; u < 8; ++u) w[u] = wp[(size_t)(k + u) * 64];
#pragma unroll
      for (int u = 0; u < 8; ++u)
#pragma unroll
        for (int i = 0; i < 4; ++i)
          acc[i] = fmaf(Xs[r4 * 4 + i][k + u], w[u], acc[i]);
    }
    float* pp = P + ((size_t)ks * 1024 + tt * 16 + r4 * 4) * 64 + c;
#pragma unroll
    for (int i = 0; i < 4; ++i) pp[(size_t)i * 64] = acc[i];
  }
}

// --- wtrans: W_qkvz [2048, 12288] fp32 -> bf16 [12288, 2048], 64x64 tiles ----
__global__ __launch_bounds__(256) void wtrans(const float* __restrict__ Wq,
                                              __hip_bfloat16* __restrict__ Wqt) {
  __shared__ float tl[64][65];
  const int b = blockIdx.x;
  const int n0 = (b % 192) * 64, k0 = (b / 192) * 64;
  const int N = NQKVZ, K = 2048;
  const int tid = threadIdx.x;
  const int rc = tid & 15, rr = tid >> 4;
#pragma unroll
  for (int i = 0; i < 4; ++i) {
    const int k = rr + 16 * i;
    const float4 v = *reinterpret_cast<const float4*>(&Wq[(size_t)(k0 + k) * N + n0 + rc * 4]);
    tl[k][rc * 4 + 0] = v.x;
    tl[k][rc * 4 + 1] = v.y;
    tl[k][rc * 4 + 2] = v.z;
    tl[k][rc * 4 + 3] = v.w;
  }
  __syncthreads();
  const int wcx = tid & 7, wry = tid >> 3;
#pragma unroll
  for (int i = 0; i < 2; ++i) {
    const int n = wry + 32 * i;
    uint u[8];
#pragma unroll
    for (int j = 0; j < 8; ++j)
      u[j] = __bfloat16_as_ushort(__float2bfloat16(tl[wcx * 8 + j][n]));
    uint4 o;
    o.x = u[0] | (u[1] << 16);
    o.y = u[2] | (u[3] << 16);
    o.z = u[4] | (u[5] << 16);
    o.w = u[6] | (u[7] << 16);
    *reinterpret_cast<uint4*>((void*)&Wqt[(size_t)(n0 + n) * K + k0 + wcx * 8]) = o;
  }
}

// --- convs: conv_qk_norm (0..4095) + conv_v (4096..4607) + gb (4608..4735) ---
__global__ __launch_bounds__(256) void convs(const __hip_bfloat16* __restrict__ qkvz,
                                             const float* __restrict__ conv_w,
                                             float* __restrict__ QK,
                                             float* __restrict__ V,
                                             const float* __restrict__ P,
                                             const float* __restrict__ dt_bias,
                                             const float* __restrict__ A_log,
                                             float* __restrict__ gg,
                                             float* __restrict__ bet) {
  const int bid = blockIdx.x;
  const int tid = threadIdx.x;
  if (bid < 4096) {
    const int kh = bid & 15;
    const int t = (bid >> 4) * 4 + (tid >> 6);
    const int l = tid & 63;
    const int cols[4] = {kh * 768 + l, kh * 768 + l + 64,
                         kh * 768 + 128 + l, kh * 768 + 128 + l + 64};
    const int chs[4] = {kh * 128 + l, kh * 128 + l + 64,
                        2048 + kh * 128 + l, 2048 + kh * 128 + l + 64};
    float y[4];
#pragma unroll
    for (int j = 0; j < 4; ++j) {
      const float* wp = &conv_w[chs[j] * 4];
      float acc = 0.f;
#pragma unroll
      for (int s = 0; s < 4; ++s) {
        const int tt = t - 3 + s;
        if (tt >= 0)
          acc = fmaf(__bfloat162float(qkvz[(size_t)tt * NQKVZ + cols[j]]), wp[s], acc);
      }
      y[j] = acc / (1.f + expf(-acc));  // silu
    }
    float sq = y[0] * y[0] + y[1] * y[1];
    float sk = y[2] * y[2] + y[3] * y[3];
#pragma unroll
    for (int off = 32; off; off >>= 1) {
      sq += __shfl_xor(sq, off);
      sk += __shfl_xor(sk, off);
    }
    const float rq = rsqrtf(sq + 1e-6f) * 0.08838834764831845f;  // * DK^-0.5
    const float rk = rsqrtf(sk + 1e-6f);
    const size_t qb = (size_t)t * 4096 + kh * 128;
    QK[qb + l] = y[0] * rq;
    QK[qb + l + 64] = y[1] * rq;
    QK[qb + 2048 + l] = y[2] * rk;
    QK[qb + 2048 + l + 64] = y[3] * rk;
  } else if (bid < 4608) {
    const int b = bid - 4096;
    const int c2 = (b & 15) * 256 + tid;
    const int vh = c2 >> 7;
    const int col = (vh >> 1) * 768 + 256 + (vh & 1) * 128 + (c2 & 127);
    const int t0 = (b >> 4) * 32;
    const float4 w = *reinterpret_cast<const float4*>(&conv_w[(4096 + c2) * 4]);
    float x0, x1, x2;
    if (t0 == 0) {
      x0 = 0.f; x1 = 0.f; x2 = 0.f;
    } else {
      x0 = __bfloat162float(qkvz[(size_t)(t0 - 3) * NQKVZ + col]);
      x1 = __bfloat162float(qkvz[(size_t)(t0 - 2) * NQKVZ + col]);
      x2 = __bfloat162float(qkvz[(size_t)(t0 - 1) * NQKVZ + col]);
    }
#pragma unroll 4
    for (int tt = 0; tt < 32; ++tt) {
      const int t = t0 + tt;
      const float x3 = __bfloat162float(qkvz[(size_t)t * NQKVZ + col]);
      float acc = x0 * w.x;
      acc = fmaf(x1, w.y, acc);
      acc = fmaf(x2, w.z, acc);
      acc = fmaf(x3, w.w, acc);
      V[(size_t)t * 4096 + c2] = acc / (1.f + expf(-acc));
      x0 = x1; x1 = x2; x2 = x3;
    }
  } else {
    const int idx = (bid - 4608) * 256 + tid;  // t*32 + vh
    const int t = idx >> 5, vh = idx & 31;
    const int cb = (vh >> 1) * 4 + (vh & 1);
    float b = 0.f, a = 0.f;
#pragma unroll
    for (int s = 0; s < 4; ++s) {
      b += P[((size_t)s * 1024 + t) * 64 + cb];
      a += P[((size_t)s * 1024 + t) * 64 + cb + 2];
    }
    const float x = a + dt_bias[vh];
    const float sp = (x > 20.f) ? x : log1pf(expf(x));
    gg[idx] = -expf(A_log[vh]) * sp;
    bet[idx] = 1.f / (1.f + expf(-b));
  }
}

// ---------------- phase 1: per (chunk, v-head) intra-chunk precompute --------
__global__ __launch_bounds__(256, 2) void phase1(
    const float* __restrict__ QK, const float* __restrict__ V,
    const float* __restrict__ g, const float* __restrict__ bet,
    __hip_bfloat16* __restrict__ Ub, __hip_bfloat16* __restrict__ Wb,
    __hip_bfloat16* __restrict__ KTb, __hip_bfloat16* __restrict__ Qgb,
    __hip_bfloat16* __restrict__ Bb, float* __restrict__ gend) {
  const int vh = blockIdx.x, ch = blockIdx.y, kh = vh >> 1;
  const int tid = threadIdx.x;
  const int t0 = ch * CHUNK;
  __shared__ __align__(16) __hip_bfloat16 KbS[64][128];
  __shared__ __align__(16) __hip_bfloat16 QbS[64][128];
  __shared__ __align__(16) float Al[64][68];
  __shared__ float bs[64], gams[64], bets[64], lams[64];

  const int row = tid >> 2;
  const size_t hb = (size_t)ch * 32 + vh;
  {
    const int cc = (tid & 3) * 32;
    const float* ksrc = &QK[(size_t)(t0 + row) * 4096 + 2048 + kh * 128 + cc];
    const float* qsrc = &QK[(size_t)(t0 + row) * 4096 + kh * 128 + cc];
#pragma unroll
    for (int u = 0; u < 32; u += 4) {
      const float4 kv = *reinterpret_cast<const float4*>(ksrc + u);
      const float4 qv = *reinterpret_cast<const float4*>(qsrc + u);
      const int d0 = cc + u;
      const int sidx = (d0 & 7) | ((((d0 >> 3) ^ (row & 7)) & 15) << 3);
      ushort4 kk4, qq4;
      kk4.x = __bfloat16_as_ushort(__float2bfloat16(kv.x));
      kk4.y = __bfloat16_as_ushort(__float2bfloat16(kv.y));
      kk4.z = __bfloat16_as_ushort(__float2bfloat16(kv.z));
      kk4.w = __bfloat16_as_ushort(__float2bfloat16(kv.w));
      qq4.x = __bfloat16_as_ushort(__float2bfloat16(qv.x));
      qq4.y = __bfloat16_as_ushort(__float2bfloat16(qv.y));
      qq4.z = __bfloat16_as_ushort(__float2bfloat16(qv.z));
      qq4.w = __bfloat16_as_ushort(__float2bfloat16(qv.w));
      *reinterpret_cast<ushort4*>(&KbS[row][sidx]) = kk4;
      *reinterpret_cast<ushort4*>(&QbS[row][sidx]) = qq4;
    }
  }
  if (tid < 64) {
    float b = g[(size_t)(t0 + tid) * 32 + vh];
#pragma unroll
    for (int off = 1; off < 64; off <<= 1) {
      const float o = __shfl_up(b, off);
      if (tid >= off) b += o;
    }
    const float b63 = __shfl(b, 63);
    const float ga = expf(b);
    bs[tid] = b;
    gams[tid] = ga;
    lams[tid] = expf(b63 - b);
    bets[tid] = bet[(size_t)(t0 + tid) * 32 + vh];
    if (tid == 63) gend[ch * 32 + vh] = ga;
  }
  __syncthreads();
  {
    const int i = tid & 63;
    const float li = lams[i];
    __hip_bfloat16* kt = &KTb[hb * 128 * 64];
    const int dbase = (tid >> 6) * 32;
#pragma unroll
    for (int dd = 0; dd < 32; ++dd) {
      const int d = dbase + dd;
      const int sidx = (d & 7) | ((((d >> 3) ^ (i & 7)) & 15) << 3);
      kt[(size_t)d * 64 + (i ^ ((d & 7) << 3))] =
          __float2bfloat16(li * __bfloat162float(KbS[i][sidx]));
    }
  }
  {
    const float gai = gams[row];
    __hip_bfloat16* qg = &Qgb[(hb * 64 + row) * 128];
    const int cc = (tid & 3) * 32;
#pragma unroll
    for (int u = 0; u < 32; u += 4) {
      const int d0 = cc + u;
      const int sidx = (d0 & 7) | ((((d0 >> 3) ^ (row & 7)) & 15) << 3);
      ushort4 qq;
      qq.x = __bfloat16_as_ushort(__float2bfloat16(gai * __bfloat162float(QbS[row][sidx + 0])));
      qq.y = __bfloat16_as_ushort(__float2bfloat16(gai * __bfloat162float(QbS[row][sidx + 1])));
      qq.z = __bfloat16_as_ushort(__float2bfloat16(gai * __bfloat162float(QbS[row][sidx + 2])));
      qq.w = __bfloat16_as_ushort(__float2bfloat16(gai * __bfloat162float(QbS[row][sidx + 3])));
      *reinterpret_cast<ushort4*>(&qg[d0 ^ ((row & 7) << 3)]) = qq;
    }
  }
  {
    const int w = tid >> 6, lane = tid & 63;
    const int lrow = lane & 15, lk = lane >> 4;
    bf16x8 af[4], qf[4];
#pragma unroll
    for (int kk = 0; kk < 4; ++kk) {
      const int c = ((kk * 4 + lk) ^ (lrow & 7)) * 8;
      af[kk] = *reinterpret_cast<const bf16x8*>(&KbS[w * 16 + lrow][c]);
      qf[kk] = *reinterpret_cast<const bf16x8*>(&QbS[w * 16 + lrow][c]);
    }
#pragma unroll
    for (int n = 0; n < 4; ++n) {
      f32x4 aA = {}, aB = {};
#pragma unroll
      for (int kk = 0; kk < 4; ++kk) {
        const bf16x8 bf = *reinterpret_cast<const bf16x8*>(
            &KbS[n * 16 + lrow][((kk * 4 + lk) ^ (lrow & 7)) * 8]);
        aA = __builtin_amdgcn_mfma_f32_16x16x32_bf16(af[kk], bf, aA, 0, 0, 0);
        aB = __builtin_amdgcn_mfma_f32_16x16x32_bf16(qf[kk], bf, aB, 0, 0, 0);
      }
      __hip_bfloat16* Bout = &Bb[hb * 64 * 64];
#pragma unroll
      for (int r = 0; r < 4; ++r) {
        const int i = w * 16 + lk * 4 + r;
        const int j = n * 16 + lrow;
        const float dec = expf(bs[i] - bs[j]);
        Al[i][j] = (j < i) ? bets[i] * dec * aA[r] : 0.f;
        Bout[(size_t)i * 64 + (j ^ ((i & 7) << 3))] =
            __float2bfloat16((j <= i) ? dec * aB[r] : 0.f);
      }
    }
  }
  __syncthreads();
  {
    const int cc = tid;
    float x[64];
    const bool isV = cc < 128;
    const float* src = isV ? &V[(size_t)t0 * 4096 + vh * 128 + cc]
                           : &QK[(size_t)t0 * 4096 + 2048 + kh * 128 + (cc - 128)];
#pragma unroll
    for (int i = 0; i < 64; ++i) {
      const float sc = isV ? bets[i] : bets[i] * gams[i];
      x[i] = sc * src[(size_t)i * 4096];
    }
#pragma unroll
    for (int i = 1; i < 64; ++i) {
      float s0 = 0.f, s1 = 0.f, s2 = 0.f, s3 = 0.f;
      int j = 0;
#pragma unroll
      for (; j + 4 <= i; j += 4) {
        const float4 a = *reinterpret_cast<const float4*>(&Al[i][j]);
        s0 = fmaf(a.x, x[j], s0);
        s1 = fmaf(a.y, x[j + 1], s1);
        s2 = fmaf(a.z, x[j + 2], s2);
        s3 = fmaf(a.w, x[j + 3], s3);
      }
#pragma unroll
      for (; j < i; ++j) s0 = fmaf(Al[i][j], x[j], s0);
      x[i] -= (s0 + s1) + (s2 + s3);
    }
    if (isV) {
      __hip_bfloat16* dst = &Ub[hb * 64 * 128 + cc];
#pragma unroll
      for (int i = 0; i < 64; ++i) dst[(size_t)i * 128] = __float2bfloat16(x[i]);
    } else {
      const int d = cc - 128;
      __hip_bfloat16* dst = &Wb[hb * 64 * 128];
#pragma unroll
      for (int i = 0; i < 64; ++i)
        dst[(size_t)i * 128 + (d ^ ((i & 7) << 3))] = __float2bfloat16(-x[i]);
    }
  }
}

// ---------------- phaseB: serial MFMA state propagation ----------------------
__global__ __launch_bounds__(128) void phaseB(
    const __hip_bfloat16* __restrict__ Ug, const __hip_bfloat16* __restrict__ Wb,
    const __hip_bfloat16* __restrict__ KTb, const __hip_bfloat16* __restrict__ Qgb,
    const __hip_bfloat16* __restrict__ Bb, const float* __restrict__ gendg,
    float* __restrict__ Og) {
  const int vh = blockIdx.x, slice = blockIdx.y;
  const int tid = threadIdx.x, lane = tid & 63, w = tid >> 6;
  const int l15 = lane & 15, l4 = lane >> 4;
  const int cg = slice * 32 + w * 16;
  const int swz = (l15 & 7) << 3;

  __shared__ __hip_bfloat16 Wl[2][8192];
  __shared__ __hip_bfloat16 KTl[2][8192];
  __shared__ __hip_bfloat16 Qgl[2][8192];
  __shared__ __hip_bfloat16 Bl[2][4096];
  __shared__ __hip_bfloat16 Sop[2][2048];
  __shared__ __hip_bfloat16 dLs[2][1024];

  f32x4 accS[8] = {};
  for (int x = lane; x < 1024; x += 64) reinterpret_cast<uint*>(Sop[w])[x] = 0;

  float ubuf[4][4];
#define STAGE(b_, c_) do {                                                      \
    const size_t hb_ = ((size_t)(c_) * 32 + vh);                                \
    _Pragma("unroll") for (int it = 0; it < 8; ++it) {                          \
      __builtin_amdgcn_global_load_lds(                                         \
          (const __attribute__((address_space(1))) void*)(Wb + hb_ * 8192 + it * 1024 + tid * 8), \
          (__attribute__((address_space(3))) void*)(&Wl[b_][it * 1024 + tid * 8]), 16, 0, 0); \
      __builtin_amdgcn_global_load_lds(                                         \
          (const __attribute__((address_space(1))) void*)(KTb + hb_ * 8192 + it * 1024 + tid * 8), \
          (__attribute__((address_space(3))) void*)(&KTl[b_][it * 1024 + tid * 8]), 16, 0, 0); \
      __builtin_amdgcn_global_load_lds(                                         \
          (const __attribute__((address_space(1))) void*)(Qgb + hb_ * 8192 + it * 1024 + tid * 8), \
          (__attribute__((address_space(3))) void*)(&Qgl[b_][it * 1024 + tid * 8]), 16, 0, 0); \
      if (it < 4)                                                               \
        __builtin_amdgcn_global_load_lds(                                       \
            (const __attribute__((address_space(1))) void*)(Bb + hb_ * 4096 + it * 1024 + tid * 8), \
            (__attribute__((address_space(3))) void*)(&Bl[b_][it * 1024 + tid * 8]), 16, 0, 0); \
    }                                                                           \
  } while (0)
#define UPREF(c_) do {                                                          \
    const __hip_bfloat16* up_ = Ug + ((size_t)(c_) * 32 + vh) * 64 * 128 + cg + l15; \
    _Pragma("unroll") for (int m_ = 0; m_ < 4; ++m_)                            \
      _Pragma("unroll") for (int r_ = 0; r_ < 4; ++r_)                          \
        ubuf[m_][r_] = __bfloat162float(up_[(size_t)(m_ * 16 + l4 * 4 + r_) * 128]); \
  } while (0)

  STAGE(0, 0);
  UPREF(0);
  __syncthreads();
  int buf = 0;
  for (int ch = 0; ch < NCHUNK; ++ch) {
    if (ch + 1 < NCHUNK) STAGE(buf ^ 1, ch + 1);
    f32x4 acc_d[4];
#pragma unroll
    for (int m = 0; m < 4; ++m) {
      f32x4 t;
      t[0] = ubuf[m][0]; t[1] = ubuf[m][1]; t[2] = ubuf[m][2]; t[3] = ubuf[m][3];
      acc_d[m] = t;
    }
    if (ch + 1 < NCHUNK) UPREF(ch + 1);
    // op1: delta = U + (-W) @ S
#pragma unroll
    for (int t = 0; t < 4; ++t) {
      const bf16x8 bS = *reinterpret_cast<const bf16x8*>(
          &Sop[w][l15 * 128 + ((t * 32 + l4 * 8) ^ swz)]);
#pragma unroll
      for (int m = 0; m < 4; ++m) {
        const bf16x8 aW = *reinterpret_cast<const bf16x8*>(
            &Wl[buf][(m * 16 + l15) * 128 + ((t * 32 + l4 * 8) ^ swz)]);
        acc_d[m] = __builtin_amdgcn_mfma_f32_16x16x32_bf16(aW, bS, acc_d[m], 0, 0, 0);
      }
    }
#pragma unroll
    for (int m = 0; m < 4; ++m)
      *reinterpret_cast<ushort4*>(&dLs[w][l15 * 64 + ((m * 16 + l4 * 4) ^ swz)]) =
          pack4(acc_d[m]);
    // opO: o = γq @ S + B @ δ
    f32x4 acc_o[4] = {};
#pragma unroll
    for (int t = 0; t < 4; ++t) {
      const bf16x8 bS = *reinterpret_cast<const bf16x8*>(
          &Sop[w][l15 * 128 + ((t * 32 + l4 * 8) ^ swz)]);
#pragma unroll
      for (int m = 0; m < 4; ++m) {
        const bf16x8 aQ = *reinterpret_cast<const bf16x8*>(
            &Qgl[buf][(m * 16 + l15) * 128 + ((t * 32 + l4 * 8) ^ swz)]);
        acc_o[m] = __builtin_amdgcn_mfma_f32_16x16x32_bf16(aQ, bS, acc_o[m], 0, 0, 0);
      }
    }
#pragma unroll
    for (int t2 = 0; t2 < 2; ++t2) {
      const bf16x8 bD = *reinterpret_cast<const bf16x8*>(
          &dLs[w][l15 * 64 + ((t2 * 32 + l4 * 8) ^ swz)]);
#pragma unroll
      for (int m = 0; m < 4; ++m) {
        const bf16x8 aB = *reinterpret_cast<const bf16x8*>(
            &Bl[buf][(m * 16 + l15) * 64 + ((t2 * 32 + l4 * 8) ^ swz)]);
        acc_o[m] = __builtin_amdgcn_mfma_f32_16x16x32_bf16(aB, bD, acc_o[m], 0, 0, 0);
      }
    }
    float* ob = Og + (size_t)(ch * 64) * 4096 + (size_t)vh * 128 + cg + l15;
#pragma unroll
    for (int m = 0; m < 4; ++m)
#pragma unroll
      for (int r = 0; r < 4; ++r)
        ob[(size_t)(m * 16 + l4 * 4 + r) * 4096] = acc_o[m][r];
    // op3: S = ge*S + Kᵀλ @ δ
    const float ge = gendg[ch * 32 + vh];
#pragma unroll
    for (int f = 0; f < 8; ++f) {
      accS[f][0] *= ge; accS[f][1] *= ge; accS[f][2] *= ge; accS[f][3] *= ge;
    }
#pragma unroll
    for (int t2 = 0; t2 < 2; ++t2) {
      const bf16x8 bD = *reinterpret_cast<const bf16x8*>(
          &dLs[w][l15 * 64 + ((t2 * 32 + l4 * 8) ^ swz)]);
#pragma unroll
      for (int f = 0; f < 8; ++f) {
        const bf16x8 aK = *reinterpret_cast<const bf16x8*>(
            &KTl[buf][(f * 16 + l15) * 64 + ((t2 * 32 + l4 * 8) ^ swz)]);
        accS[f] = __builtin_amdgcn_mfma_f32_16x16x32_bf16(aK, bD, accS[f], 0, 0, 0);
      }
    }
#pragma unroll
    for (int f = 0; f < 8; ++f)
      *reinterpret_cast<ushort4*>(&Sop[w][l15 * 128 + ((f * 16 + l4 * 4) ^ swz)]) =
          pack4(accS[f]);
    __syncthreads();
    buf ^= 1;
  }
#undef STAGE
#undef UPREF
}

// --- gfuse: gate_norm (0..8191) + transpose W_out (8192..10239) --------------
__global__ __launch_bounds__(256) void gfuse(const float* __restrict__ O,
                                             const __hip_bfloat16* __restrict__ qkvz,
                                             const float* __restrict__ norm_w,
                                             __hip_bfloat16* __restrict__ G,
                                             const float* __restrict__ Wo,
                                             __hip_bfloat16* __restrict__ Wot) {
  __shared__ float tl[64][65];
  const int bid = blockIdx.x;
  const int tid = threadIdx.x;
  if (bid < 8192) {
    const int vh = (bid & 7) * 4 + (tid >> 6);
    const int t = bid >> 3, l = tid & 63;
    const size_t ob = (size_t)t * 4096 + vh * 128;
    const size_t zb = (size_t)t * NQKVZ + (vh >> 1) * 768 + 512 + (vh & 1) * 128;
    const float o0 = O[ob + l], o1 = O[ob + l + 64];
    const float z0 = __bfloat162float(qkvz[zb + l]);
    const float z1 = __bfloat162float(qkvz[zb + l + 64]);
    const float g0 = o0 * z0 / (1.f + expf(-z0));
    const float g1 = o1 * z1 / (1.f + expf(-z1));
    float ss = g0 * g0 + g1 * g1;
#pragma unroll
    for (int off = 32; off; off >>= 1) ss += __shfl_xor(ss, off);
    const float rr = rsqrtf(ss * (1.f / 128.f) + 1e-6f);
    G[ob + l] = __float2bfloat16(g0 * rr * norm_w[l]);
    G[ob + l + 64] = __float2bfloat16(g1 * rr * norm_w[l + 64]);
    return;
  }
  const int b = bid - 8192;
  const int n0 = (b & 31) * 64, k0 = (b >> 5) * 64;
  const int N = 2048, K = 4096;
  const int rc = tid & 15, rr2 = tid >> 4;
#pragma unroll
  for (int i = 0; i < 4; ++i) {
    const int k = rr2 + 16 * i;
    const float4 v = *reinterpret_cast<const float4*>(&Wo[(size_t)(k0 + k) * N + n0 + rc * 4]);
    tl[k][rc * 4 + 0] = v.x;
    tl[k][rc * 4 + 1] = v.y;
    tl[k][rc * 4 + 2] = v.z;
    tl[k][rc * 4 + 3] = v.w;
  }
  __syncthreads();
  const int wcx = tid & 7, wry = tid >> 3;
#pragma unroll
  for (int i = 0; i < 2; ++i) {
    const int n = wry + 32 * i;
    uint u[8];
#pragma unroll
    for (int j = 0; j < 8; ++j)
      u[j] = __bfloat16_as_ushort(__float2bfloat16(tl[wcx * 8 + j][n]));
    uint4 o;
    o.x = u[0] | (u[1] << 16);
    o.y = u[2] | (u[3] << 16);
    o.z = u[4] | (u[5] << 16);
    o.w = u[6] | (u[7] << 16);
    *reinterpret_cast<uint4*>((void*)&Wot[(size_t)(n0 + n) * K + k0 + wcx * 8]) = o;
  }
}

extern "C" void kernel_launch(void* const* d_in, const int* in_sizes, int n_in,
                              void* d_out, int out_size, void* d_ws, size_t ws_size,
                              hipStream_t stream) {
  const float* X = (const float*)d_in[0];
  const float* W_qkvz = (const float*)d_in[1];
  const float* W_ba = (const float*)d_in[2];
  const float* conv_w = (const float*)d_in[3];
  const float* dt_bias = (const float*)d_in[4];
  const float* A_log = (const float*)d_in[5];
  const float* norm_w = (const float*)d_in[6];
  const float* W_out = (const float*)d_in[7];
  float* out = (float*)d_out;

  float* ws = (float*)d_ws;
  float* qkvz = ws;                                // region sized 12,582,912 f (used as bf16)
  float* P = qkvz + (size_t)T_LEN * NQKVZ;         //    262,144 f (ba partials)
  float* QK = P + 262144;                          //  4,194,304 f
  float* V = QK + (size_t)T_LEN * 4096;            //  4,194,304 f
  float* U_f = V + (size_t)T_LEN * 4096;           //  4,194,304 f (bf16 U uses half)
  float* Wb_f = U_f + (size_t)NCHUNK * 32 * 64 * 128; // 2,097,152 f
  float* KT_f = Wb_f + 2097152;                    //  2,097,152 f
  float* Qg_f = KT_f + 2097152;                    //  2,097,152 f
  float* Bb_f = Qg_f + 2097152;                    //  1,048,576 f (bf16 x 2.10M)
  float* gg = Bb_f + 1048576;                      //     32,768 f
  float* bet = gg + 32768;                         //     32,768 f
  float* gend = bet + 32768;                       //        512 f

  __hip_bfloat16* qkvzb = (__hip_bfloat16*)qkvz;   // bf16 qkvz
  __hip_bfloat16* Ub = (__hip_bfloat16*)U_f;
  __hip_bfloat16* Wb = (__hip_bfloat16*)Wb_f;
  __hip_bfloat16* KTb = (__hip_bfloat16*)KT_f;
  __hip_bfloat16* Qgb = (__hip_bfloat16*)Qg_f;
  __hip_bfloat16* Bb = (__hip_bfloat16*)Bb_f;
  // lifetime aliases:
  __hip_bfloat16* Wqkvz_t = (__hip_bfloat16*)V;    // spans V+U+Wb+KT (dead after 1st gemm)
  __hip_bfloat16* Xb = (__hip_bfloat16*)Qg_f;      // dead after 1st gemm
  __hip_bfloat16* Gb = (__hip_bfloat16*)Bb_f;      // Bb dead after phaseB
  __hip_bfloat16* Wout_t = (__hip_bfloat16*)qkvz;  // qkvz dead after gfuse's gate part
  float* O = V;                                    // V dead after phase1
  __hip_bfloat16* Pout = (__hip_bfloat16*)U_f;     // U+Wb+KT dead after phaseB

  preba<<<dim3(2048 + 256), 256, 0, stream>>>(X, Xb, W_ba, P);
  wtrans<<<dim3(6144), 256, 0, stream>>>(W_qkvz, Wqkvz_t);
  gemm256<<<dim3(NQKVZ / 256, T_LEN / 256, 1), 512, 0, stream>>>(
      Xb, Wqkvz_t, qkvzb, T_LEN, NQKVZ, 2048, 2048);
  convs<<<dim3(4096 + 512 + 128), 256, 0, stream>>>(qkvzb, conv_w, QK, V, P,
                                                    dt_bias, A_log, gg, bet);
  phase1<<<dim3(HV_N, NCHUNK), 256, 0, stream>>>(QK, V, gg, bet, Ub, Wb, KTb, Qgb, Bb, gend);
  phaseB<<<dim3(HV_N, 4), 128, 0, stream>>>(Ub, Wb, KTb, Qgb, Bb, gend, O);
  gfuse<<<dim3(8192 + 2048), 256, 0, stream>>>(O, qkvzb, norm_w, Gb, W_out, Wout_t);
  gemm_bf16<<<dim3(2048 / 128, T_LEN / 128, 4), 256, 0, stream>>>(
      Gb, Wout_t, Pout, T_LEN, 2048, 1024, 4096);
  add4<<<dim3(T_LEN * 2048 / 4 / 256), 256, 0, stream>>>(Pout, out, T_LEN * 2048);
}

// Round 23
// 251.362 us; speedup vs baseline: 1.0393x; 1.0248x over previous
//
#include <hip/hip_runtime.h>
#include <hip/hip_bf16.h>
#include <math.h>

// Qwen3Next GatedDeltaNet — round 22: restore the best-measured config
// (251.5 µs): fused prep2 (cast X + W_qkvz transpose + ba GEMM), gemm256
// for the qkvz GEMM, gemm_bf16<128> z=4 bf16-partials + add4 for the
// out-GEMM. phase1/phaseB MFMA versions, bf16 intermediates throughout.

#define T_LEN 1024
#define HK_N 16
#define HV_N 32
#define NQKVZ 12288
#define CHUNK 64
#define NCHUNK 16

typedef __bf16 bf16x8 __attribute__((ext_vector_type(8)));
typedef float f32x4 __attribute__((ext_vector_type(4)));

__device__ __forceinline__ ushort4 pack4(const f32x4 v) {
  ushort4 o;
  o.x = __bfloat16_as_ushort(__float2bfloat16(v[0]));
  o.y = __bfloat16_as_ushort(__float2bfloat16(v[1]));
  o.z = __bfloat16_as_ushort(__float2bfloat16(v[2]));
  o.w = __bfloat16_as_ushort(__float2bfloat16(v[3]));
  return o;
}

// ---- 256x256 big-tile bf16 GEMM: C[M,N] = A[M,K] @ B[N,K]^T, bf16 out ------
// 512 thr = 8 waves (2M x 4N). BK=64. Double-buffered, 2-K-tile prefetch
// depth with counted vmcnt(8). All LDS reads complete (lgkmcnt(0)+barrier)
// before the buffer is restaged -> race-free by construction.
__global__ __launch_bounds__(512) void gemm256(const __hip_bfloat16* __restrict__ A,
                                               const __hip_bfloat16* __restrict__ B,
                                               __hip_bfloat16* __restrict__ C,
                                               int M, int N, int Klen) {
  __shared__ __align__(16) __hip_bfloat16 As[2][256 * 64];  // 32 KB x2
  __shared__ __align__(16) __hip_bfloat16 Bs[2][256 * 64];  // 32 KB x2
  const int tid = threadIdx.x;
  const int wid = tid >> 6, lane = tid & 63;
  const int wr = wid >> 2, wc = wid & 3;
  const int m0 = blockIdx.y * 256, n0 = blockIdx.x * 256;
  const int lrow = lane & 15, lk = lane >> 4;
  const int rswz = (lrow & 7) * 8;
  f32x4 acc[8][4] = {};
  const int nk = Klen >> 6;

#define GST(b_, kt_) do {                                                       \
    _Pragma("unroll") for (int it = 0; it < 4; ++it) {                          \
      const int c_ = it * 512 + tid;                                            \
      const int row_ = c_ >> 3;                                                 \
      const int col8_ = ((c_ & 7) ^ (row_ & 7)) * 8;                            \
      __builtin_amdgcn_global_load_lds(                                         \
          (const __attribute__((address_space(1))) void*)                       \
              (A + (size_t)(m0 + row_) * Klen + ((kt_) << 6) + col8_),          \
          (__attribute__((address_space(3))) void*)(&As[b_][c_ * 8]), 16, 0, 0);\
    }                                                                           \
    _Pragma("unroll") for (int it = 0; it < 4; ++it) {                          \
      const int c_ = it * 512 + tid;                                            \
      const int row_ = c_ >> 3;                                                 \
      const int col8_ = ((c_ & 7) ^ (row_ & 7)) * 8;                            \
      __builtin_amdgcn_global_load_lds(                                         \
          (const __attribute__((address_space(1))) void*)                       \
              (B + (size_t)(n0 + row_) * Klen + ((kt_) << 6) + col8_),          \
          (__attribute__((address_space(3))) void*)(&Bs[b_][c_ * 8]), 16, 0, 0);\
    }                                                                           \
  } while (0)

  GST(0, 0);
  GST(1, 1);
  int cur = 0;
  for (int t = 0; t < nk; ++t) {
    if (t < nk - 1) asm volatile("s_waitcnt vmcnt(8)" ::: "memory");
    else            asm volatile("s_waitcnt vmcnt(0)" ::: "memory");
    __builtin_amdgcn_s_barrier();      // tile t landed everywhere
    __builtin_amdgcn_sched_barrier(0);
    bf16x8 af[8], bfv[4];
    // ---- k-half 0: read frags, MFMA 32 ----
#pragma unroll
    for (int m = 0; m < 8; ++m)
      af[m] = *reinterpret_cast<const bf16x8*>(
          &As[cur][(wr * 128 + m * 16 + lrow) * 64 + ((lk * 8) ^ rswz)]);
#pragma unroll
    for (int n = 0; n < 4; ++n)
      bfv[n] = *reinterpret_cast<const bf16x8*>(
          &Bs[cur][(wc * 64 + n * 16 + lrow) * 64 + ((lk * 8) ^ rswz)]);
    __builtin_amdgcn_s_setprio(1);
#pragma unroll
    for (int m = 0; m < 8; ++m)
#pragma unroll
      for (int n = 0; n < 4; ++n)
        acc[m][n] = __builtin_amdgcn_mfma_f32_16x16x32_bf16(af[m], bfv[n], acc[m][n], 0, 0, 0);
    __builtin_amdgcn_s_setprio(0);
    // ---- k-half 1: read frags into regs, THEN release the buffer ----
#pragma unroll
    for (int m = 0; m < 8; ++m)
      af[m] = *reinterpret_cast<const bf16x8*>(
          &As[cur][(wr * 128 + m * 16 + lrow) * 64 + ((32 + lk * 8) ^ rswz)]);
#pragma unroll
    for (int n = 0; n < 4; ++n)
      bfv[n] = *reinterpret_cast<const bf16x8*>(
          &Bs[cur][(wc * 64 + n * 16 + lrow) * 64 + ((32 + lk * 8) ^ rswz)]);
    asm volatile("s_waitcnt lgkmcnt(0)" ::: "memory");
    __builtin_amdgcn_sched_barrier(0);
    __builtin_amdgcn_s_barrier();      // all waves' reads of buf[cur] done
    __builtin_amdgcn_sched_barrier(0);
    if (t + 2 < nk) GST(cur, t + 2);   // restage freed buffer (overlaps MFMA)
    __builtin_amdgcn_s_setprio(1);
#pragma unroll
    for (int m = 0; m < 8; ++m)
#pragma unroll
      for (int n = 0; n < 4; ++n)
        acc[m][n] = __builtin_amdgcn_mfma_f32_16x16x32_bf16(af[m], bfv[n], acc[m][n], 0, 0, 0);
    __builtin_amdgcn_s_setprio(0);
    cur ^= 1;
  }
#undef GST
#pragma unroll
  for (int m = 0; m < 8; ++m)
#pragma unroll
    for (int n = 0; n < 4; ++n)
#pragma unroll
      for (int r = 0; r < 4; ++r)
        C[(size_t)(m0 + wr * 128 + m * 16 + lk * 4 + r) * N + n0 + wc * 64 + n * 16 + lrow] =
            __float2bfloat16(acc[m][n][r]);
}

// ------- bf16 MFMA GEMM (128-tile, proven): C (z-partials) = A @ B^T ---------
template <int BM, bool BF16OUT>
__global__ __launch_bounds__(256) void gemm_bf16(const __hip_bfloat16* __restrict__ A,
                                                 const __hip_bfloat16* __restrict__ B,
                                                 void* __restrict__ Cv,
                                                 int M, int N, int Klen, int ldk) {
  constexpr int AITS = BM / 32;
  constexpr int MF = BM / 32;
  __shared__ __align__(16) __hip_bfloat16 As[2][BM * 64];
  __shared__ __align__(16) __hip_bfloat16 Bs[2][128 * 64];
  const int tid = threadIdx.x;
  const int wid = tid >> 6, lane = tid & 63;
  const int wr = wid >> 1, wc = wid & 1;
  const int m0 = blockIdx.y * BM, n0 = blockIdx.x * 128;
  const size_t kbase = (size_t)blockIdx.z * Klen;
  const int lrow = lane & 15, lk = lane >> 4;
  const int rswz = (lrow & 7) * 8;
  f32x4 acc[MF][4] = {};
  const int nk = Klen >> 6;

#define GSTAGE(b_, k0_) do {                                                    \
    _Pragma("unroll") for (int it = 0; it < AITS; ++it) {                       \
      const int c_ = it * 256 + tid;                                            \
      const int row_ = c_ >> 3;                                                 \
      const int col8_ = ((c_ & 7) ^ (row_ & 7)) * 8;                            \
      __builtin_amdgcn_global_load_lds(                                         \
          (const __attribute__((address_space(1))) void*)                       \
              (A + (size_t)(m0 + row_) * ldk + kbase + (k0_) + col8_),          \
          (__attribute__((address_space(3))) void*)(&As[b_][it * 2048 + tid * 8]), 16, 0, 0); \
    }                                                                           \
    _Pragma("unroll") for (int it = 0; it < 4; ++it) {                          \
      const int c_ = it * 256 + tid;                                            \
      const int row_ = c_ >> 3;                                                 \
      const int col8_ = ((c_ & 7) ^ (row_ & 7)) * 8;                            \
      __builtin_amdgcn_global_load_lds(                                         \
          (const __attribute__((address_space(1))) void*)                       \
              (B + (size_t)(n0 + row_) * ldk + kbase + (k0_) + col8_),          \
          (__attribute__((address_space(3))) void*)(&Bs[b_][it * 2048 + tid * 8]), 16, 0, 0); \
    }                                                                           \
  } while (0)

  GSTAGE(0, 0);
  int buf = 0;
  for (int k = 0; k < nk; ++k) {
    if (k + 1 < nk) {
      GSTAGE(buf ^ 1, (k + 1) << 6);
      if constexpr (BM == 128) asm volatile("s_waitcnt vmcnt(8)" ::: "memory");
      else                     asm volatile("s_waitcnt vmcnt(6)" ::: "memory");
    } else {
      asm volatile("s_waitcnt vmcnt(0)" ::: "memory");
    }
    __builtin_amdgcn_s_barrier();
    __builtin_amdgcn_sched_barrier(0);
#pragma unroll
    for (int kk = 0; kk < 2; ++kk) {
      bf16x8 af[MF], bfv[4];
#pragma unroll
      for (int m = 0; m < MF; ++m)
        af[m] = *reinterpret_cast<const bf16x8*>(
            &As[buf][(wr * (BM / 2) + m * 16 + lrow) * 64 + ((kk * 32 + lk * 8) ^ rswz)]);
#pragma unroll
      for (int n = 0; n < 4; ++n)
        bfv[n] = *reinterpret_cast<const bf16x8*>(
            &Bs[buf][(wc * 64 + n * 16 + lrow) * 64 + ((kk * 32 + lk * 8) ^ rswz)]);
#pragma unroll
      for (int m = 0; m < MF; ++m)
#pragma unroll
        for (int n = 0; n < 4; ++n)
          acc[m][n] = __builtin_amdgcn_mfma_f32_16x16x32_bf16(af[m], bfv[n], acc[m][n], 0, 0, 0);
    }
    __builtin_amdgcn_sched_barrier(0);
    __builtin_amdgcn_s_barrier();
    buf ^= 1;
  }
#undef GSTAGE
  if constexpr (BF16OUT) {
    __hip_bfloat16* Cz = (__hip_bfloat16*)Cv + (size_t)blockIdx.z * M * N;
#pragma unroll
    for (int m = 0; m < MF; ++m)
#pragma unroll
      for (int n = 0; n < 4; ++n)
#pragma unroll
        for (int r = 0; r < 4; ++r)
          Cz[(size_t)(m0 + wr * (BM / 2) + m * 16 + lk * 4 + r) * N + n0 + wc * 64 + n * 16 + lrow] =
              __float2bfloat16(acc[m][n][r]);
  } else {
    float* Cz = (float*)Cv + (size_t)blockIdx.z * M * N;
#pragma unroll
    for (int m = 0; m < MF; ++m)
#pragma unroll
      for (int n = 0; n < 4; ++n)
#pragma unroll
        for (int r = 0; r < 4; ++r)
          Cz[(size_t)(m0 + wr * (BM / 2) + m * 16 + lk * 4 + r) * N + n0 + wc * 64 + n * 16 + lrow] =
              acc[m][n][r];
  }
}

// -------- out = sum of 4 bf16 K-slice partials (fp32 accumulate) -------------
__global__ void add4(const __hip_bfloat16* __restrict__ P, float* __restrict__ out, int n) {
  const int i = (blockIdx.x * 256 + threadIdx.x) * 4;
  if (i < n) {
    float s[4] = {0.f, 0.f, 0.f, 0.f};
#pragma unroll
    for (int z = 0; z < 4; ++z) {
      const ushort4 v = *reinterpret_cast<const ushort4*>(P + (size_t)z * n + i);
      s[0] += __bfloat162float(__ushort_as_bfloat16(v.x));
      s[1] += __bfloat162float(__ushort_as_bfloat16(v.y));
      s[2] += __bfloat162float(__ushort_as_bfloat16(v.z));
      s[3] += __bfloat162float(__ushort_as_bfloat16(v.w));
    }
    *reinterpret_cast<float4*>(out + i) = make_float4(s[0], s[1], s[2], s[3]);
  }
}

// --- prep2: cast X (0..2047) + transpose W_qkvz (2048..8191) + ba (8192..) ---
__global__ __launch_bounds__(256) void prep2(const float* __restrict__ X,
                                             __hip_bfloat16* __restrict__ Xb,
                                             const float* __restrict__ Wq,
                                             __hip_bfloat16* __restrict__ Wqt,
                                             const float* __restrict__ Wba,
                                             float* __restrict__ P) {
  __shared__ __align__(16) float smem[16 * 512];  // 32 KB union
  const int bid = blockIdx.x;
  const int tid = threadIdx.x;
  if (bid < 2048) {
    const int i = (bid * 256 + tid) * 4;
    const float4 v = *reinterpret_cast<const float4*>(X + i);
    ushort4 o;
    o.x = __bfloat16_as_ushort(__float2bfloat16(v.x));
    o.y = __bfloat16_as_ushort(__float2bfloat16(v.y));
    o.z = __bfloat16_as_ushort(__float2bfloat16(v.z));
    o.w = __bfloat16_as_ushort(__float2bfloat16(v.w));
    *reinterpret_cast<ushort4*>((void*)(Xb + i)) = o;
  } else if (bid < 8192) {
    // transpose W_qkvz [2048, 12288] -> bf16 [12288, 2048], 64x64 tiles
    float (*tl)[65] = reinterpret_cast<float (*)[65]>(smem);
    const int b = bid - 2048;
    const int n0 = (b % 192) * 64, k0 = (b / 192) * 64;
    const int N = NQKVZ, K = 2048;
    const int rc = tid & 15, rr = tid >> 4;
#pragma unroll
    for (int i = 0; i < 4; ++i) {
      const int k = rr + 16 * i;
      const float4 v = *reinterpret_cast<const float4*>(&Wq[(size_t)(k0 + k) * N + n0 + rc * 4]);
      tl[k][rc * 4 + 0] = v.x;
      tl[k][rc * 4 + 1] = v.y;
      tl[k][rc * 4 + 2] = v.z;
      tl[k][rc * 4 + 3] = v.w;
    }
    __syncthreads();
    const int wcx = tid & 7, wry = tid >> 3;
#pragma unroll
    for (int i = 0; i < 2; ++i) {
      const int n = wry + 32 * i;
      uint u[8];
#pragma unroll
      for (int j = 0; j < 8; ++j)
        u[j] = __bfloat16_as_ushort(__float2bfloat16(tl[wcx * 8 + j][n]));
      uint4 o;
      o.x = u[0] | (u[1] << 16);
      o.y = u[2] | (u[3] << 16);
      o.z = u[4] | (u[5] << 16);
      o.w = u[6] | (u[7] << 16);
      *reinterpret_cast<uint4*>((void*)&Wqt[(size_t)(n0 + n) * K + k0 + wcx * 8]) = o;
    }
  } else {
    // split-K ba GEMM: X[1024,2048] @ Wba[2048,64] -> P[4][1024][64]
    float (*Xs)[512] = reinterpret_cast<float (*)[512]>(smem);
    const int b = bid - 8192;
    const int tt = b & 63, ks = b >> 6;
    const int c = tid & 63, r4 = tid >> 6;
    const float* xsrc = X + (size_t)(tt * 16) * 2048 + ks * 512;
#pragma unroll
    for (int u = 0; u < 8; ++u) {
      const int flat = (u * 256 + tid) * 4;
      const int r = flat >> 9, k = flat & 511;
      *reinterpret_cast<float4*>(&Xs[r][k]) =
          *reinterpret_cast<const float4*>(&xsrc[(size_t)r * 2048 + k]);
    }
    __syncthreads();
    float acc[4] = {};
    const float* wp = Wba + (size_t)(ks * 512) * 64 + c;
    for (int k = 0; k < 512; k += 8) {
      float w[8];
#pragma unroll
      for (int u = 0; u < 8; ++u) w[u] = wp[(size_t)(k + u) * 64];
#pragma unroll
      for (int u = 0; u < 8; ++u)
#pragma unroll
        for (int i = 0; i < 4; ++i)
          acc[i] = fmaf(Xs[r4 * 4 + i][k + u], w[u], acc[i]);
    }
    float* pp = P + ((size_t)ks * 1024 + tt * 16 + r4 * 4) * 64 + c;
#pragma unroll
    for (int i = 0; i < 4; ++i) pp[(size_t)i * 64] = acc[i];
  }
}

// --- convs: conv_qk_norm (0..4095) + conv_v (4096..4607) + gb (4608..4735) ---
__global__ __launch_bounds__(256) void convs(const __hip_bfloat16* __restrict__ qkvz,
                                             const float* __restrict__ conv_w,
                                             float* __restrict__ QK,
                                             float* __restrict__ V,
                                             const float* __restrict__ P,
                                             const float* __restrict__ dt_bias,
                                             const float* __restrict__ A_log,
                                             float* __restrict__ gg,
                                             float* __restrict__ bet) {
  const int bid = blockIdx.x;
  const int tid = threadIdx.x;
  if (bid < 4096) {
    const int kh = bid & 15;
    const int t = (bid >> 4) * 4 + (tid >> 6);
    const int l = tid & 63;
    const int cols[4] = {kh * 768 + l, kh * 768 + l + 64,
                         kh * 768 + 128 + l, kh * 768 + 128 + l + 64};
    const int chs[4] = {kh * 128 + l, kh * 128 + l + 64,
                        2048 + kh * 128 + l, 2048 + kh * 128 + l + 64};
    float y[4];
#pragma unroll
    for (int j = 0; j < 4; ++j) {
      const float* wp = &conv_w[chs[j] * 4];
      float acc = 0.f;
#pragma unroll
      for (int s = 0; s < 4; ++s) {
        const int tt = t - 3 + s;
        if (tt >= 0)
          acc = fmaf(__bfloat162float(qkvz[(size_t)tt * NQKVZ + cols[j]]), wp[s], acc);
      }
      y[j] = acc / (1.f + expf(-acc));  // silu
    }
    float sq = y[0] * y[0] + y[1] * y[1];
    float sk = y[2] * y[2] + y[3] * y[3];
#pragma unroll
    for (int off = 32; off; off >>= 1) {
      sq += __shfl_xor(sq, off);
      sk += __shfl_xor(sk, off);
    }
    const float rq = rsqrtf(sq + 1e-6f) * 0.08838834764831845f;  // * DK^-0.5
    const float rk = rsqrtf(sk + 1e-6f);
    const size_t qb = (size_t)t * 4096 + kh * 128;
    QK[qb + l] = y[0] * rq;
    QK[qb + l + 64] = y[1] * rq;
    QK[qb + 2048 + l] = y[2] * rk;
    QK[qb + 2048 + l + 64] = y[3] * rk;
  } else if (bid < 4608) {
    const int b = bid - 4096;
    const int c2 = (b & 15) * 256 + tid;
    const int vh = c2 >> 7;
    const int col = (vh >> 1) * 768 + 256 + (vh & 1) * 128 + (c2 & 127);
    const int t0 = (b >> 4) * 32;
    const float4 w = *reinterpret_cast<const float4*>(&conv_w[(4096 + c2) * 4]);
    float x0, x1, x2;
    if (t0 == 0) {
      x0 = 0.f; x1 = 0.f; x2 = 0.f;
    } else {
      x0 = __bfloat162float(qkvz[(size_t)(t0 - 3) * NQKVZ + col]);
      x1 = __bfloat162float(qkvz[(size_t)(t0 - 2) * NQKVZ + col]);
      x2 = __bfloat162float(qkvz[(size_t)(t0 - 1) * NQKVZ + col]);
    }
#pragma unroll 4
    for (int tt = 0; tt < 32; ++tt) {
      const int t = t0 + tt;
      const float x3 = __bfloat162float(qkvz[(size_t)t * NQKVZ + col]);
      float acc = x0 * w.x;
      acc = fmaf(x1, w.y, acc);
      acc = fmaf(x2, w.z, acc);
      acc = fmaf(x3, w.w, acc);
      V[(size_t)t * 4096 + c2] = acc / (1.f + expf(-acc));
      x0 = x1; x1 = x2; x2 = x3;
    }
  } else {
    const int idx = (bid - 4608) * 256 + tid;  // t*32 + vh
    const int t = idx >> 5, vh = idx & 31;
    const int cb = (vh >> 1) * 4 + (vh & 1);
    float b = 0.f, a = 0.f;
#pragma unroll
    for (int s = 0; s < 4; ++s) {
      b += P[((size_t)s * 1024 + t) * 64 + cb];
      a += P[((size_t)s * 1024 + t) * 64 + cb + 2];
    }
    const float x = a + dt_bias[vh];
    const float sp = (x > 20.f) ? x : log1pf(expf(x));
    gg[idx] = -expf(A_log[vh]) * sp;
    bet[idx] = 1.f / (1.f + expf(-b));
  }
}

// ---------------- phase 1: per (chunk, v-head) intra-chunk precompute --------
__global__ __launch_bounds__(256, 2) void phase1(
    const float* __restrict__ QK, const float* __restrict__ V,
    const float* __restrict__ g, const float* __restrict__ bet,
    __hip_bfloat16* __restrict__ Ub, __hip_bfloat16* __restrict__ Wb,
    __hip_bfloat16* __restrict__ KTb, __hip_bfloat16* __restrict__ Qgb,
    __hip_bfloat16* __restrict__ Bb, float* __restrict__ gend) {
  const int vh = blockIdx.x, ch = blockIdx.y, kh = vh >> 1;
  const int tid = threadIdx.x;
  const int t0 = ch * CHUNK;
  __shared__ __align__(16) __hip_bfloat16 KbS[64][128];
  __shared__ __align__(16) __hip_bfloat16 QbS[64][128];
  __shared__ __align__(16) float Al[64][68];
  __shared__ float bs[64], gams[64], bets[64], lams[64];

  const int row = tid >> 2;
  const size_t hb = (size_t)ch * 32 + vh;
  {
    const int cc = (tid & 3) * 32;
    const float* ksrc = &QK[(size_t)(t0 + row) * 4096 + 2048 + kh * 128 + cc];
    const float* qsrc = &QK[(size_t)(t0 + row) * 4096 + kh * 128 + cc];
#pragma unroll
    for (int u = 0; u < 32; u += 4) {
      const float4 kv = *reinterpret_cast<const float4*>(ksrc + u);
      const float4 qv = *reinterpret_cast<const float4*>(qsrc + u);
      const int d0 = cc + u;
      const int sidx = (d0 & 7) | ((((d0 >> 3) ^ (row & 7)) & 15) << 3);
      ushort4 kk4, qq4;
      kk4.x = __bfloat16_as_ushort(__float2bfloat16(kv.x));
      kk4.y = __bfloat16_as_ushort(__float2bfloat16(kv.y));
      kk4.z = __bfloat16_as_ushort(__float2bfloat16(kv.z));
      kk4.w = __bfloat16_as_ushort(__float2bfloat16(kv.w));
      qq4.x = __bfloat16_as_ushort(__float2bfloat16(qv.x));
      qq4.y = __bfloat16_as_ushort(__float2bfloat16(qv.y));
      qq4.z = __bfloat16_as_ushort(__float2bfloat16(qv.z));
      qq4.w = __bfloat16_as_ushort(__float2bfloat16(qv.w));
      *reinterpret_cast<ushort4*>(&KbS[row][sidx]) = kk4;
      *reinterpret_cast<ushort4*>(&QbS[row][sidx]) = qq4;
    }
  }
  if (tid < 64) {
    float b = g[(size_t)(t0 + tid) * 32 + vh];
#pragma unroll
    for (int off = 1; off < 64; off <<= 1) {
      const float o = __shfl_up(b, off);
      if (tid >= off) b += o;
    }
    const float b63 = __shfl(b, 63);
    const float ga = expf(b);
    bs[tid] = b;
    gams[tid] = ga;
    lams[tid] = expf(b63 - b);
    bets[tid] = bet[(size_t)(t0 + tid) * 32 + vh];
    if (tid == 63) gend[ch * 32 + vh] = ga;
  }
  __syncthreads();
  {
    const int i = tid & 63;
    const float li = lams[i];
    __hip_bfloat16* kt = &KTb[hb * 128 * 64];
    const int dbase = (tid >> 6) * 32;
#pragma unroll
    for (int dd = 0; dd < 32; ++dd) {
      const int d = dbase + dd;
      const int sidx = (d & 7) | ((((d >> 3) ^ (i & 7)) & 15) << 3);
      kt[(size_t)d * 64 + (i ^ ((d & 7) << 3))] =
          __float2bfloat16(li * __bfloat162float(KbS[i][sidx]));
    }
  }
  {
    const float gai = gams[row];
    __hip_bfloat16* qg = &Qgb[(hb * 64 + row) * 128];
    const int cc = (tid & 3) * 32;
#pragma unroll
    for (int u = 0; u < 32; u += 4) {
      const int d0 = cc + u;
      const int sidx = (d0 & 7) | ((((d0 >> 3) ^ (row & 7)) & 15) << 3);
      ushort4 qq;
      qq.x = __bfloat16_as_ushort(__float2bfloat16(gai * __bfloat162float(QbS[row][sidx + 0])));
      qq.y = __bfloat16_as_ushort(__float2bfloat16(gai * __bfloat162float(QbS[row][sidx + 1])));
      qq.z = __bfloat16_as_ushort(__float2bfloat16(gai * __bfloat162float(QbS[row][sidx + 2])));
      qq.w = __bfloat16_as_ushort(__float2bfloat16(gai * __bfloat162float(QbS[row][sidx + 3])));
      *reinterpret_cast<ushort4*>(&qg[d0 ^ ((row & 7) << 3)]) = qq;
    }
  }
  {
    const int w = tid >> 6, lane = tid & 63;
    const int lrow = lane & 15, lk = lane >> 4;
    bf16x8 af[4], qf[4];
#pragma unroll
    for (int kk = 0; kk < 4; ++kk) {
      const int c = ((kk * 4 + lk) ^ (lrow & 7)) * 8;
      af[kk] = *reinterpret_cast<const bf16x8*>(&KbS[w * 16 + lrow][c]);
      qf[kk] = *reinterpret_cast<const bf16x8*>(&QbS[w * 16 + lrow][c]);
    }
#pragma unroll
    for (int n = 0; n < 4; ++n) {
      f32x4 aA = {}, aB = {};
#pragma unroll
      for (int kk = 0; kk < 4; ++kk) {
        const bf16x8 bf = *reinterpret_cast<const bf16x8*>(
            &KbS[n * 16 + lrow][((kk * 4 + lk) ^ (lrow & 7)) * 8]);
        aA = __builtin_amdgcn_mfma_f32_16x16x32_bf16(af[kk], bf, aA, 0, 0, 0);
        aB = __builtin_amdgcn_mfma_f32_16x16x32_bf16(qf[kk], bf, aB, 0, 0, 0);
      }
      __hip_bfloat16* Bout = &Bb[hb * 64 * 64];
#pragma unroll
      for (int r = 0; r < 4; ++r) {
        const int i = w * 16 + lk * 4 + r;
        const int j = n * 16 + lrow;
        const float dec = expf(bs[i] - bs[j]);
        Al[i][j] = (j < i) ? bets[i] * dec * aA[r] : 0.f;
        Bout[(size_t)i * 64 + (j ^ ((i & 7) << 3))] =
            __float2bfloat16((j <= i) ? dec * aB[r] : 0.f);
      }
    }
  }
  __syncthreads();
  {
    const int cc = tid;
    float x[64];
    const bool isV = cc < 128;
    const float* src = isV ? &V[(size_t)t0 * 4096 + vh * 128 + cc]
                           : &QK[(size_t)t0 * 4096 + 2048 + kh * 128 + (cc - 128)];
#pragma unroll
    for (int i = 0; i < 64; ++i) {
      const float sc = isV ? bets[i] : bets[i] * gams[i];
      x[i] = sc * src[(size_t)i * 4096];
    }
#pragma unroll
    for (int i = 1; i < 64; ++i) {
      float s0 = 0.f, s1 = 0.f, s2 = 0.f, s3 = 0.f;
      int j = 0;
#pragma unroll
      for (; j + 4 <= i; j += 4) {
        const float4 a = *reinterpret_cast<const float4*>(&Al[i][j]);
        s0 = fmaf(a.x, x[j], s0);
        s1 = fmaf(a.y, x[j + 1], s1);
        s2 = fmaf(a.z, x[j + 2], s2);
        s3 = fmaf(a.w, x[j + 3], s3);
      }
#pragma unroll
      for (; j < i; ++j) s0 = fmaf(Al[i][j], x[j], s0);
      x[i] -= (s0 + s1) + (s2 + s3);
    }
    if (isV) {
      __hip_bfloat16* dst = &Ub[hb * 64 * 128 + cc];
#pragma unroll
      for (int i = 0; i < 64; ++i) dst[(size_t)i * 128] = __float2bfloat16(x[i]);
    } else {
      const int d = cc - 128;
      __hip_bfloat16* dst = &Wb[hb * 64 * 128];
#pragma unroll
      for (int i = 0; i < 64; ++i)
        dst[(size_t)i * 128 + (d ^ ((i & 7) << 3))] = __float2bfloat16(-x[i]);
    }
  }
}

// ---------------- phaseB: serial MFMA state propagation ----------------------
__global__ __launch_bounds__(128) void phaseB(
    const __hip_bfloat16* __restrict__ Ug, const __hip_bfloat16* __restrict__ Wb,
    const __hip_bfloat16* __restrict__ KTb, const __hip_bfloat16* __restrict__ Qgb,
    const __hip_bfloat16* __restrict__ Bb, const float* __restrict__ gendg,
    float* __restrict__ Og) {
  const int vh = blockIdx.x, slice = blockIdx.y;
  const int tid = threadIdx.x, lane = tid & 63, w = tid >> 6;
  const int l15 = lane & 15, l4 = lane >> 4;
  const int cg = slice * 32 + w * 16;
  const int swz = (l15 & 7) << 3;

  __shared__ __hip_bfloat16 Wl[2][8192];
  __shared__ __hip_bfloat16 KTl[2][8192];
  __shared__ __hip_bfloat16 Qgl[2][8192];
  __shared__ __hip_bfloat16 Bl[2][4096];
  __shared__ __hip_bfloat16 Sop[2][2048];
  __shared__ __hip_bfloat16 dLs[2][1024];

  f32x4 accS[8] = {};
  for (int x = lane; x < 1024; x += 64) reinterpret_cast<uint*>(Sop[w])[x] = 0;

  float ubuf[4][4];
#define STAGE(b_, c_) do {                                                      \
    const size_t hb_ = ((size_t)(c_) * 32 + vh);                                \
    _Pragma("unroll") for (int it = 0; it < 8; ++it) {                          \
      __builtin_amdgcn_global_load_lds(                                         \
          (const __attribute__((address_space(1))) void*)(Wb + hb_ * 8192 + it * 1024 + tid * 8), \
          (__attribute__((address_space(3))) void*)(&Wl[b_][it * 1024 + tid * 8]), 16, 0, 0); \
      __builtin_amdgcn_global_load_lds(                                         \
          (const __attribute__((address_space(1))) void*)(KTb + hb_ * 8192 + it * 1024 + tid * 8), \
          (__attribute__((address_space(3))) void*)(&KTl[b_][it * 1024 + tid * 8]), 16, 0, 0); \
      __builtin_amdgcn_global_load_lds(                                         \
          (const __attribute__((address_space(1))) void*)(Qgb + hb_ * 8192 + it * 1024 + tid * 8), \
          (__attribute__((address_space(3))) void*)(&Qgl[b_][it * 1024 + tid * 8]), 16, 0, 0); \
      if (it < 4)                                                               \
        __builtin_amdgcn_global_load_lds(                                       \
            (const __attribute__((address_space(1))) void*)(Bb + hb_ * 4096 + it * 1024 + tid * 8), \
            (__attribute__((address_space(3))) void*)(&Bl[b_][it * 1024 + tid * 8]), 16, 0, 0); \
    }                                                                           \
  } while (0)
#define UPREF(c_) do {                                                          \
    const __hip_bfloat16* up_ = Ug + ((size_t)(c_) * 32 + vh) * 64 * 128 + cg + l15; \
    _Pragma("unroll") for (int m_ = 0; m_ < 4; ++m_)                            \
      _Pragma("unroll") for (int r_ = 0; r_ < 4; ++r_)                          \
        ubuf[m_][r_] = __bfloat162float(up_[(size_t)(m_ * 16 + l4 * 4 + r_) * 128]); \
  } while (0)

  STAGE(0, 0);
  UPREF(0);
  __syncthreads();
  int buf = 0;
  for (int ch = 0; ch < NCHUNK; ++ch) {
    if (ch + 1 < NCHUNK) STAGE(buf ^ 1, ch + 1);
    f32x4 acc_d[4];
#pragma unroll
    for (int m = 0; m < 4; ++m) {
      f32x4 t;
      t[0] = ubuf[m][0]; t[1] = ubuf[m][1]; t[2] = ubuf[m][2]; t[3] = ubuf[m][3];
      acc_d[m] = t;
    }
    if (ch + 1 < NCHUNK) UPREF(ch + 1);
    // op1: delta = U + (-W) @ S
#pragma unroll
    for (int t = 0; t < 4; ++t) {
      const bf16x8 bS = *reinterpret_cast<const bf16x8*>(
          &Sop[w][l15 * 128 + ((t * 32 + l4 * 8) ^ swz)]);
#pragma unroll
      for (int m = 0; m < 4; ++m) {
        const bf16x8 aW = *reinterpret_cast<const bf16x8*>(
            &Wl[buf][(m * 16 + l15) * 128 + ((t * 32 + l4 * 8) ^ swz)]);
        acc_d[m] = __builtin_amdgcn_mfma_f32_16x16x32_bf16(aW, bS, acc_d[m], 0, 0, 0);
      }
    }
#pragma unroll
    for (int m = 0; m < 4; ++m)
      *reinterpret_cast<ushort4*>(&dLs[w][l15 * 64 + ((m * 16 + l4 * 4) ^ swz)]) =
          pack4(acc_d[m]);
    // opO: o = γq @ S + B @ δ
    f32x4 acc_o[4] = {};
#pragma unroll
    for (int t = 0; t < 4; ++t) {
      const bf16x8 bS = *reinterpret_cast<const bf16x8*>(
          &Sop[w][l15 * 128 + ((t * 32 + l4 * 8) ^ swz)]);
#pragma unroll
      for (int m = 0; m < 4; ++m) {
        const bf16x8 aQ = *reinterpret_cast<const bf16x8*>(
            &Qgl[buf][(m * 16 + l15) * 128 + ((t * 32 + l4 * 8) ^ swz)]);
        acc_o[m] = __builtin_amdgcn_mfma_f32_16x16x32_bf16(aQ, bS, acc_o[m], 0, 0, 0);
      }
    }
#pragma unroll
    for (int t2 = 0; t2 < 2; ++t2) {
      const bf16x8 bD = *reinterpret_cast<const bf16x8*>(
          &dLs[w][l15 * 64 + ((t2 * 32 + l4 * 8) ^ swz)]);
#pragma unroll
      for (int m = 0; m < 4; ++m) {
        const bf16x8 aB = *reinterpret_cast<const bf16x8*>(
            &Bl[buf][(m * 16 + l15) * 64 + ((t2 * 32 + l4 * 8) ^ swz)]);
        acc_o[m] = __builtin_amdgcn_mfma_f32_16x16x32_bf16(aB, bD, acc_o[m], 0, 0, 0);
      }
    }
    float* ob = Og + (size_t)(ch * 64) * 4096 + (size_t)vh * 128 + cg + l15;
#pragma unroll
    for (int m = 0; m < 4; ++m)
#pragma unroll
      for (int r = 0; r < 4; ++r)
        ob[(size_t)(m * 16 + l4 * 4 + r) * 4096] = acc_o[m][r];
    // op3: S = ge*S + Kᵀλ @ δ
    const float ge = gendg[ch * 32 + vh];
#pragma unroll
    for (int f = 0; f < 8; ++f) {
      accS[f][0] *= ge; accS[f][1] *= ge; accS[f][2] *= ge; accS[f][3] *= ge;
    }
#pragma unroll
    for (int t2 = 0; t2 < 2; ++t2) {
      const bf16x8 bD = *reinterpret_cast<const bf16x8*>(
          &dLs[w][l15 * 64 + ((t2 * 32 + l4 * 8) ^ swz)]);
#pragma unroll
      for (int f = 0; f < 8; ++f) {
        const bf16x8 aK = *reinterpret_cast<const bf16x8*>(
            &KTl[buf][(f * 16 + l15) * 64 + ((t2 * 32 + l4 * 8) ^ swz)]);
        accS[f] = __builtin_amdgcn_mfma_f32_16x16x32_bf16(aK, bD, accS[f], 0, 0, 0);
      }
    }
#pragma unroll
    for (int f = 0; f < 8; ++f)
      *reinterpret_cast<ushort4*>(&Sop[w][l15 * 128 + ((f * 16 + l4 * 4) ^ swz)]) =
          pack4(accS[f]);
    __syncthreads();
    buf ^= 1;
  }
#undef STAGE
#undef UPREF
}

// --- gfuse: gate_norm (0..8191) + transpose W_out (8192..10239) --------------
__global__ __launch_bounds__(256) void gfuse(const float* __restrict__ O,
                                             const __hip_bfloat16* __restrict__ qkvz,
                                             const float* __restrict__ norm_w,
                                             __hip_bfloat16* __restrict__ G,
                                             const float* __restrict__ Wo,
                                             __hip_bfloat16* __restrict__ Wot) {
  __shared__ float tl[64][65];
  const int bid = blockIdx.x;
  const int tid = threadIdx.x;
  if (bid < 8192) {
    const int vh = (bid & 7) * 4 + (tid >> 6);
    const int t = bid >> 3, l = tid & 63;
    const size_t ob = (size_t)t * 4096 + vh * 128;
    const size_t zb = (size_t)t * NQKVZ + (vh >> 1) * 768 + 512 + (vh & 1) * 128;
    const float o0 = O[ob + l], o1 = O[ob + l + 64];
    const float z0 = __bfloat162float(qkvz[zb + l]);
    const float z1 = __bfloat162float(qkvz[zb + l + 64]);
    const float g0 = o0 * z0 / (1.f + expf(-z0));
    const float g1 = o1 * z1 / (1.f + expf(-z1));
    float ss = g0 * g0 + g1 * g1;
#pragma unroll
    for (int off = 32; off; off >>= 1) ss += __shfl_xor(ss, off);
    const float rr = rsqrtf(ss * (1.f / 128.f) + 1e-6f);
    G[ob + l] = __float2bfloat16(g0 * rr * norm_w[l]);
    G[ob + l + 64] = __float2bfloat16(g1 * rr * norm_w[l + 64]);
    return;
  }
  const int b = bid - 8192;
  const int n0 = (b & 31) * 64, k0 = (b >> 5) * 64;
  const int N = 2048, K = 4096;
  const int rc = tid & 15, rr2 = tid >> 4;
#pragma unroll
  for (int i = 0; i < 4; ++i) {
    const int k = rr2 + 16 * i;
    const float4 v = *reinterpret_cast<const float4*>(&Wo[(size_t)(k0 + k) * N + n0 + rc * 4]);
    tl[k][rc * 4 + 0] = v.x;
    tl[k][rc * 4 + 1] = v.y;
    tl[k][rc * 4 + 2] = v.z;
    tl[k][rc * 4 + 3] = v.w;
  }
  __syncthreads();
  const int wcx = tid & 7, wry = tid >> 3;
#pragma unroll
  for (int i = 0; i < 2; ++i) {
    const int n = wry + 32 * i;
    uint u[8];
#pragma unroll
    for (int j = 0; j < 8; ++j)
      u[j] = __bfloat16_as_ushort(__float2bfloat16(tl[wcx * 8 + j][n]));
    uint4 o;
    o.x = u[0] | (u[1] << 16);
    o.y = u[2] | (u[3] << 16);
    o.z = u[4] | (u[5] << 16);
    o.w = u[6] | (u[7] << 16);
    *reinterpret_cast<uint4*>((void*)&Wot[(size_t)(n0 + n) * K + k0 + wcx * 8]) = o;
  }
}

extern "C" void kernel_launch(void* const* d_in, const int* in_sizes, int n_in,
                              void* d_out, int out_size, void* d_ws, size_t ws_size,
                              hipStream_t stream) {
  const float* X = (const float*)d_in[0];
  const float* W_qkvz = (const float*)d_in[1];
  const float* W_ba = (const float*)d_in[2];
  const float* conv_w = (const float*)d_in[3];
  const float* dt_bias = (const float*)d_in[4];
  const float* A_log = (const float*)d_in[5];
  const float* norm_w = (const float*)d_in[6];
  const float* W_out = (const float*)d_in[7];
  float* out = (float*)d_out;

  float* ws = (float*)d_ws;
  float* qkvz = ws;                                // region sized 12,582,912 f (used as bf16)
  float* P = qkvz + (size_t)T_LEN * NQKVZ;         //    262,144 f (ba partials)
  float* QK = P + 262144;                          //  4,194,304 f
  float* V = QK + (size_t)T_LEN * 4096;            //  4,194,304 f
  float* U_f = V + (size_t)T_LEN * 4096;           //  4,194,304 f (bf16 U uses half)
  float* Wb_f = U_f + (size_t)NCHUNK * 32 * 64 * 128; // 2,097,152 f
  float* KT_f = Wb_f + 2097152;                    //  2,097,152 f
  float* Qg_f = KT_f + 2097152;                    //  2,097,152 f
  float* Bb_f = Qg_f + 2097152;                    //  1,048,576 f (bf16 x 2.10M)
  float* gg = Bb_f + 1048576;                      //     32,768 f
  float* bet = gg + 32768;                         //     32,768 f
  float* gend = bet + 32768;                       //        512 f

  __hip_bfloat16* qkvzb = (__hip_bfloat16*)qkvz;   // bf16 qkvz
  __hip_bfloat16* Ub = (__hip_bfloat16*)U_f;
  __hip_bfloat16* Wb = (__hip_bfloat16*)Wb_f;
  __hip_bfloat16* KTb = (__hip_bfloat16*)KT_f;
  __hip_bfloat16* Qgb = (__hip_bfloat16*)Qg_f;
  __hip_bfloat16* Bb = (__hip_bfloat16*)Bb_f;
  // lifetime aliases:
  __hip_bfloat16* Wqkvz_t = (__hip_bfloat16*)V;    // spans V+U+Wb+KT (dead after 1st gemm)
  __hip_bfloat16* Xb = (__hip_bfloat16*)Qg_f;      // dead after 1st gemm
  __hip_bfloat16* Gb = (__hip_bfloat16*)Bb_f;      // Bb dead after phaseB
  __hip_bfloat16* Wout_t = (__hip_bfloat16*)qkvz;  // qkvz dead after gfuse's gate part
  float* O = V;                                    // V dead after phase1
  __hip_bfloat16* Pout = (__hip_bfloat16*)U_f;     // U+Wb+KT dead after phaseB

  prep2<<<dim3(2048 + 6144 + 256), 256, 0, stream>>>(X, Xb, W_qkvz, Wqkvz_t, W_ba, P);
  gemm256<<<dim3(NQKVZ / 256, T_LEN / 256), 512, 0, stream>>>(
      Xb, Wqkvz_t, qkvzb, T_LEN, NQKVZ, 2048);
  convs<<<dim3(4096 + 512 + 128), 256, 0, stream>>>(qkvzb, conv_w, QK, V, P,
                                                    dt_bias, A_log, gg, bet);
  phase1<<<dim3(HV_N, NCHUNK), 256, 0, stream>>>(QK, V, gg, bet, Ub, Wb, KTb, Qgb, Bb, gend);
  phaseB<<<dim3(HV_N, 4), 128, 0, stream>>>(Ub, Wb, KTb, Qgb, Bb, gend, O);
  gfuse<<<dim3(8192 + 2048), 256, 0, stream>>>(O, qkvzb, norm_w, Gb, W_out, Wout_t);
  gemm_bf16<128, true><<<dim3(2048 / 128, T_LEN / 128, 4), 256, 0, stream>>>(
      Gb, Wout_t, Pout, T_LEN, 2048, 1024, 4096);
  add4<<<dim3(T_LEN * 2048 / 4 / 256), 256, 0, stream>>>(Pout, out, T_LEN * 2048);
}

// Round 24
// 250.898 us; speedup vs baseline: 1.0412x; 1.0018x over previous
//
#include <hip/hip_runtime.h>
#include <hip/hip_bf16.h>
#include <math.h>

// Qwen3Next GatedDeltaNet — round 23: prep2 LDS union shrunk 32 KB -> 16.6 KB
// (ba GEMM processes its K-slice in two 256-wide halves through Xs[16][256]).
// LDS was capping the latency-bound prep2 at 5 blocks/CU (28% occupancy);
// 16.6 KB allows 8 blocks/CU (full 32 waves). Everything else = 251.4 config.

#define T_LEN 1024
#define HK_N 16
#define HV_N 32
#define NQKVZ 12288
#define CHUNK 64
#define NCHUNK 16

typedef __bf16 bf16x8 __attribute__((ext_vector_type(8)));
typedef float f32x4 __attribute__((ext_vector_type(4)));

__device__ __forceinline__ ushort4 pack4(const f32x4 v) {
  ushort4 o;
  o.x = __bfloat16_as_ushort(__float2bfloat16(v[0]));
  o.y = __bfloat16_as_ushort(__float2bfloat16(v[1]));
  o.z = __bfloat16_as_ushort(__float2bfloat16(v[2]));
  o.w = __bfloat16_as_ushort(__float2bfloat16(v[3]));
  return o;
}

// ---- 256x256 big-tile bf16 GEMM: C[M,N] = A[M,K] @ B[N,K]^T, bf16 out ------
__global__ __launch_bounds__(512) void gemm256(const __hip_bfloat16* __restrict__ A,
                                               const __hip_bfloat16* __restrict__ B,
                                               __hip_bfloat16* __restrict__ C,
                                               int M, int N, int Klen) {
  __shared__ __align__(16) __hip_bfloat16 As[2][256 * 64];
  __shared__ __align__(16) __hip_bfloat16 Bs[2][256 * 64];
  const int tid = threadIdx.x;
  const int wid = tid >> 6, lane = tid & 63;
  const int wr = wid >> 2, wc = wid & 3;
  const int m0 = blockIdx.y * 256, n0 = blockIdx.x * 256;
  const int lrow = lane & 15, lk = lane >> 4;
  const int rswz = (lrow & 7) * 8;
  f32x4 acc[8][4] = {};
  const int nk = Klen >> 6;

#define GST(b_, kt_) do {                                                       \
    _Pragma("unroll") for (int it = 0; it < 4; ++it) {                          \
      const int c_ = it * 512 + tid;                                            \
      const int row_ = c_ >> 3;                                                 \
      const int col8_ = ((c_ & 7) ^ (row_ & 7)) * 8;                            \
      __builtin_amdgcn_global_load_lds(                                         \
          (const __attribute__((address_space(1))) void*)                       \
              (A + (size_t)(m0 + row_) * Klen + ((kt_) << 6) + col8_),          \
          (__attribute__((address_space(3))) void*)(&As[b_][c_ * 8]), 16, 0, 0);\
    }                                                                           \
    _Pragma("unroll") for (int it = 0; it < 4; ++it) {                          \
      const int c_ = it * 512 + tid;                                            \
      const int row_ = c_ >> 3;                                                 \
      const int col8_ = ((c_ & 7) ^ (row_ & 7)) * 8;                            \
      __builtin_amdgcn_global_load_lds(                                         \
          (const __attribute__((address_space(1))) void*)                       \
              (B + (size_t)(n0 + row_) * Klen + ((kt_) << 6) + col8_),          \
          (__attribute__((address_space(3))) void*)(&Bs[b_][c_ * 8]), 16, 0, 0);\
    }                                                                           \
  } while (0)

  GST(0, 0);
  GST(1, 1);
  int cur = 0;
  for (int t = 0; t < nk; ++t) {
    if (t < nk - 1) asm volatile("s_waitcnt vmcnt(8)" ::: "memory");
    else            asm volatile("s_waitcnt vmcnt(0)" ::: "memory");
    __builtin_amdgcn_s_barrier();
    __builtin_amdgcn_sched_barrier(0);
    bf16x8 af[8], bfv[4];
#pragma unroll
    for (int m = 0; m < 8; ++m)
      af[m] = *reinterpret_cast<const bf16x8*>(
          &As[cur][(wr * 128 + m * 16 + lrow) * 64 + ((lk * 8) ^ rswz)]);
#pragma unroll
    for (int n = 0; n < 4; ++n)
      bfv[n] = *reinterpret_cast<const bf16x8*>(
          &Bs[cur][(wc * 64 + n * 16 + lrow) * 64 + ((lk * 8) ^ rswz)]);
    __builtin_amdgcn_s_setprio(1);
#pragma unroll
    for (int m = 0; m < 8; ++m)
#pragma unroll
      for (int n = 0; n < 4; ++n)
        acc[m][n] = __builtin_amdgcn_mfma_f32_16x16x32_bf16(af[m], bfv[n], acc[m][n], 0, 0, 0);
    __builtin_amdgcn_s_setprio(0);
#pragma unroll
    for (int m = 0; m < 8; ++m)
      af[m] = *reinterpret_cast<const bf16x8*>(
          &As[cur][(wr * 128 + m * 16 + lrow) * 64 + ((32 + lk * 8) ^ rswz)]);
#pragma unroll
    for (int n = 0; n < 4; ++n)
      bfv[n] = *reinterpret_cast<const bf16x8*>(
          &Bs[cur][(wc * 64 + n * 16 + lrow) * 64 + ((32 + lk * 8) ^ rswz)]);
    asm volatile("s_waitcnt lgkmcnt(0)" ::: "memory");
    __builtin_amdgcn_sched_barrier(0);
    __builtin_amdgcn_s_barrier();
    __builtin_amdgcn_sched_barrier(0);
    if (t + 2 < nk) GST(cur, t + 2);
    __builtin_amdgcn_s_setprio(1);
#pragma unroll
    for (int m = 0; m < 8; ++m)
#pragma unroll
      for (int n = 0; n < 4; ++n)
        acc[m][n] = __builtin_amdgcn_mfma_f32_16x16x32_bf16(af[m], bfv[n], acc[m][n], 0, 0, 0);
    __builtin_amdgcn_s_setprio(0);
    cur ^= 1;
  }
#undef GST
#pragma unroll
  for (int m = 0; m < 8; ++m)
#pragma unroll
    for (int n = 0; n < 4; ++n)
#pragma unroll
      for (int r = 0; r < 4; ++r)
        C[(size_t)(m0 + wr * 128 + m * 16 + lk * 4 + r) * N + n0 + wc * 64 + n * 16 + lrow] =
            __float2bfloat16(acc[m][n][r]);
}

// ------- bf16 MFMA GEMM (128-tile, proven): C (z-partials) = A @ B^T ---------
template <int BM, bool BF16OUT>
__global__ __launch_bounds__(256) void gemm_bf16(const __hip_bfloat16* __restrict__ A,
                                                 const __hip_bfloat16* __restrict__ B,
                                                 void* __restrict__ Cv,
                                                 int M, int N, int Klen, int ldk) {
  constexpr int AITS = BM / 32;
  constexpr int MF = BM / 32;
  __shared__ __align__(16) __hip_bfloat16 As[2][BM * 64];
  __shared__ __align__(16) __hip_bfloat16 Bs[2][128 * 64];
  const int tid = threadIdx.x;
  const int wid = tid >> 6, lane = tid & 63;
  const int wr = wid >> 1, wc = wid & 1;
  const int m0 = blockIdx.y * BM, n0 = blockIdx.x * 128;
  const size_t kbase = (size_t)blockIdx.z * Klen;
  const int lrow = lane & 15, lk = lane >> 4;
  const int rswz = (lrow & 7) * 8;
  f32x4 acc[MF][4] = {};
  const int nk = Klen >> 6;

#define GSTAGE(b_, k0_) do {                                                    \
    _Pragma("unroll") for (int it = 0; it < AITS; ++it) {                       \
      const int c_ = it * 256 + tid;                                            \
      const int row_ = c_ >> 3;                                                 \
      const int col8_ = ((c_ & 7) ^ (row_ & 7)) * 8;                            \
      __builtin_amdgcn_global_load_lds(                                         \
          (const __attribute__((address_space(1))) void*)                       \
              (A + (size_t)(m0 + row_) * ldk + kbase + (k0_) + col8_),          \
          (__attribute__((address_space(3))) void*)(&As[b_][it * 2048 + tid * 8]), 16, 0, 0); \
    }                                                                           \
    _Pragma("unroll") for (int it = 0; it < 4; ++it) {                          \
      const int c_ = it * 256 + tid;                                            \
      const int row_ = c_ >> 3;                                                 \
      const int col8_ = ((c_ & 7) ^ (row_ & 7)) * 8;                            \
      __builtin_amdgcn_global_load_lds(                                         \
          (const __attribute__((address_space(1))) void*)                       \
              (B + (size_t)(n0 + row_) * ldk + kbase + (k0_) + col8_),          \
          (__attribute__((address_space(3))) void*)(&Bs[b_][it * 2048 + tid * 8]), 16, 0, 0); \
    }                                                                           \
  } while (0)

  GSTAGE(0, 0);
  int buf = 0;
  for (int k = 0; k < nk; ++k) {
    if (k + 1 < nk) {
      GSTAGE(buf ^ 1, (k + 1) << 6);
      if constexpr (BM == 128) asm volatile("s_waitcnt vmcnt(8)" ::: "memory");
      else                     asm volatile("s_waitcnt vmcnt(6)" ::: "memory");
    } else {
      asm volatile("s_waitcnt vmcnt(0)" ::: "memory");
    }
    __builtin_amdgcn_s_barrier();
    __builtin_amdgcn_sched_barrier(0);
#pragma unroll
    for (int kk = 0; kk < 2; ++kk) {
      bf16x8 af[MF], bfv[4];
#pragma unroll
      for (int m = 0; m < MF; ++m)
        af[m] = *reinterpret_cast<const bf16x8*>(
            &As[buf][(wr * (BM / 2) + m * 16 + lrow) * 64 + ((kk * 32 + lk * 8) ^ rswz)]);
#pragma unroll
      for (int n = 0; n < 4; ++n)
        bfv[n] = *reinterpret_cast<const bf16x8*>(
            &Bs[buf][(wc * 64 + n * 16 + lrow) * 64 + ((kk * 32 + lk * 8) ^ rswz)]);
#pragma unroll
      for (int m = 0; m < MF; ++m)
#pragma unroll
        for (int n = 0; n < 4; ++n)
          acc[m][n] = __builtin_amdgcn_mfma_f32_16x16x32_bf16(af[m], bfv[n], acc[m][n], 0, 0, 0);
    }
    __builtin_amdgcn_sched_barrier(0);
    __builtin_amdgcn_s_barrier();
    buf ^= 1;
  }
#undef GSTAGE
  if constexpr (BF16OUT) {
    __hip_bfloat16* Cz = (__hip_bfloat16*)Cv + (size_t)blockIdx.z * M * N;
#pragma unroll
    for (int m = 0; m < MF; ++m)
#pragma unroll
      for (int n = 0; n < 4; ++n)
#pragma unroll
        for (int r = 0; r < 4; ++r)
          Cz[(size_t)(m0 + wr * (BM / 2) + m * 16 + lk * 4 + r) * N + n0 + wc * 64 + n * 16 + lrow] =
              __float2bfloat16(acc[m][n][r]);
  } else {
    float* Cz = (float*)Cv + (size_t)blockIdx.z * M * N;
#pragma unroll
    for (int m = 0; m < MF; ++m)
#pragma unroll
      for (int n = 0; n < 4; ++n)
#pragma unroll
        for (int r = 0; r < 4; ++r)
          Cz[(size_t)(m0 + wr * (BM / 2) + m * 16 + lk * 4 + r) * N + n0 + wc * 64 + n * 16 + lrow] =
              acc[m][n][r];
  }
}

// -------- out = sum of 4 bf16 K-slice partials (fp32 accumulate) -------------
__global__ void add4(const __hip_bfloat16* __restrict__ P, float* __restrict__ out, int n) {
  const int i = (blockIdx.x * 256 + threadIdx.x) * 4;
  if (i < n) {
    float s[4] = {0.f, 0.f, 0.f, 0.f};
#pragma unroll
    for (int z = 0; z < 4; ++z) {
      const ushort4 v = *reinterpret_cast<const ushort4*>(P + (size_t)z * n + i);
      s[0] += __bfloat162float(__ushort_as_bfloat16(v.x));
      s[1] += __bfloat162float(__ushort_as_bfloat16(v.y));
      s[2] += __bfloat162float(__ushort_as_bfloat16(v.z));
      s[3] += __bfloat162float(__ushort_as_bfloat16(v.w));
    }
    *reinterpret_cast<float4*>(out + i) = make_float4(s[0], s[1], s[2], s[3]);
  }
}

// --- prep2: cast X (0..2047) + transpose W_qkvz (2048..8191) + ba (8192..) ---
// LDS union = 16.6 KB (transpose tile); ba K-slice done in two 256 halves.
__global__ __launch_bounds__(256) void prep2(const float* __restrict__ X,
                                             __hip_bfloat16* __restrict__ Xb,
                                             const float* __restrict__ Wq,
                                             __hip_bfloat16* __restrict__ Wqt,
                                             const float* __restrict__ Wba,
                                             float* __restrict__ P) {
  __shared__ __align__(16) float smem[64 * 65];  // 16.6 KB union
  const int bid = blockIdx.x;
  const int tid = threadIdx.x;
  if (bid < 2048) {
    const int i = (bid * 256 + tid) * 4;
    const float4 v = *reinterpret_cast<const float4*>(X + i);
    ushort4 o;
    o.x = __bfloat16_as_ushort(__float2bfloat16(v.x));
    o.y = __bfloat16_as_ushort(__float2bfloat16(v.y));
    o.z = __bfloat16_as_ushort(__float2bfloat16(v.z));
    o.w = __bfloat16_as_ushort(__float2bfloat16(v.w));
    *reinterpret_cast<ushort4*>((void*)(Xb + i)) = o;
  } else if (bid < 8192) {
    // transpose W_qkvz [2048, 12288] -> bf16 [12288, 2048], 64x64 tiles
    float (*tl)[65] = reinterpret_cast<float (*)[65]>(smem);
    const int b = bid - 2048;
    const int n0 = (b % 192) * 64, k0 = (b / 192) * 64;
    const int N = NQKVZ, K = 2048;
    const int rc = tid & 15, rr = tid >> 4;
#pragma unroll
    for (int i = 0; i < 4; ++i) {
      const int k = rr + 16 * i;
      const float4 v = *reinterpret_cast<const float4*>(&Wq[(size_t)(k0 + k) * N + n0 + rc * 4]);
      tl[k][rc * 4 + 0] = v.x;
      tl[k][rc * 4 + 1] = v.y;
      tl[k][rc * 4 + 2] = v.z;
      tl[k][rc * 4 + 3] = v.w;
    }
    __syncthreads();
    const int wcx = tid & 7, wry = tid >> 3;
#pragma unroll
    for (int i = 0; i < 2; ++i) {
      const int n = wry + 32 * i;
      uint u[8];
#pragma unroll
      for (int j = 0; j < 8; ++j)
        u[j] = __bfloat16_as_ushort(__float2bfloat16(tl[wcx * 8 + j][n]));
      uint4 o;
      o.x = u[0] | (u[1] << 16);
      o.y = u[2] | (u[3] << 16);
      o.z = u[4] | (u[5] << 16);
      o.w = u[6] | (u[7] << 16);
      *reinterpret_cast<uint4*>((void*)&Wqt[(size_t)(n0 + n) * K + k0 + wcx * 8]) = o;
    }
  } else {
    // split-K ba GEMM: X[1024,2048] @ Wba[2048,64] -> P[4][1024][64]
    // K-slice of 512 processed as two 256-wide halves through Xs[16][256].
    float (*Xs)[256] = reinterpret_cast<float (*)[256]>(smem);
    const int b = bid - 8192;
    const int tt = b & 63, ks = b >> 6;
    const int c = tid & 63, r4 = tid >> 6;
    float acc[4] = {};
#pragma unroll
    for (int h = 0; h < 2; ++h) {
      const float* xsrc = X + (size_t)(tt * 16) * 2048 + ks * 512 + h * 256;
#pragma unroll
      for (int u = 0; u < 4; ++u) {
        const int flat = (u * 256 + tid) * 4;
        const int r = flat >> 8, k = flat & 255;
        *reinterpret_cast<float4*>(&Xs[r][k]) =
            *reinterpret_cast<const float4*>(&xsrc[(size_t)r * 2048 + k]);
      }
      __syncthreads();
      const float* wp = Wba + (size_t)(ks * 512 + h * 256) * 64 + c;
      for (int k = 0; k < 256; k += 8) {
        float w[8];
#pragma unroll
        for (int u = 0; u < 8; ++u) w[u] = wp[(size_t)(k + u) * 64];
#pragma unroll
        for (int u = 0; u < 8; ++u)
#pragma unroll
          for (int i = 0; i < 4; ++i)
            acc[i] = fmaf(Xs[r4 * 4 + i][k + u], w[u], acc[i]);
      }
      __syncthreads();
    }
    float* pp = P + ((size_t)ks * 1024 + tt * 16 + r4 * 4) * 64 + c;
#pragma unroll
    for (int i = 0; i < 4; ++i) pp[(size_t)i * 64] = acc[i];
  }
}

// --- convs: conv_qk_norm (0..4095) + conv_v (4096..4607) + gb (4608..4735) ---
__global__ __launch_bounds__(256) void convs(const __hip_bfloat16* __restrict__ qkvz,
                                             const float* __restrict__ conv_w,
                                             float* __restrict__ QK,
                                             float* __restrict__ V,
                                             const float* __restrict__ P,
                                             const float* __restrict__ dt_bias,
                                             const float* __restrict__ A_log,
                                             float* __restrict__ gg,
                                             float* __restrict__ bet) {
  const int bid = blockIdx.x;
  const int tid = threadIdx.x;
  if (bid < 4096) {
    const int kh = bid & 15;
    const int t = (bid >> 4) * 4 + (tid >> 6);
    const int l = tid & 63;
    const int cols[4] = {kh * 768 + l, kh * 768 + l + 64,
                         kh * 768 + 128 + l, kh * 768 + 128 + l + 64};
    const int chs[4] = {kh * 128 + l, kh * 128 + l + 64,
                        2048 + kh * 128 + l, 2048 + kh * 128 + l + 64};
    float y[4];
#pragma unroll
    for (int j = 0; j < 4; ++j) {
      const float* wp = &conv_w[chs[j] * 4];
      float acc = 0.f;
#pragma unroll
      for (int s = 0; s < 4; ++s) {
        const int tt = t - 3 + s;
        if (tt >= 0)
          acc = fmaf(__bfloat162float(qkvz[(size_t)tt * NQKVZ + cols[j]]), wp[s], acc);
      }
      y[j] = acc / (1.f + expf(-acc));  // silu
    }
    float sq = y[0] * y[0] + y[1] * y[1];
    float sk = y[2] * y[2] + y[3] * y[3];
#pragma unroll
    for (int off = 32; off; off >>= 1) {
      sq += __shfl_xor(sq, off);
      sk += __shfl_xor(sk, off);
    }
    const float rq = rsqrtf(sq + 1e-6f) * 0.08838834764831845f;  // * DK^-0.5
    const float rk = rsqrtf(sk + 1e-6f);
    const size_t qb = (size_t)t * 4096 + kh * 128;
    QK[qb + l] = y[0] * rq;
    QK[qb + l + 64] = y[1] * rq;
    QK[qb + 2048 + l] = y[2] * rk;
    QK[qb + 2048 + l + 64] = y[3] * rk;
  } else if (bid < 4608) {
    const int b = bid - 4096;
    const int c2 = (b & 15) * 256 + tid;
    const int vh = c2 >> 7;
    const int col = (vh >> 1) * 768 + 256 + (vh & 1) * 128 + (c2 & 127);
    const int t0 = (b >> 4) * 32;
    const float4 w = *reinterpret_cast<const float4*>(&conv_w[(4096 + c2) * 4]);
    float x0, x1, x2;
    if (t0 == 0) {
      x0 = 0.f; x1 = 0.f; x2 = 0.f;
    } else {
      x0 = __bfloat162float(qkvz[(size_t)(t0 - 3) * NQKVZ + col]);
      x1 = __bfloat162float(qkvz[(size_t)(t0 - 2) * NQKVZ + col]);
      x2 = __bfloat162float(qkvz[(size_t)(t0 - 1) * NQKVZ + col]);
    }
#pragma unroll 4
    for (int tt = 0; tt < 32; ++tt) {
      const int t = t0 + tt;
      const float x3 = __bfloat162float(qkvz[(size_t)t * NQKVZ + col]);
      float acc = x0 * w.x;
      acc = fmaf(x1, w.y, acc);
      acc = fmaf(x2, w.z, acc);
      acc = fmaf(x3, w.w, acc);
      V[(size_t)t * 4096 + c2] = acc / (1.f + expf(-acc));
      x0 = x1; x1 = x2; x2 = x3;
    }
  } else {
    const int idx = (bid - 4608) * 256 + tid;  // t*32 + vh
    const int t = idx >> 5, vh = idx & 31;
    const int cb = (vh >> 1) * 4 + (vh & 1);
    float b = 0.f, a = 0.f;
#pragma unroll
    for (int s = 0; s < 4; ++s) {
      b += P[((size_t)s * 1024 + t) * 64 + cb];
      a += P[((size_t)s * 1024 + t) * 64 + cb + 2];
    }
    const float x = a + dt_bias[vh];
    const float sp = (x > 20.f) ? x : log1pf(expf(x));
    gg[idx] = -expf(A_log[vh]) * sp;
    bet[idx] = 1.f / (1.f + expf(-b));
  }
}

// ---------------- phase 1: per (chunk, v-head) intra-chunk precompute --------
__global__ __launch_bounds__(256, 2) void phase1(
    const float* __restrict__ QK, const float* __restrict__ V,
    const float* __restrict__ g, const float* __restrict__ bet,
    __hip_bfloat16* __restrict__ Ub, __hip_bfloat16* __restrict__ Wb,
    __hip_bfloat16* __restrict__ KTb, __hip_bfloat16* __restrict__ Qgb,
    __hip_bfloat16* __restrict__ Bb, float* __restrict__ gend) {
  const int vh = blockIdx.x, ch = blockIdx.y, kh = vh >> 1;
  const int tid = threadIdx.x;
  const int t0 = ch * CHUNK;
  __shared__ __align__(16) __hip_bfloat16 KbS[64][128];
  __shared__ __align__(16) __hip_bfloat16 QbS[64][128];
  __shared__ __align__(16) float Al[64][68];
  __shared__ float bs[64], gams[64], bets[64], lams[64];

  const int row = tid >> 2;
  const size_t hb = (size_t)ch * 32 + vh;
  {
    const int cc = (tid & 3) * 32;
    const float* ksrc = &QK[(size_t)(t0 + row) * 4096 + 2048 + kh * 128 + cc];
    const float* qsrc = &QK[(size_t)(t0 + row) * 4096 + kh * 128 + cc];
#pragma unroll
    for (int u = 0; u < 32; u += 4) {
      const float4 kv = *reinterpret_cast<const float4*>(ksrc + u);
      const float4 qv = *reinterpret_cast<const float4*>(qsrc + u);
      const int d0 = cc + u;
      const int sidx = (d0 & 7) | ((((d0 >> 3) ^ (row & 7)) & 15) << 3);
      ushort4 kk4, qq4;
      kk4.x = __bfloat16_as_ushort(__float2bfloat16(kv.x));
      kk4.y = __bfloat16_as_ushort(__float2bfloat16(kv.y));
      kk4.z = __bfloat16_as_ushort(__float2bfloat16(kv.z));
      kk4.w = __bfloat16_as_ushort(__float2bfloat16(kv.w));
      qq4.x = __bfloat16_as_ushort(__float2bfloat16(qv.x));
      qq4.y = __bfloat16_as_ushort(__float2bfloat16(qv.y));
      qq4.z = __bfloat16_as_ushort(__float2bfloat16(qv.z));
      qq4.w = __bfloat16_as_ushort(__float2bfloat16(qv.w));
      *reinterpret_cast<ushort4*>(&KbS[row][sidx]) = kk4;
      *reinterpret_cast<ushort4*>(&QbS[row][sidx]) = qq4;
    }
  }
  if (tid < 64) {
    float b = g[(size_t)(t0 + tid) * 32 + vh];
#pragma unroll
    for (int off = 1; off < 64; off <<= 1) {
      const float o = __shfl_up(b, off);
      if (tid >= off) b += o;
    }
    const float b63 = __shfl(b, 63);
    const float ga = expf(b);
    bs[tid] = b;
    gams[tid] = ga;
    lams[tid] = expf(b63 - b);
    bets[tid] = bet[(size_t)(t0 + tid) * 32 + vh];
    if (tid == 63) gend[ch * 32 + vh] = ga;
  }
  __syncthreads();
  {
    const int i = tid & 63;
    const float li = lams[i];
    __hip_bfloat16* kt = &KTb[hb * 128 * 64];
    const int dbase = (tid >> 6) * 32;
#pragma unroll
    for (int dd = 0; dd < 32; ++dd) {
      const int d = dbase + dd;
      const int sidx = (d & 7) | ((((d >> 3) ^ (i & 7)) & 15) << 3);
      kt[(size_t)d * 64 + (i ^ ((d & 7) << 3))] =
          __float2bfloat16(li * __bfloat162float(KbS[i][sidx]));
    }
  }
  {
    const float gai = gams[row];
    __hip_bfloat16* qg = &Qgb[(hb * 64 + row) * 128];
    const int cc = (tid & 3) * 32;
#pragma unroll
    for (int u = 0; u < 32; u += 4) {
      const int d0 = cc + u;
      const int sidx = (d0 & 7) | ((((d0 >> 3) ^ (row & 7)) & 15) << 3);
      ushort4 qq;
      qq.x = __bfloat16_as_ushort(__float2bfloat16(gai * __bfloat162float(QbS[row][sidx + 0])));
      qq.y = __bfloat16_as_ushort(__float2bfloat16(gai * __bfloat162float(QbS[row][sidx + 1])));
      qq.z = __bfloat16_as_ushort(__float2bfloat16(gai * __bfloat162float(QbS[row][sidx + 2])));
      qq.w = __bfloat16_as_ushort(__float2bfloat16(gai * __bfloat162float(QbS[row][sidx + 3])));
      *reinterpret_cast<ushort4*>(&qg[d0 ^ ((row & 7) << 3)]) = qq;
    }
  }
  {
    const int w = tid >> 6, lane = tid & 63;
    const int lrow = lane & 15, lk = lane >> 4;
    bf16x8 af[4], qf[4];
#pragma unroll
    for (int kk = 0; kk < 4; ++kk) {
      const int c = ((kk * 4 + lk) ^ (lrow & 7)) * 8;
      af[kk] = *reinterpret_cast<const bf16x8*>(&KbS[w * 16 + lrow][c]);
      qf[kk] = *reinterpret_cast<const bf16x8*>(&QbS[w * 16 + lrow][c]);
    }
#pragma unroll
    for (int n = 0; n < 4; ++n) {
      f32x4 aA = {}, aB = {};
#pragma unroll
      for (int kk = 0; kk < 4; ++kk) {
        const bf16x8 bf = *reinterpret_cast<const bf16x8*>(
            &KbS[n * 16 + lrow][((kk * 4 + lk) ^ (lrow & 7)) * 8]);
        aA = __builtin_amdgcn_mfma_f32_16x16x32_bf16(af[kk], bf, aA, 0, 0, 0);
        aB = __builtin_amdgcn_mfma_f32_16x16x32_bf16(qf[kk], bf, aB, 0, 0, 0);
      }
      __hip_bfloat16* Bout = &Bb[hb * 64 * 64];
#pragma unroll
      for (int r = 0; r < 4; ++r) {
        const int i = w * 16 + lk * 4 + r;
        const int j = n * 16 + lrow;
        const float dec = expf(bs[i] - bs[j]);
        Al[i][j] = (j < i) ? bets[i] * dec * aA[r] : 0.f;
        Bout[(size_t)i * 64 + (j ^ ((i & 7) << 3))] =
            __float2bfloat16((j <= i) ? dec * aB[r] : 0.f);
      }
    }
  }
  __syncthreads();
  {
    const int cc = tid;
    float x[64];
    const bool isV = cc < 128;
    const float* src = isV ? &V[(size_t)t0 * 4096 + vh * 128 + cc]
                           : &QK[(size_t)t0 * 4096 + 2048 + kh * 128 + (cc - 128)];
#pragma unroll
    for (int i = 0; i < 64; ++i) {
      const float sc = isV ? bets[i] : bets[i] * gams[i];
      x[i] = sc * src[(size_t)i * 4096];
    }
#pragma unroll
    for (int i = 1; i < 64; ++i) {
      float s0 = 0.f, s1 = 0.f, s2 = 0.f, s3 = 0.f;
      int j = 0;
#pragma unroll
      for (; j + 4 <= i; j += 4) {
        const float4 a = *reinterpret_cast<const float4*>(&Al[i][j]);
        s0 = fmaf(a.x, x[j], s0);
        s1 = fmaf(a.y, x[j + 1], s1);
        s2 = fmaf(a.z, x[j + 2], s2);
        s3 = fmaf(a.w, x[j + 3], s3);
      }
#pragma unroll
      for (; j < i; ++j) s0 = fmaf(Al[i][j], x[j], s0);
      x[i] -= (s0 + s1) + (s2 + s3);
    }
    if (isV) {
      __hip_bfloat16* dst = &Ub[hb * 64 * 128 + cc];
#pragma unroll
      for (int i = 0; i < 64; ++i) dst[(size_t)i * 128] = __float2bfloat16(x[i]);
    } else {
      const int d = cc - 128;
      __hip_bfloat16* dst = &Wb[hb * 64 * 128];
#pragma unroll
      for (int i = 0; i < 64; ++i)
        dst[(size_t)i * 128 + (d ^ ((i & 7) << 3))] = __float2bfloat16(-x[i]);
    }
  }
}

// ---------------- phaseB: serial MFMA state propagation ----------------------
__global__ __launch_bounds__(128) void phaseB(
    const __hip_bfloat16* __restrict__ Ug, const __hip_bfloat16* __restrict__ Wb,
    const __hip_bfloat16* __restrict__ KTb, const __hip_bfloat16* __restrict__ Qgb,
    const __hip_bfloat16* __restrict__ Bb, const float* __restrict__ gendg,
    float* __restrict__ Og) {
  const int vh = blockIdx.x, slice = blockIdx.y;
  const int tid = threadIdx.x, lane = tid & 63, w = tid >> 6;
  const int l15 = lane & 15, l4 = lane >> 4;
  const int cg = slice * 32 + w * 16;
  const int swz = (l15 & 7) << 3;

  __shared__ __hip_bfloat16 Wl[2][8192];
  __shared__ __hip_bfloat16 KTl[2][8192];
  __shared__ __hip_bfloat16 Qgl[2][8192];
  __shared__ __hip_bfloat16 Bl[2][4096];
  __shared__ __hip_bfloat16 Sop[2][2048];
  __shared__ __hip_bfloat16 dLs[2][1024];

  f32x4 accS[8] = {};
  for (int x = lane; x < 1024; x += 64) reinterpret_cast<uint*>(Sop[w])[x] = 0;

  float ubuf[4][4];
#define STAGE(b_, c_) do {                                                      \
    const size_t hb_ = ((size_t)(c_) * 32 + vh);                                \
    _Pragma("unroll") for (int it = 0; it < 8; ++it) {                          \
      __builtin_amdgcn_global_load_lds(                                         \
          (const __attribute__((address_space(1))) void*)(Wb + hb_ * 8192 + it * 1024 + tid * 8), \
          (__attribute__((address_space(3))) void*)(&Wl[b_][it * 1024 + tid * 8]), 16, 0, 0); \
      __builtin_amdgcn_global_load_lds(                                         \
          (const __attribute__((address_space(1))) void*)(KTb + hb_ * 8192 + it * 1024 + tid * 8), \
          (__attribute__((address_space(3))) void*)(&KTl[b_][it * 1024 + tid * 8]), 16, 0, 0); \
      __builtin_amdgcn_global_load_lds(                                         \
          (const __attribute__((address_space(1))) void*)(Qgb + hb_ * 8192 + it * 1024 + tid * 8), \
          (__attribute__((address_space(3))) void*)(&Qgl[b_][it * 1024 + tid * 8]), 16, 0, 0); \
      if (it < 4)                                                               \
        __builtin_amdgcn_global_load_lds(                                       \
            (const __attribute__((address_space(1))) void*)(Bb + hb_ * 4096 + it * 1024 + tid * 8), \
            (__attribute__((address_space(3))) void*)(&Bl[b_][it * 1024 + tid * 8]), 16, 0, 0); \
    }                                                                           \
  } while (0)
#define UPREF(c_) do {                                                          \
    const __hip_bfloat16* up_ = Ug + ((size_t)(c_) * 32 + vh) * 64 * 128 + cg + l15; \
    _Pragma("unroll") for (int m_ = 0; m_ < 4; ++m_)                            \
      _Pragma("unroll") for (int r_ = 0; r_ < 4; ++r_)                          \
        ubuf[m_][r_] = __bfloat162float(up_[(size_t)(m_ * 16 + l4 * 4 + r_) * 128]); \
  } while (0)

  STAGE(0, 0);
  UPREF(0);
  __syncthreads();
  int buf = 0;
  for (int ch = 0; ch < NCHUNK; ++ch) {
    if (ch + 1 < NCHUNK) STAGE(buf ^ 1, ch + 1);
    f32x4 acc_d[4];
#pragma unroll
    for (int m = 0; m < 4; ++m) {
      f32x4 t;
      t[0] = ubuf[m][0]; t[1] = ubuf[m][1]; t[2] = ubuf[m][2]; t[3] = ubuf[m][3];
      acc_d[m] = t;
    }
    if (ch + 1 < NCHUNK) UPREF(ch + 1);
    // op1: delta = U + (-W) @ S
#pragma unroll
    for (int t = 0; t < 4; ++t) {
      const bf16x8 bS = *reinterpret_cast<const bf16x8*>(
          &Sop[w][l15 * 128 + ((t * 32 + l4 * 8) ^ swz)]);
#pragma unroll
      for (int m = 0; m < 4; ++m) {
        const bf16x8 aW = *reinterpret_cast<const bf16x8*>(
            &Wl[buf][(m * 16 + l15) * 128 + ((t * 32 + l4 * 8) ^ swz)]);
        acc_d[m] = __builtin_amdgcn_mfma_f32_16x16x32_bf16(aW, bS, acc_d[m], 0, 0, 0);
      }
    }
#pragma unroll
    for (int m = 0; m < 4; ++m)
      *reinterpret_cast<ushort4*>(&dLs[w][l15 * 64 + ((m * 16 + l4 * 4) ^ swz)]) =
          pack4(acc_d[m]);
    // opO: o = γq @ S + B @ δ
    f32x4 acc_o[4] = {};
#pragma unroll
    for (int t = 0; t < 4; ++t) {
      const bf16x8 bS = *reinterpret_cast<const bf16x8*>(
          &Sop[w][l15 * 128 + ((t * 32 + l4 * 8) ^ swz)]);
#pragma unroll
      for (int m = 0; m < 4; ++m) {
        const bf16x8 aQ = *reinterpret_cast<const bf16x8*>(
            &Qgl[buf][(m * 16 + l15) * 128 + ((t * 32 + l4 * 8) ^ swz)]);
        acc_o[m] = __builtin_amdgcn_mfma_f32_16x16x32_bf16(aQ, bS, acc_o[m], 0, 0, 0);
      }
    }
#pragma unroll
    for (int t2 = 0; t2 < 2; ++t2) {
      const bf16x8 bD = *reinterpret_cast<const bf16x8*>(
          &dLs[w][l15 * 64 + ((t2 * 32 + l4 * 8) ^ swz)]);
#pragma unroll
      for (int m = 0; m < 4; ++m) {
        const bf16x8 aB = *reinterpret_cast<const bf16x8*>(
            &Bl[buf][(m * 16 + l15) * 64 + ((t2 * 32 + l4 * 8) ^ swz)]);
        acc_o[m] = __builtin_amdgcn_mfma_f32_16x16x32_bf16(aB, bD, acc_o[m], 0, 0, 0);
      }
    }
    float* ob = Og + (size_t)(ch * 64) * 4096 + (size_t)vh * 128 + cg + l15;
#pragma unroll
    for (int m = 0; m < 4; ++m)
#pragma unroll
      for (int r = 0; r < 4; ++r)
        ob[(size_t)(m * 16 + l4 * 4 + r) * 4096] = acc_o[m][r];
    // op3: S = ge*S + Kᵀλ @ δ
    const float ge = gendg[ch * 32 + vh];
#pragma unroll
    for (int f = 0; f < 8; ++f) {
      accS[f][0] *= ge; accS[f][1] *= ge; accS[f][2] *= ge; accS[f][3] *= ge;
    }
#pragma unroll
    for (int t2 = 0; t2 < 2; ++t2) {
      const bf16x8 bD = *reinterpret_cast<const bf16x8*>(
          &dLs[w][l15 * 64 + ((t2 * 32 + l4 * 8) ^ swz)]);
#pragma unroll
      for (int f = 0; f < 8; ++f) {
        const bf16x8 aK = *reinterpret_cast<const bf16x8*>(
            &KTl[buf][(f * 16 + l15) * 64 + ((t2 * 32 + l4 * 8) ^ swz)]);
        accS[f] = __builtin_amdgcn_mfma_f32_16x16x32_bf16(aK, bD, accS[f], 0, 0, 0);
      }
    }
#pragma unroll
    for (int f = 0; f < 8; ++f)
      *reinterpret_cast<ushort4*>(&Sop[w][l15 * 128 + ((f * 16 + l4 * 4) ^ swz)]) =
          pack4(accS[f]);
    __syncthreads();
    buf ^= 1;
  }
#undef STAGE
#undef UPREF
}

// --- gfuse: gate_norm (0..8191) + transpose W_out (8192..10239) --------------
__global__ __launch_bounds__(256) void gfuse(const float* __restrict__ O,
                                             const __hip_bfloat16* __restrict__ qkvz,
                                             const float* __restrict__ norm_w,
                                             __hip_bfloat16* __restrict__ G,
                                             const float* __restrict__ Wo,
                                             __hip_bfloat16* __restrict__ Wot) {
  __shared__ float tl[64][65];
  const int bid = blockIdx.x;
  const int tid = threadIdx.x;
  if (bid < 8192) {
    const int vh = (bid & 7) * 4 + (tid >> 6);
    const int t = bid >> 3, l = tid & 63;
    const size_t ob = (size_t)t * 4096 + vh * 128;
    const size_t zb = (size_t)t * NQKVZ + (vh >> 1) * 768 + 512 + (vh & 1) * 128;
    const float o0 = O[ob + l], o1 = O[ob + l + 64];
    const float z0 = __bfloat162float(qkvz[zb + l]);
    const float z1 = __bfloat162float(qkvz[zb + l + 64]);
    const float g0 = o0 * z0 / (1.f + expf(-z0));
    const float g1 = o1 * z1 / (1.f + expf(-z1));
    float ss = g0 * g0 + g1 * g1;
#pragma unroll
    for (int off = 32; off; off >>= 1) ss += __shfl_xor(ss, off);
    const float rr = rsqrtf(ss * (1.f / 128.f) + 1e-6f);
    G[ob + l] = __float2bfloat16(g0 * rr * norm_w[l]);
    G[ob + l + 64] = __float2bfloat16(g1 * rr * norm_w[l + 64]);
    return;
  }
  const int b = bid - 8192;
  const int n0 = (b & 31) * 64, k0 = (b >> 5) * 64;
  const int N = 2048, K = 4096;
  const int rc = tid & 15, rr2 = tid >> 4;
#pragma unroll
  for (int i = 0; i < 4; ++i) {
    const int k = rr2 + 16 * i;
    const float4 v = *reinterpret_cast<const float4*>(&Wo[(size_t)(k0 + k) * N + n0 + rc * 4]);
    tl[k][rc * 4 + 0] = v.x;
    tl[k][rc * 4 + 1] = v.y;
    tl[k][rc * 4 + 2] = v.z;
    tl[k][rc * 4 + 3] = v.w;
  }
  __syncthreads();
  const int wcx = tid & 7, wry = tid >> 3;
#pragma unroll
  for (int i = 0; i < 2; ++i) {
    const int n = wry + 32 * i;
    uint u[8];
#pragma unroll
    for (int j = 0; j < 8; ++j)
      u[j] = __bfloat16_as_ushort(__float2bfloat16(tl[wcx * 8 + j][n]));
    uint4 o;
    o.x = u[0] | (u[1] << 16);
    o.y = u[2] | (u[3] << 16);
    o.z = u[4] | (u[5] << 16);
    o.w = u[6] | (u[7] << 16);
    *reinterpret_cast<uint4*>((void*)&Wot[(size_t)(n0 + n) * K + k0 + wcx * 8]) = o;
  }
}

extern "C" void kernel_launch(void* const* d_in, const int* in_sizes, int n_in,
                              void* d_out, int out_size, void* d_ws, size_t ws_size,
                              hipStream_t stream) {
  const float* X = (const float*)d_in[0];
  const float* W_qkvz = (const float*)d_in[1];
  const float* W_ba = (const float*)d_in[2];
  const float* conv_w = (const float*)d_in[3];
  const float* dt_bias = (const float*)d_in[4];
  const float* A_log = (const float*)d_in[5];
  const float* norm_w = (const float*)d_in[6];
  const float* W_out = (const float*)d_in[7];
  float* out = (float*)d_out;

  float* ws = (float*)d_ws;
  float* qkvz = ws;                                // region sized 12,582,912 f (used as bf16)
  float* P = qkvz + (size_t)T_LEN * NQKVZ;         //    262,144 f (ba partials)
  float* QK = P + 262144;                          //  4,194,304 f
  float* V = QK + (size_t)T_LEN * 4096;            //  4,194,304 f
  float* U_f = V + (size_t)T_LEN * 4096;           //  4,194,304 f (bf16 U uses half)
  float* Wb_f = U_f + (size_t)NCHUNK * 32 * 64 * 128; // 2,097,152 f
  float* KT_f = Wb_f + 2097152;                    //  2,097,152 f
  float* Qg_f = KT_f + 2097152;                    //  2,097,152 f
  float* Bb_f = Qg_f + 2097152;                    //  1,048,576 f (bf16 x 2.10M)
  float* gg = Bb_f + 1048576;                      //     32,768 f
  float* bet = gg + 32768;                         //     32,768 f
  float* gend = bet + 32768;                       //        512 f

  __hip_bfloat16* qkvzb = (__hip_bfloat16*)qkvz;   // bf16 qkvz
  __hip_bfloat16* Ub = (__hip_bfloat16*)U_f;
  __hip_bfloat16* Wb = (__hip_bfloat16*)Wb_f;
  __hip_bfloat16* KTb = (__hip_bfloat16*)KT_f;
  __hip_bfloat16* Qgb = (__hip_bfloat16*)Qg_f;
  __hip_bfloat16* Bb = (__hip_bfloat16*)Bb_f;
  // lifetime aliases:
  __hip_bfloat16* Wqkvz_t = (__hip_bfloat16*)V;    // spans V+U+Wb+KT (dead after 1st gemm)
  __hip_bfloat16* Xb = (__hip_bfloat16*)Qg_f;      // dead after 1st gemm
  __hip_bfloat16* Gb = (__hip_bfloat16*)Bb_f;      // Bb dead after phaseB
  __hip_bfloat16* Wout_t = (__hip_bfloat16*)qkvz;  // qkvz dead after gfuse's gate part
  float* O = V;                                    // V dead after phase1
  __hip_bfloat16* Pout = (__hip_bfloat16*)U_f;     // U+Wb+KT dead after phaseB

  prep2<<<dim3(2048 + 6144 + 256), 256, 0, stream>>>(X, Xb, W_qkvz, Wqkvz_t, W_ba, P);
  gemm256<<<dim3(NQKVZ / 256, T_LEN / 256), 512, 0, stream>>>(
      Xb, Wqkvz_t, qkvzb, T_LEN, NQKVZ, 2048);
  convs<<<dim3(4096 + 512 + 128), 256, 0, stream>>>(qkvzb, conv_w, QK, V, P,
                                                    dt_bias, A_log, gg, bet);
  phase1<<<dim3(HV_N, NCHUNK), 256, 0, stream>>>(QK, V, gg, bet, Ub, Wb, KTb, Qgb, Bb, gend);
  phaseB<<<dim3(HV_N, 4), 128, 0, stream>>>(Ub, Wb, KTb, Qgb, Bb, gend, O);
  gfuse<<<dim3(8192 + 2048), 256, 0, stream>>>(O, qkvzb, norm_w, Gb, W_out, Wout_t);
  gemm_bf16<128, true><<<dim3(2048 / 128, T_LEN / 128, 4), 256, 0, stream>>>(
      Gb, Wout_t, Pout, T_LEN, 2048, 1024, 4096);
  add4<<<dim3(T_LEN * 2048 / 4 / 256), 256, 0, stream>>>(Pout, out, T_LEN * 2048);
}

// Round 25
// 236.815 us; speedup vs baseline: 1.1032x; 1.0595x over previous
//
#include <hip/hip_runtime.h>
#include <hip/hip_bf16.h>
#include <math.h>

// Qwen3Next GatedDeltaNet — round 25: prep2 dispatch-order fix. Round 24 showed
// occupancy (28%) was NOT LDS-limited -> timeline effect: the 256 ba blocks were
// LAST in bid order (1 block/CU serial tail after the transpose drains). Now:
// ba blocks first (512 of them, 8 rows each = 2x parallelism), then cast, then
// transpose, so ba latency hides under the transpose stream. Rest = 251 config.

#define T_LEN 1024
#define HK_N 16
#define HV_N 32
#define NQKVZ 12288
#define CHUNK 64
#define NCHUNK 16

typedef __bf16 bf16x8 __attribute__((ext_vector_type(8)));
typedef float f32x4 __attribute__((ext_vector_type(4)));

__device__ __forceinline__ ushort4 pack4(const f32x4 v) {
  ushort4 o;
  o.x = __bfloat16_as_ushort(__float2bfloat16(v[0]));
  o.y = __bfloat16_as_ushort(__float2bfloat16(v[1]));
  o.z = __bfloat16_as_ushort(__float2bfloat16(v[2]));
  o.w = __bfloat16_as_ushort(__float2bfloat16(v[3]));
  return o;
}

// ---- 256x256 big-tile bf16 GEMM: C[M,N] = A[M,K] @ B[N,K]^T, bf16 out ------
__global__ __launch_bounds__(512) void gemm256(const __hip_bfloat16* __restrict__ A,
                                               const __hip_bfloat16* __restrict__ B,
                                               __hip_bfloat16* __restrict__ C,
                                               int M, int N, int Klen) {
  __shared__ __align__(16) __hip_bfloat16 As[2][256 * 64];
  __shared__ __align__(16) __hip_bfloat16 Bs[2][256 * 64];
  const int tid = threadIdx.x;
  const int wid = tid >> 6, lane = tid & 63;
  const int wr = wid >> 2, wc = wid & 3;
  const int m0 = blockIdx.y * 256, n0 = blockIdx.x * 256;
  const int lrow = lane & 15, lk = lane >> 4;
  const int rswz = (lrow & 7) * 8;
  f32x4 acc[8][4] = {};
  const int nk = Klen >> 6;

#define GST(b_, kt_) do {                                                       \
    _Pragma("unroll") for (int it = 0; it < 4; ++it) {                          \
      const int c_ = it * 512 + tid;                                            \
      const int row_ = c_ >> 3;                                                 \
      const int col8_ = ((c_ & 7) ^ (row_ & 7)) * 8;                            \
      __builtin_amdgcn_global_load_lds(                                         \
          (const __attribute__((address_space(1))) void*)                       \
              (A + (size_t)(m0 + row_) * Klen + ((kt_) << 6) + col8_),          \
          (__attribute__((address_space(3))) void*)(&As[b_][c_ * 8]), 16, 0, 0);\
    }                                                                           \
    _Pragma("unroll") for (int it = 0; it < 4; ++it) {                          \
      const int c_ = it * 512 + tid;                                            \
      const int row_ = c_ >> 3;                                                 \
      const int col8_ = ((c_ & 7) ^ (row_ & 7)) * 8;                            \
      __builtin_amdgcn_global_load_lds(                                         \
          (const __attribute__((address_space(1))) void*)                       \
              (B + (size_t)(n0 + row_) * Klen + ((kt_) << 6) + col8_),          \
          (__attribute__((address_space(3))) void*)(&Bs[b_][c_ * 8]), 16, 0, 0);\
    }                                                                           \
  } while (0)

  GST(0, 0);
  GST(1, 1);
  int cur = 0;
  for (int t = 0; t < nk; ++t) {
    if (t < nk - 1) asm volatile("s_waitcnt vmcnt(8)" ::: "memory");
    else            asm volatile("s_waitcnt vmcnt(0)" ::: "memory");
    __builtin_amdgcn_s_barrier();
    __builtin_amdgcn_sched_barrier(0);
    bf16x8 af[8], bfv[4];
#pragma unroll
    for (int m = 0; m < 8; ++m)
      af[m] = *reinterpret_cast<const bf16x8*>(
          &As[cur][(wr * 128 + m * 16 + lrow) * 64 + ((lk * 8) ^ rswz)]);
#pragma unroll
    for (int n = 0; n < 4; ++n)
      bfv[n] = *reinterpret_cast<const bf16x8*>(
          &Bs[cur][(wc * 64 + n * 16 + lrow) * 64 + ((lk * 8) ^ rswz)]);
    __builtin_amdgcn_s_setprio(1);
#pragma unroll
    for (int m = 0; m < 8; ++m)
#pragma unroll
      for (int n = 0; n < 4; ++n)
        acc[m][n] = __builtin_amdgcn_mfma_f32_16x16x32_bf16(af[m], bfv[n], acc[m][n], 0, 0, 0);
    __builtin_amdgcn_s_setprio(0);
#pragma unroll
    for (int m = 0; m < 8; ++m)
      af[m] = *reinterpret_cast<const bf16x8*>(
          &As[cur][(wr * 128 + m * 16 + lrow) * 64 + ((32 + lk * 8) ^ rswz)]);
#pragma unroll
    for (int n = 0; n < 4; ++n)
      bfv[n] = *reinterpret_cast<const bf16x8*>(
          &Bs[cur][(wc * 64 + n * 16 + lrow) * 64 + ((32 + lk * 8) ^ rswz)]);
    asm volatile("s_waitcnt lgkmcnt(0)" ::: "memory");
    __builtin_amdgcn_sched_barrier(0);
    __builtin_amdgcn_s_barrier();
    __builtin_amdgcn_sched_barrier(0);
    if (t + 2 < nk) GST(cur, t + 2);
    __builtin_amdgcn_s_setprio(1);
#pragma unroll
    for (int m = 0; m < 8; ++m)
#pragma unroll
      for (int n = 0; n < 4; ++n)
        acc[m][n] = __builtin_amdgcn_mfma_f32_16x16x32_bf16(af[m], bfv[n], acc[m][n], 0, 0, 0);
    __builtin_amdgcn_s_setprio(0);
    cur ^= 1;
  }
#undef GST
#pragma unroll
  for (int m = 0; m < 8; ++m)
#pragma unroll
    for (int n = 0; n < 4; ++n)
#pragma unroll
      for (int r = 0; r < 4; ++r)
        C[(size_t)(m0 + wr * 128 + m * 16 + lk * 4 + r) * N + n0 + wc * 64 + n * 16 + lrow] =
            __float2bfloat16(acc[m][n][r]);
}

// ------- bf16 MFMA GEMM (128-tile, proven): C (z-partials) = A @ B^T ---------
template <int BM, bool BF16OUT>
__global__ __launch_bounds__(256) void gemm_bf16(const __hip_bfloat16* __restrict__ A,
                                                 const __hip_bfloat16* __restrict__ B,
                                                 void* __restrict__ Cv,
                                                 int M, int N, int Klen, int ldk) {
  constexpr int AITS = BM / 32;
  constexpr int MF = BM / 32;
  __shared__ __align__(16) __hip_bfloat16 As[2][BM * 64];
  __shared__ __align__(16) __hip_bfloat16 Bs[2][128 * 64];
  const int tid = threadIdx.x;
  const int wid = tid >> 6, lane = tid & 63;
  const int wr = wid >> 1, wc = wid & 1;
  const int m0 = blockIdx.y * BM, n0 = blockIdx.x * 128;
  const size_t kbase = (size_t)blockIdx.z * Klen;
  const int lrow = lane & 15, lk = lane >> 4;
  const int rswz = (lrow & 7) * 8;
  f32x4 acc[MF][4] = {};
  const int nk = Klen >> 6;

#define GSTAGE(b_, k0_) do {                                                    \
    _Pragma("unroll") for (int it = 0; it < AITS; ++it) {                       \
      const int c_ = it * 256 + tid;                                            \
      const int row_ = c_ >> 3;                                                 \
      const int col8_ = ((c_ & 7) ^ (row_ & 7)) * 8;                            \
      __builtin_amdgcn_global_load_lds(                                         \
          (const __attribute__((address_space(1))) void*)                       \
              (A + (size_t)(m0 + row_) * ldk + kbase + (k0_) + col8_),          \
          (__attribute__((address_space(3))) void*)(&As[b_][it * 2048 + tid * 8]), 16, 0, 0); \
    }                                                                           \
    _Pragma("unroll") for (int it = 0; it < 4; ++it) {                          \
      const int c_ = it * 256 + tid;                                            \
      const int row_ = c_ >> 3;                                                 \
      const int col8_ = ((c_ & 7) ^ (row_ & 7)) * 8;                            \
      __builtin_amdgcn_global_load_lds(                                         \
          (const __attribute__((address_space(1))) void*)                       \
              (B + (size_t)(n0 + row_) * ldk + kbase + (k0_) + col8_),          \
          (__attribute__((address_space(3))) void*)(&Bs[b_][it * 2048 + tid * 8]), 16, 0, 0); \
    }                                                                           \
  } while (0)

  GSTAGE(0, 0);
  int buf = 0;
  for (int k = 0; k < nk; ++k) {
    if (k + 1 < nk) {
      GSTAGE(buf ^ 1, (k + 1) << 6);
      if constexpr (BM == 128) asm volatile("s_waitcnt vmcnt(8)" ::: "memory");
      else                     asm volatile("s_waitcnt vmcnt(6)" ::: "memory");
    } else {
      asm volatile("s_waitcnt vmcnt(0)" ::: "memory");
    }
    __builtin_amdgcn_s_barrier();
    __builtin_amdgcn_sched_barrier(0);
#pragma unroll
    for (int kk = 0; kk < 2; ++kk) {
      bf16x8 af[MF], bfv[4];
#pragma unroll
      for (int m = 0; m < MF; ++m)
        af[m] = *reinterpret_cast<const bf16x8*>(
            &As[buf][(wr * (BM / 2) + m * 16 + lrow) * 64 + ((kk * 32 + lk * 8) ^ rswz)]);
#pragma unroll
      for (int n = 0; n < 4; ++n)
        bfv[n] = *reinterpret_cast<const bf16x8*>(
            &Bs[buf][(wc * 64 + n * 16 + lrow) * 64 + ((kk * 32 + lk * 8) ^ rswz)]);
#pragma unroll
      for (int m = 0; m < MF; ++m)
#pragma unroll
        for (int n = 0; n < 4; ++n)
          acc[m][n] = __builtin_amdgcn_mfma_f32_16x16x32_bf16(af[m], bfv[n], acc[m][n], 0, 0, 0);
    }
    __builtin_amdgcn_sched_barrier(0);
    __builtin_amdgcn_s_barrier();
    buf ^= 1;
  }
#undef GSTAGE
  if constexpr (BF16OUT) {
    __hip_bfloat16* Cz = (__hip_bfloat16*)Cv + (size_t)blockIdx.z * M * N;
#pragma unroll
    for (int m = 0; m < MF; ++m)
#pragma unroll
      for (int n = 0; n < 4; ++n)
#pragma unroll
        for (int r = 0; r < 4; ++r)
          Cz[(size_t)(m0 + wr * (BM / 2) + m * 16 + lk * 4 + r) * N + n0 + wc * 64 + n * 16 + lrow] =
              __float2bfloat16(acc[m][n][r]);
  } else {
    float* Cz = (float*)Cv + (size_t)blockIdx.z * M * N;
#pragma unroll
    for (int m = 0; m < MF; ++m)
#pragma unroll
      for (int n = 0; n < 4; ++n)
#pragma unroll
        for (int r = 0; r < 4; ++r)
          Cz[(size_t)(m0 + wr * (BM / 2) + m * 16 + lk * 4 + r) * N + n0 + wc * 64 + n * 16 + lrow] =
              acc[m][n][r];
  }
}

// -------- out = sum of 4 bf16 K-slice partials (fp32 accumulate) -------------
__global__ void add4(const __hip_bfloat16* __restrict__ P, float* __restrict__ out, int n) {
  const int i = (blockIdx.x * 256 + threadIdx.x) * 4;
  if (i < n) {
    float s[4] = {0.f, 0.f, 0.f, 0.f};
#pragma unroll
    for (int z = 0; z < 4; ++z) {
      const ushort4 v = *reinterpret_cast<const ushort4*>(P + (size_t)z * n + i);
      s[0] += __bfloat162float(__ushort_as_bfloat16(v.x));
      s[1] += __bfloat162float(__ushort_as_bfloat16(v.y));
      s[2] += __bfloat162float(__ushort_as_bfloat16(v.z));
      s[3] += __bfloat162float(__ushort_as_bfloat16(v.w));
    }
    *reinterpret_cast<float4*>(out + i) = make_float4(s[0], s[1], s[2], s[3]);
  }
}

// --- prep2: ba GEMM (0..511) + cast X (512..2559) + transpose (2560..8703) ---
__global__ __launch_bounds__(256) void prep2(const float* __restrict__ X,
                                             __hip_bfloat16* __restrict__ Xb,
                                             const float* __restrict__ Wq,
                                             __hip_bfloat16* __restrict__ Wqt,
                                             const float* __restrict__ Wba,
                                             float* __restrict__ P) {
  __shared__ __align__(16) float smem[64 * 65];  // 16.6 KB union
  const int bid = blockIdx.x;
  const int tid = threadIdx.x;
  if (bid < 512) {
    // split-K ba GEMM: X[1024,2048] @ Wba[2048,64] -> P[4][1024][64]
    // 512 blocks: tt in 0..127 (8 rows each), ks in 0..3 (512-col K-slice,
    // processed as two 256-wide halves through Xs[8][256]).
    float (*Xs)[256] = reinterpret_cast<float (*)[256]>(smem);
    const int tt = bid & 127, ks = bid >> 7;
    const int c = tid & 63, r4 = tid >> 6;
    float acc[2] = {};
#pragma unroll
    for (int h = 0; h < 2; ++h) {
      const float* xsrc = X + (size_t)(tt * 8) * 2048 + ks * 512 + h * 256;
#pragma unroll
      for (int u = 0; u < 2; ++u) {
        const int flat = (u * 256 + tid) * 4;
        const int r = flat >> 8, k = flat & 255;
        *reinterpret_cast<float4*>(&Xs[r][k]) =
            *reinterpret_cast<const float4*>(&xsrc[(size_t)r * 2048 + k]);
      }
      __syncthreads();
      const float* wp = Wba + (size_t)(ks * 512 + h * 256) * 64 + c;
      for (int k = 0; k < 256; k += 8) {
        float w[8];
#pragma unroll
        for (int u = 0; u < 8; ++u) w[u] = wp[(size_t)(k + u) * 64];
#pragma unroll
        for (int u = 0; u < 8; ++u)
#pragma unroll
          for (int i = 0; i < 2; ++i)
            acc[i] = fmaf(Xs[r4 * 2 + i][k + u], w[u], acc[i]);
      }
      __syncthreads();
    }
    float* pp = P + ((size_t)ks * 1024 + tt * 8 + r4 * 2) * 64 + c;
#pragma unroll
    for (int i = 0; i < 2; ++i) pp[(size_t)i * 64] = acc[i];
  } else if (bid < 2560) {
    const int i = ((bid - 512) * 256 + tid) * 4;
    const float4 v = *reinterpret_cast<const float4*>(X + i);
    ushort4 o;
    o.x = __bfloat16_as_ushort(__float2bfloat16(v.x));
    o.y = __bfloat16_as_ushort(__float2bfloat16(v.y));
    o.z = __bfloat16_as_ushort(__float2bfloat16(v.z));
    o.w = __bfloat16_as_ushort(__float2bfloat16(v.w));
    *reinterpret_cast<ushort4*>((void*)(Xb + i)) = o;
  } else {
    // transpose W_qkvz [2048, 12288] -> bf16 [12288, 2048], 64x64 tiles
    float (*tl)[65] = reinterpret_cast<float (*)[65]>(smem);
    const int b = bid - 2560;
    const int n0 = (b % 192) * 64, k0 = (b / 192) * 64;
    const int N = NQKVZ, K = 2048;
    const int rc = tid & 15, rr = tid >> 4;
#pragma unroll
    for (int i = 0; i < 4; ++i) {
      const int k = rr + 16 * i;
      const float4 v = *reinterpret_cast<const float4*>(&Wq[(size_t)(k0 + k) * N + n0 + rc * 4]);
      tl[k][rc * 4 + 0] = v.x;
      tl[k][rc * 4 + 1] = v.y;
      tl[k][rc * 4 + 2] = v.z;
      tl[k][rc * 4 + 3] = v.w;
    }
    __syncthreads();
    const int wcx = tid & 7, wry = tid >> 3;
#pragma unroll
    for (int i = 0; i < 2; ++i) {
      const int n = wry + 32 * i;
      uint u[8];
#pragma unroll
      for (int j = 0; j < 8; ++j)
        u[j] = __bfloat16_as_ushort(__float2bfloat16(tl[wcx * 8 + j][n]));
      uint4 o;
      o.x = u[0] | (u[1] << 16);
      o.y = u[2] | (u[3] << 16);
      o.z = u[4] | (u[5] << 16);
      o.w = u[6] | (u[7] << 16);
      *reinterpret_cast<uint4*>((void*)&Wqt[(size_t)(n0 + n) * K + k0 + wcx * 8]) = o;
    }
  }
}

// --- convs: conv_qk_norm (0..4095) + conv_v (4096..4607) + gb (4608..4735) ---
__global__ __launch_bounds__(256) void convs(const __hip_bfloat16* __restrict__ qkvz,
                                             const float* __restrict__ conv_w,
                                             float* __restrict__ QK,
                                             float* __restrict__ V,
                                             const float* __restrict__ P,
                                             const float* __restrict__ dt_bias,
                                             const float* __restrict__ A_log,
                                             float* __restrict__ gg,
                                             float* __restrict__ bet) {
  const int bid = blockIdx.x;
  const int tid = threadIdx.x;
  if (bid < 4096) {
    const int kh = bid & 15;
    const int t = (bid >> 4) * 4 + (tid >> 6);
    const int l = tid & 63;
    const int cols[4] = {kh * 768 + l, kh * 768 + l + 64,
                         kh * 768 + 128 + l, kh * 768 + 128 + l + 64};
    const int chs[4] = {kh * 128 + l, kh * 128 + l + 64,
                        2048 + kh * 128 + l, 2048 + kh * 128 + l + 64};
    float y[4];
#pragma unroll
    for (int j = 0; j < 4; ++j) {
      const float* wp = &conv_w[chs[j] * 4];
      float acc = 0.f;
#pragma unroll
      for (int s = 0; s < 4; ++s) {
        const int tt = t - 3 + s;
        if (tt >= 0)
          acc = fmaf(__bfloat162float(qkvz[(size_t)tt * NQKVZ + cols[j]]), wp[s], acc);
      }
      y[j] = acc / (1.f + expf(-acc));  // silu
    }
    float sq = y[0] * y[0] + y[1] * y[1];
    float sk = y[2] * y[2] + y[3] * y[3];
#pragma unroll
    for (int off = 32; off; off >>= 1) {
      sq += __shfl_xor(sq, off);
      sk += __shfl_xor(sk, off);
    }
    const float rq = rsqrtf(sq + 1e-6f) * 0.08838834764831845f;  // * DK^-0.5
    const float rk = rsqrtf(sk + 1e-6f);
    const size_t qb = (size_t)t * 4096 + kh * 128;
    QK[qb + l] = y[0] * rq;
    QK[qb + l + 64] = y[1] * rq;
    QK[qb + 2048 + l] = y[2] * rk;
    QK[qb + 2048 + l + 64] = y[3] * rk;
  } else if (bid < 4608) {
    const int b = bid - 4096;
    const int c2 = (b & 15) * 256 + tid;
    const int vh = c2 >> 7;
    const int col = (vh >> 1) * 768 + 256 + (vh & 1) * 128 + (c2 & 127);
    const int t0 = (b >> 4) * 32;
    const float4 w = *reinterpret_cast<const float4*>(&conv_w[(4096 + c2) * 4]);
    float x0, x1, x2;
    if (t0 == 0) {
      x0 = 0.f; x1 = 0.f; x2 = 0.f;
    } else {
      x0 = __bfloat162float(qkvz[(size_t)(t0 - 3) * NQKVZ + col]);
      x1 = __bfloat162float(qkvz[(size_t)(t0 - 2) * NQKVZ + col]);
      x2 = __bfloat162float(qkvz[(size_t)(t0 - 1) * NQKVZ + col]);
    }
#pragma unroll 4
    for (int tt = 0; tt < 32; ++tt) {
      const int t = t0 + tt;
      const float x3 = __bfloat162float(qkvz[(size_t)t * NQKVZ + col]);
      float acc = x0 * w.x;
      acc = fmaf(x1, w.y, acc);
      acc = fmaf(x2, w.z, acc);
      acc = fmaf(x3, w.w, acc);
      V[(size_t)t * 4096 + c2] = acc / (1.f + expf(-acc));
      x0 = x1; x1 = x2; x2 = x3;
    }
  } else {
    const int idx = (bid - 4608) * 256 + tid;  // t*32 + vh
    const int t = idx >> 5, vh = idx & 31;
    const int cb = (vh >> 1) * 4 + (vh & 1);
    float b = 0.f, a = 0.f;
#pragma unroll
    for (int s = 0; s < 4; ++s) {
      b += P[((size_t)s * 1024 + t) * 64 + cb];
      a += P[((size_t)s * 1024 + t) * 64 + cb + 2];
    }
    const float x = a + dt_bias[vh];
    const float sp = (x > 20.f) ? x : log1pf(expf(x));
    gg[idx] = -expf(A_log[vh]) * sp;
    bet[idx] = 1.f / (1.f + expf(-b));
  }
}

// ---------------- phase 1: per (chunk, v-head) intra-chunk precompute --------
__global__ __launch_bounds__(256, 2) void phase1(
    const float* __restrict__ QK, const float* __restrict__ V,
    const float* __restrict__ g, const float* __restrict__ bet,
    __hip_bfloat16* __restrict__ Ub, __hip_bfloat16* __restrict__ Wb,
    __hip_bfloat16* __restrict__ KTb, __hip_bfloat16* __restrict__ Qgb,
    __hip_bfloat16* __restrict__ Bb, float* __restrict__ gend) {
  const int vh = blockIdx.x, ch = blockIdx.y, kh = vh >> 1;
  const int tid = threadIdx.x;
  const int t0 = ch * CHUNK;
  __shared__ __align__(16) __hip_bfloat16 KbS[64][128];
  __shared__ __align__(16) __hip_bfloat16 QbS[64][128];
  __shared__ __align__(16) float Al[64][68];
  __shared__ float bs[64], gams[64], bets[64], lams[64];

  const int row = tid >> 2;
  const size_t hb = (size_t)ch * 32 + vh;
  {
    const int cc = (tid & 3) * 32;
    const float* ksrc = &QK[(size_t)(t0 + row) * 4096 + 2048 + kh * 128 + cc];
    const float* qsrc = &QK[(size_t)(t0 + row) * 4096 + kh * 128 + cc];
#pragma unroll
    for (int u = 0; u < 32; u += 4) {
      const float4 kv = *reinterpret_cast<const float4*>(ksrc + u);
      const float4 qv = *reinterpret_cast<const float4*>(qsrc + u);
      const int d0 = cc + u;
      const int sidx = (d0 & 7) | ((((d0 >> 3) ^ (row & 7)) & 15) << 3);
      ushort4 kk4, qq4;
      kk4.x = __bfloat16_as_ushort(__float2bfloat16(kv.x));
      kk4.y = __bfloat16_as_ushort(__float2bfloat16(kv.y));
      kk4.z = __bfloat16_as_ushort(__float2bfloat16(kv.z));
      kk4.w = __bfloat16_as_ushort(__float2bfloat16(kv.w));
      qq4.x = __bfloat16_as_ushort(__float2bfloat16(qv.x));
      qq4.y = __bfloat16_as_ushort(__float2bfloat16(qv.y));
      qq4.z = __bfloat16_as_ushort(__float2bfloat16(qv.z));
      qq4.w = __bfloat16_as_ushort(__float2bfloat16(qv.w));
      *reinterpret_cast<ushort4*>(&KbS[row][sidx]) = kk4;
      *reinterpret_cast<ushort4*>(&QbS[row][sidx]) = qq4;
    }
  }
  if (tid < 64) {
    float b = g[(size_t)(t0 + tid) * 32 + vh];
#pragma unroll
    for (int off = 1; off < 64; off <<= 1) {
      const float o = __shfl_up(b, off);
      if (tid >= off) b += o;
    }
    const float b63 = __shfl(b, 63);
    const float ga = expf(b);
    bs[tid] = b;
    gams[tid] = ga;
    lams[tid] = expf(b63 - b);
    bets[tid] = bet[(size_t)(t0 + tid) * 32 + vh];
    if (tid == 63) gend[ch * 32 + vh] = ga;
  }
  __syncthreads();
  {
    const int i = tid & 63;
    const float li = lams[i];
    __hip_bfloat16* kt = &KTb[hb * 128 * 64];
    const int dbase = (tid >> 6) * 32;
#pragma unroll
    for (int dd = 0; dd < 32; ++dd) {
      const int d = dbase + dd;
      const int sidx = (d & 7) | ((((d >> 3) ^ (i & 7)) & 15) << 3);
      kt[(size_t)d * 64 + (i ^ ((d & 7) << 3))] =
          __float2bfloat16(li * __bfloat162float(KbS[i][sidx]));
    }
  }
  {
    const float gai = gams[row];
    __hip_bfloat16* qg = &Qgb[(hb * 64 + row) * 128];
    const int cc = (tid & 3) * 32;
#pragma unroll
    for (int u = 0; u < 32; u += 4) {
      const int d0 = cc + u;
      const int sidx = (d0 & 7) | ((((d0 >> 3) ^ (row & 7)) & 15) << 3);
      ushort4 qq;
      qq.x = __bfloat16_as_ushort(__float2bfloat16(gai * __bfloat162float(QbS[row][sidx + 0])));
      qq.y = __bfloat16_as_ushort(__float2bfloat16(gai * __bfloat162float(QbS[row][sidx + 1])));
      qq.z = __bfloat16_as_ushort(__float2bfloat16(gai * __bfloat162float(QbS[row][sidx + 2])));
      qq.w = __bfloat16_as_ushort(__float2bfloat16(gai * __bfloat162float(QbS[row][sidx + 3])));
      *reinterpret_cast<ushort4*>(&qg[d0 ^ ((row & 7) << 3)]) = qq;
    }
  }
  {
    const int w = tid >> 6, lane = tid & 63;
    const int lrow = lane & 15, lk = lane >> 4;
    bf16x8 af[4], qf[4];
#pragma unroll
    for (int kk = 0; kk < 4; ++kk) {
      const int c = ((kk * 4 + lk) ^ (lrow & 7)) * 8;
      af[kk] = *reinterpret_cast<const bf16x8*>(&KbS[w * 16 + lrow][c]);
      qf[kk] = *reinterpret_cast<const bf16x8*>(&QbS[w * 16 + lrow][c]);
    }
#pragma unroll
    for (int n = 0; n < 4; ++n) {
      f32x4 aA = {}, aB = {};
#pragma unroll
      for (int kk = 0; kk < 4; ++kk) {
        const bf16x8 bf = *reinterpret_cast<const bf16x8*>(
            &KbS[n * 16 + lrow][((kk * 4 + lk) ^ (lrow & 7)) * 8]);
        aA = __builtin_amdgcn_mfma_f32_16x16x32_bf16(af[kk], bf, aA, 0, 0, 0);
        aB = __builtin_amdgcn_mfma_f32_16x16x32_bf16(qf[kk], bf, aB, 0, 0, 0);
      }
      __hip_bfloat16* Bout = &Bb[hb * 64 * 64];
#pragma unroll
      for (int r = 0; r < 4; ++r) {
        const int i = w * 16 + lk * 4 + r;
        const int j = n * 16 + lrow;
        const float dec = expf(bs[i] - bs[j]);
        Al[i][j] = (j < i) ? bets[i] * dec * aA[r] : 0.f;
        Bout[(size_t)i * 64 + (j ^ ((i & 7) << 3))] =
            __float2bfloat16((j <= i) ? dec * aB[r] : 0.f);
      }
    }
  }
  __syncthreads();
  {
    const int cc = tid;
    float x[64];
    const bool isV = cc < 128;
    const float* src = isV ? &V[(size_t)t0 * 4096 + vh * 128 + cc]
                           : &QK[(size_t)t0 * 4096 + 2048 + kh * 128 + (cc - 128)];
#pragma unroll
    for (int i = 0; i < 64; ++i) {
      const float sc = isV ? bets[i] : bets[i] * gams[i];
      x[i] = sc * src[(size_t)i * 4096];
    }
#pragma unroll
    for (int i = 1; i < 64; ++i) {
      float s0 = 0.f, s1 = 0.f, s2 = 0.f, s3 = 0.f;
      int j = 0;
#pragma unroll
      for (; j + 4 <= i; j += 4) {
        const float4 a = *reinterpret_cast<const float4*>(&Al[i][j]);
        s0 = fmaf(a.x, x[j], s0);
        s1 = fmaf(a.y, x[j + 1], s1);
        s2 = fmaf(a.z, x[j + 2], s2);
        s3 = fmaf(a.w, x[j + 3], s3);
      }
#pragma unroll
      for (; j < i; ++j) s0 = fmaf(Al[i][j], x[j], s0);
      x[i] -= (s0 + s1) + (s2 + s3);
    }
    if (isV) {
      __hip_bfloat16* dst = &Ub[hb * 64 * 128 + cc];
#pragma unroll
      for (int i = 0; i < 64; ++i) dst[(size_t)i * 128] = __float2bfloat16(x[i]);
    } else {
      const int d = cc - 128;
      __hip_bfloat16* dst = &Wb[hb * 64 * 128];
#pragma unroll
      for (int i = 0; i < 64; ++i)
        dst[(size_t)i * 128 + (d ^ ((i & 7) << 3))] = __float2bfloat16(-x[i]);
    }
  }
}

// ---------------- phaseB: serial MFMA state propagation ----------------------
__global__ __launch_bounds__(128) void phaseB(
    const __hip_bfloat16* __restrict__ Ug, const __hip_bfloat16* __restrict__ Wb,
    const __hip_bfloat16* __restrict__ KTb, const __hip_bfloat16* __restrict__ Qgb,
    const __hip_bfloat16* __restrict__ Bb, const float* __restrict__ gendg,
    float* __restrict__ Og) {
  const int vh = blockIdx.x, slice = blockIdx.y;
  const int tid = threadIdx.x, lane = tid & 63, w = tid >> 6;
  const int l15 = lane & 15, l4 = lane >> 4;
  const int cg = slice * 32 + w * 16;
  const int swz = (l15 & 7) << 3;

  __shared__ __hip_bfloat16 Wl[2][8192];
  __shared__ __hip_bfloat16 KTl[2][8192];
  __shared__ __hip_bfloat16 Qgl[2][8192];
  __shared__ __hip_bfloat16 Bl[2][4096];
  __shared__ __hip_bfloat16 Sop[2][2048];
  __shared__ __hip_bfloat16 dLs[2][1024];

  f32x4 accS[8] = {};
  for (int x = lane; x < 1024; x += 64) reinterpret_cast<uint*>(Sop[w])[x] = 0;

  float ubuf[4][4];
#define STAGE(b_, c_) do {                                                      \
    const size_t hb_ = ((size_t)(c_) * 32 + vh);                                \
    _Pragma("unroll") for (int it = 0; it < 8; ++it) {                          \
      __builtin_amdgcn_global_load_lds(                                         \
          (const __attribute__((address_space(1))) void*)(Wb + hb_ * 8192 + it * 1024 + tid * 8), \
          (__attribute__((address_space(3))) void*)(&Wl[b_][it * 1024 + tid * 8]), 16, 0, 0); \
      __builtin_amdgcn_global_load_lds(                                         \
          (const __attribute__((address_space(1))) void*)(KTb + hb_ * 8192 + it * 1024 + tid * 8), \
          (__attribute__((address_space(3))) void*)(&KTl[b_][it * 1024 + tid * 8]), 16, 0, 0); \
      __builtin_amdgcn_global_load_lds(                                         \
          (const __attribute__((address_space(1))) void*)(Qgb + hb_ * 8192 + it * 1024 + tid * 8), \
          (__attribute__((address_space(3))) void*)(&Qgl[b_][it * 1024 + tid * 8]), 16, 0, 0); \
      if (it < 4)                                                               \
        __builtin_amdgcn_global_load_lds(                                       \
            (const __attribute__((address_space(1))) void*)(Bb + hb_ * 4096 + it * 1024 + tid * 8), \
            (__attribute__((address_space(3))) void*)(&Bl[b_][it * 1024 + tid * 8]), 16, 0, 0); \
    }                                                                           \
  } while (0)
#define UPREF(c_) do {                                                          \
    const __hip_bfloat16* up_ = Ug + ((size_t)(c_) * 32 + vh) * 64 * 128 + cg + l15; \
    _Pragma("unroll") for (int m_ = 0; m_ < 4; ++m_)                            \
      _Pragma("unroll") for (int r_ = 0; r_ < 4; ++r_)                          \
        ubuf[m_][r_] = __bfloat162float(up_[(size_t)(m_ * 16 + l4 * 4 + r_) * 128]); \
  } while (0)

  STAGE(0, 0);
  UPREF(0);
  __syncthreads();
  int buf = 0;
  for (int ch = 0; ch < NCHUNK; ++ch) {
    if (ch + 1 < NCHUNK) STAGE(buf ^ 1, ch + 1);
    f32x4 acc_d[4];
#pragma unroll
    for (int m = 0; m < 4; ++m) {
      f32x4 t;
      t[0] = ubuf[m][0]; t[1] = ubuf[m][1]; t[2] = ubuf[m][2]; t[3] = ubuf[m][3];
      acc_d[m] = t;
    }
    if (ch + 1 < NCHUNK) UPREF(ch + 1);
    // op1: delta = U + (-W) @ S
#pragma unroll
    for (int t = 0; t < 4; ++t) {
      const bf16x8 bS = *reinterpret_cast<const bf16x8*>(
          &Sop[w][l15 * 128 + ((t * 32 + l4 * 8) ^ swz)]);
#pragma unroll
      for (int m = 0; m < 4; ++m) {
        const bf16x8 aW = *reinterpret_cast<const bf16x8*>(
            &Wl[buf][(m * 16 + l15) * 128 + ((t * 32 + l4 * 8) ^ swz)]);
        acc_d[m] = __builtin_amdgcn_mfma_f32_16x16x32_bf16(aW, bS, acc_d[m], 0, 0, 0);
      }
    }
#pragma unroll
    for (int m = 0; m < 4; ++m)
      *reinterpret_cast<ushort4*>(&dLs[w][l15 * 64 + ((m * 16 + l4 * 4) ^ swz)]) =
          pack4(acc_d[m]);
    // opO: o = γq @ S + B @ δ
    f32x4 acc_o[4] = {};
#pragma unroll
    for (int t = 0; t < 4; ++t) {
      const bf16x8 bS = *reinterpret_cast<const bf16x8*>(
          &Sop[w][l15 * 128 + ((t * 32 + l4 * 8) ^ swz)]);
#pragma unroll
      for (int m = 0; m < 4; ++m) {
        const bf16x8 aQ = *reinterpret_cast<const bf16x8*>(
            &Qgl[buf][(m * 16 + l15) * 128 + ((t * 32 + l4 * 8) ^ swz)]);
        acc_o[m] = __builtin_amdgcn_mfma_f32_16x16x32_bf16(aQ, bS, acc_o[m], 0, 0, 0);
      }
    }
#pragma unroll
    for (int t2 = 0; t2 < 2; ++t2) {
      const bf16x8 bD = *reinterpret_cast<const bf16x8*>(
          &dLs[w][l15 * 64 + ((t2 * 32 + l4 * 8) ^ swz)]);
#pragma unroll
      for (int m = 0; m < 4; ++m) {
        const bf16x8 aB = *reinterpret_cast<const bf16x8*>(
            &Bl[buf][(m * 16 + l15) * 64 + ((t2 * 32 + l4 * 8) ^ swz)]);
        acc_o[m] = __builtin_amdgcn_mfma_f32_16x16x32_bf16(aB, bD, acc_o[m], 0, 0, 0);
      }
    }
    float* ob = Og + (size_t)(ch * 64) * 4096 + (size_t)vh * 128 + cg + l15;
#pragma unroll
    for (int m = 0; m < 4; ++m)
#pragma unroll
      for (int r = 0; r < 4; ++r)
        ob[(size_t)(m * 16 + l4 * 4 + r) * 4096] = acc_o[m][r];
    // op3: S = ge*S + Kᵀλ @ δ
    const float ge = gendg[ch * 32 + vh];
#pragma unroll
    for (int f = 0; f < 8; ++f) {
      accS[f][0] *= ge; accS[f][1] *= ge; accS[f][2] *= ge; accS[f][3] *= ge;
    }
#pragma unroll
    for (int t2 = 0; t2 < 2; ++t2) {
      const bf16x8 bD = *reinterpret_cast<const bf16x8*>(
          &dLs[w][l15 * 64 + ((t2 * 32 + l4 * 8) ^ swz)]);
#pragma unroll
      for (int f = 0; f < 8; ++f) {
        const bf16x8 aK = *reinterpret_cast<const bf16x8*>(
            &KTl[buf][(f * 16 + l15) * 64 + ((t2 * 32 + l4 * 8) ^ swz)]);
        accS[f] = __builtin_amdgcn_mfma_f32_16x16x32_bf16(aK, bD, accS[f], 0, 0, 0);
      }
    }
#pragma unroll
    for (int f = 0; f < 8; ++f)
      *reinterpret_cast<ushort4*>(&Sop[w][l15 * 128 + ((f * 16 + l4 * 4) ^ swz)]) =
          pack4(accS[f]);
    __syncthreads();
    buf ^= 1;
  }
#undef STAGE
#undef UPREF
}

// --- gfuse: gate_norm (0..8191) + transpose W_out (8192..10239) --------------
__global__ __launch_bounds__(256) void gfuse(const float* __restrict__ O,
                                             const __hip_bfloat16* __restrict__ qkvz,
                                             const float* __restrict__ norm_w,
                                             __hip_bfloat16* __restrict__ G,
                                             const float* __restrict__ Wo,
                                             __hip_bfloat16* __restrict__ Wot) {
  __shared__ float tl[64][65];
  const int bid = blockIdx.x;
  const int tid = threadIdx.x;
  if (bid < 8192) {
    const int vh = (bid & 7) * 4 + (tid >> 6);
    const int t = bid >> 3, l = tid & 63;
    const size_t ob = (size_t)t * 4096 + vh * 128;
    const size_t zb = (size_t)t * NQKVZ + (vh >> 1) * 768 + 512 + (vh & 1) * 128;
    const float o0 = O[ob + l], o1 = O[ob + l + 64];
    const float z0 = __bfloat162float(qkvz[zb + l]);
    const float z1 = __bfloat162float(qkvz[zb + l + 64]);
    const float g0 = o0 * z0 / (1.f + expf(-z0));
    const float g1 = o1 * z1 / (1.f + expf(-z1));
    float ss = g0 * g0 + g1 * g1;
#pragma unroll
    for (int off = 32; off; off >>= 1) ss += __shfl_xor(ss, off);
    const float rr = rsqrtf(ss * (1.f / 128.f) + 1e-6f);
    G[ob + l] = __float2bfloat16(g0 * rr * norm_w[l]);
    G[ob + l + 64] = __float2bfloat16(g1 * rr * norm_w[l + 64]);
    return;
  }
  const int b = bid - 8192;
  const int n0 = (b & 31) * 64, k0 = (b >> 5) * 64;
  const int N = 2048, K = 4096;
  const int rc = tid & 15, rr2 = tid >> 4;
#pragma unroll
  for (int i = 0; i < 4; ++i) {
    const int k = rr2 + 16 * i;
    const float4 v = *reinterpret_cast<const float4*>(&Wo[(size_t)(k0 + k) * N + n0 + rc * 4]);
    tl[k][rc * 4 + 0] = v.x;
    tl[k][rc * 4 + 1] = v.y;
    tl[k][rc * 4 + 2] = v.z;
    tl[k][rc * 4 + 3] = v.w;
  }
  __syncthreads();
  const int wcx = tid & 7, wry = tid >> 3;
#pragma unroll
  for (int i = 0; i < 2; ++i) {
    const int n = wry + 32 * i;
    uint u[8];
#pragma unroll
    for (int j = 0; j < 8; ++j)
      u[j] = __bfloat16_as_ushort(__float2bfloat16(tl[wcx * 8 + j][n]));
    uint4 o;
    o.x = u[0] | (u[1] << 16);
    o.y = u[2] | (u[3] << 16);
    o.z = u[4] | (u[5] << 16);
    o.w = u[6] | (u[7] << 16);
    *reinterpret_cast<uint4*>((void*)&Wot[(size_t)(n0 + n) * K + k0 + wcx * 8]) = o;
  }
}

extern "C" void kernel_launch(void* const* d_in, const int* in_sizes, int n_in,
                              void* d_out, int out_size, void* d_ws, size_t ws_size,
                              hipStream_t stream) {
  const float* X = (const float*)d_in[0];
  const float* W_qkvz = (const float*)d_in[1];
  const float* W_ba = (const float*)d_in[2];
  const float* conv_w = (const float*)d_in[3];
  const float* dt_bias = (const float*)d_in[4];
  const float* A_log = (const float*)d_in[5];
  const float* norm_w = (const float*)d_in[6];
  const float* W_out = (const float*)d_in[7];
  float* out = (float*)d_out;

  float* ws = (float*)d_ws;
  float* qkvz = ws;                                // region sized 12,582,912 f (used as bf16)
  float* P = qkvz + (size_t)T_LEN * NQKVZ;         //    262,144 f (ba partials)
  float* QK = P + 262144;                          //  4,194,304 f
  float* V = QK + (size_t)T_LEN * 4096;            //  4,194,304 f
  float* U_f = V + (size_t)T_LEN * 4096;           //  4,194,304 f (bf16 U uses half)
  float* Wb_f = U_f + (size_t)NCHUNK * 32 * 64 * 128; // 2,097,152 f
  float* KT_f = Wb_f + 2097152;                    //  2,097,152 f
  float* Qg_f = KT_f + 2097152;                    //  2,097,152 f
  float* Bb_f = Qg_f + 2097152;                    //  1,048,576 f (bf16 x 2.10M)
  float* gg = Bb_f + 1048576;                      //     32,768 f
  float* bet = gg + 32768;                         //     32,768 f
  float* gend = bet + 32768;                       //        512 f

  __hip_bfloat16* qkvzb = (__hip_bfloat16*)qkvz;   // bf16 qkvz
  __hip_bfloat16* Ub = (__hip_bfloat16*)U_f;
  __hip_bfloat16* Wb = (__hip_bfloat16*)Wb_f;
  __hip_bfloat16* KTb = (__hip_bfloat16*)KT_f;
  __hip_bfloat16* Qgb = (__hip_bfloat16*)Qg_f;
  __hip_bfloat16* Bb = (__hip_bfloat16*)Bb_f;
  // lifetime aliases:
  __hip_bfloat16* Wqkvz_t = (__hip_bfloat16*)V;    // spans V+U+Wb+KT (dead after 1st gemm)
  __hip_bfloat16* Xb = (__hip_bfloat16*)Qg_f;      // dead after 1st gemm
  __hip_bfloat16* Gb = (__hip_bfloat16*)Bb_f;      // Bb dead after phaseB
  __hip_bfloat16* Wout_t = (__hip_bfloat16*)qkvz;  // qkvz dead after gfuse's gate part
  float* O = V;                                    // V dead after phase1
  __hip_bfloat16* Pout = (__hip_bfloat16*)U_f;     // U+Wb+KT dead after phaseB

  prep2<<<dim3(512 + 2048 + 6144), 256, 0, stream>>>(X, Xb, W_qkvz, Wqkvz_t, W_ba, P);
  gemm256<<<dim3(NQKVZ / 256, T_LEN / 256), 512, 0, stream>>>(
      Xb, Wqkvz_t, qkvzb, T_LEN, NQKVZ, 2048);
  convs<<<dim3(4096 + 512 + 128), 256, 0, stream>>>(qkvzb, conv_w, QK, V, P,
                                                    dt_bias, A_log, gg, bet);
  phase1<<<dim3(HV_N, NCHUNK), 256, 0, stream>>>(QK, V, gg, bet, Ub, Wb, KTb, Qgb, Bb, gend);
  phaseB<<<dim3(HV_N, 4), 128, 0, stream>>>(Ub, Wb, KTb, Qgb, Bb, gend, O);
  gfuse<<<dim3(8192 + 2048), 256, 0, stream>>>(O, qkvzb, norm_w, Gb, W_out, Wout_t);
  gemm_bf16<128, true><<<dim3(2048 / 128, T_LEN / 128, 4), 256, 0, stream>>>(
      Gb, Wout_t, Pout, T_LEN, 2048, 1024, 4096);
  add4<<<dim3(T_LEN * 2048 / 4 / 256), 256, 0, stream>>>(Pout, out, T_LEN * 2048);
}

// Round 26
// 229.006 us; speedup vs baseline: 1.1408x; 1.0341x over previous
//
#include <hip/hip_runtime.h>
#include <hip/hip_bf16.h>
#include <math.h>

// Qwen3Next GatedDeltaNet — round 26: gemm256 retiled 256x256 -> 256x192.
// Grid becomes 64x4 = 256 blocks = exactly 1/CU (was 192 = 75% coverage).
// Per-wave output 128x48 (3 N-frags), Bs = 192x64 x2 (112 KB LDS total),
// B staged in 3 GST iterations -> 7 loads/thread -> counted vmcnt(7).
// Same proven sync skeleton + swizzle. Rest = round-25 config (236.8 µs).

#define T_LEN 1024
#define HK_N 16
#define HV_N 32
#define NQKVZ 12288
#define CHUNK 64
#define NCHUNK 16

typedef __bf16 bf16x8 __attribute__((ext_vector_type(8)));
typedef float f32x4 __attribute__((ext_vector_type(4)));

__device__ __forceinline__ ushort4 pack4(const f32x4 v) {
  ushort4 o;
  o.x = __bfloat16_as_ushort(__float2bfloat16(v[0]));
  o.y = __bfloat16_as_ushort(__float2bfloat16(v[1]));
  o.z = __bfloat16_as_ushort(__float2bfloat16(v[2]));
  o.w = __bfloat16_as_ushort(__float2bfloat16(v[3]));
  return o;
}

// ---- 256x192 big-tile bf16 GEMM: C[M,N] = A[M,K] @ B[N,K]^T, bf16 out ------
// 512 thr = 8 waves (2M x 4N), per-wave 128x48. BK=64, 2-K-tile prefetch,
// counted vmcnt(7) (7 global_load_lds per tile: 4 A + 3 B).
__global__ __launch_bounds__(512) void gemm256(const __hip_bfloat16* __restrict__ A,
                                               const __hip_bfloat16* __restrict__ B,
                                               __hip_bfloat16* __restrict__ C,
                                               int M, int N, int Klen) {
  __shared__ __align__(16) __hip_bfloat16 As[2][256 * 64];  // 32 KB x2
  __shared__ __align__(16) __hip_bfloat16 Bs[2][192 * 64];  // 24 KB x2
  const int tid = threadIdx.x;
  const int wid = tid >> 6, lane = tid & 63;
  const int wr = wid >> 2, wc = wid & 3;
  const int m0 = blockIdx.y * 256, n0 = blockIdx.x * 192;
  const int lrow = lane & 15, lk = lane >> 4;
  const int rswz = (lrow & 7) * 8;
  f32x4 acc[8][3] = {};
  const int nk = Klen >> 6;

#define GST(b_, kt_) do {                                                       \
    _Pragma("unroll") for (int it = 0; it < 4; ++it) {                          \
      const int c_ = it * 512 + tid;                                            \
      const int row_ = c_ >> 3;                                                 \
      const int col8_ = ((c_ & 7) ^ (row_ & 7)) * 8;                            \
      __builtin_amdgcn_global_load_lds(                                         \
          (const __attribute__((address_space(1))) void*)                       \
              (A + (size_t)(m0 + row_) * Klen + ((kt_) << 6) + col8_),          \
          (__attribute__((address_space(3))) void*)(&As[b_][c_ * 8]), 16, 0, 0);\
    }                                                                           \
    _Pragma("unroll") for (int it = 0; it < 3; ++it) {                          \
      const int c_ = it * 512 + tid;                                            \
      const int row_ = c_ >> 3;                                                 \
      const int col8_ = ((c_ & 7) ^ (row_ & 7)) * 8;                            \
      __builtin_amdgcn_global_load_lds(                                         \
          (const __attribute__((address_space(1))) void*)                       \
              (B + (size_t)(n0 + row_) * Klen + ((kt_) << 6) + col8_),          \
          (__attribute__((address_space(3))) void*)(&Bs[b_][c_ * 8]), 16, 0, 0);\
    }                                                                           \
  } while (0)

  GST(0, 0);
  GST(1, 1);
  int cur = 0;
  for (int t = 0; t < nk; ++t) {
    if (t < nk - 1) asm volatile("s_waitcnt vmcnt(7)" ::: "memory");
    else            asm volatile("s_waitcnt vmcnt(0)" ::: "memory");
    __builtin_amdgcn_s_barrier();      // tile t landed everywhere
    __builtin_amdgcn_sched_barrier(0);
    bf16x8 af[8], bfv[3];
    // ---- k-half 0: read frags, MFMA 24 ----
#pragma unroll
    for (int m = 0; m < 8; ++m)
      af[m] = *reinterpret_cast<const bf16x8*>(
          &As[cur][(wr * 128 + m * 16 + lrow) * 64 + ((lk * 8) ^ rswz)]);
#pragma unroll
    for (int n = 0; n < 3; ++n)
      bfv[n] = *reinterpret_cast<const bf16x8*>(
          &Bs[cur][(wc * 48 + n * 16 + lrow) * 64 + ((lk * 8) ^ rswz)]);
    __builtin_amdgcn_s_setprio(1);
#pragma unroll
    for (int m = 0; m < 8; ++m)
#pragma unroll
      for (int n = 0; n < 3; ++n)
        acc[m][n] = __builtin_amdgcn_mfma_f32_16x16x32_bf16(af[m], bfv[n], acc[m][n], 0, 0, 0);
    __builtin_amdgcn_s_setprio(0);
    // ---- k-half 1: read frags into regs, THEN release the buffer ----
#pragma unroll
    for (int m = 0; m < 8; ++m)
      af[m] = *reinterpret_cast<const bf16x8*>(
          &As[cur][(wr * 128 + m * 16 + lrow) * 64 + ((32 + lk * 8) ^ rswz)]);
#pragma unroll
    for (int n = 0; n < 3; ++n)
      bfv[n] = *reinterpret_cast<const bf16x8*>(
          &Bs[cur][(wc * 48 + n * 16 + lrow) * 64 + ((32 + lk * 8) ^ rswz)]);
    asm volatile("s_waitcnt lgkmcnt(0)" ::: "memory");
    __builtin_amdgcn_sched_barrier(0);
    __builtin_amdgcn_s_barrier();      // all waves' reads of buf[cur] done
    __builtin_amdgcn_sched_barrier(0);
    if (t + 2 < nk) GST(cur, t + 2);   // restage freed buffer (overlaps MFMA)
    __builtin_amdgcn_s_setprio(1);
#pragma unroll
    for (int m = 0; m < 8; ++m)
#pragma unroll
      for (int n = 0; n < 3; ++n)
        acc[m][n] = __builtin_amdgcn_mfma_f32_16x16x32_bf16(af[m], bfv[n], acc[m][n], 0, 0, 0);
    __builtin_amdgcn_s_setprio(0);
    cur ^= 1;
  }
#undef GST
#pragma unroll
  for (int m = 0; m < 8; ++m)
#pragma unroll
    for (int n = 0; n < 3; ++n)
#pragma unroll
      for (int r = 0; r < 4; ++r)
        C[(size_t)(m0 + wr * 128 + m * 16 + lk * 4 + r) * N + n0 + wc * 48 + n * 16 + lrow] =
            __float2bfloat16(acc[m][n][r]);
}

// ------- bf16 MFMA GEMM (128-tile, proven): C (z-partials) = A @ B^T ---------
template <int BM, bool BF16OUT>
__global__ __launch_bounds__(256) void gemm_bf16(const __hip_bfloat16* __restrict__ A,
                                                 const __hip_bfloat16* __restrict__ B,
                                                 void* __restrict__ Cv,
                                                 int M, int N, int Klen, int ldk) {
  constexpr int AITS = BM / 32;
  constexpr int MF = BM / 32;
  __shared__ __align__(16) __hip_bfloat16 As[2][BM * 64];
  __shared__ __align__(16) __hip_bfloat16 Bs[2][128 * 64];
  const int tid = threadIdx.x;
  const int wid = tid >> 6, lane = tid & 63;
  const int wr = wid >> 1, wc = wid & 1;
  const int m0 = blockIdx.y * BM, n0 = blockIdx.x * 128;
  const size_t kbase = (size_t)blockIdx.z * Klen;
  const int lrow = lane & 15, lk = lane >> 4;
  const int rswz = (lrow & 7) * 8;
  f32x4 acc[MF][4] = {};
  const int nk = Klen >> 6;

#define GSTAGE(b_, k0_) do {                                                    \
    _Pragma("unroll") for (int it = 0; it < AITS; ++it) {                       \
      const int c_ = it * 256 + tid;                                            \
      const int row_ = c_ >> 3;                                                 \
      const int col8_ = ((c_ & 7) ^ (row_ & 7)) * 8;                            \
      __builtin_amdgcn_global_load_lds(                                         \
          (const __attribute__((address_space(1))) void*)                       \
              (A + (size_t)(m0 + row_) * ldk + kbase + (k0_) + col8_),          \
          (__attribute__((address_space(3))) void*)(&As[b_][it * 2048 + tid * 8]), 16, 0, 0); \
    }                                                                           \
    _Pragma("unroll") for (int it = 0; it < 4; ++it) {                          \
      const int c_ = it * 256 + tid;                                            \
      const int row_ = c_ >> 3;                                                 \
      const int col8_ = ((c_ & 7) ^ (row_ & 7)) * 8;                            \
      __builtin_amdgcn_global_load_lds(                                         \
          (const __attribute__((address_space(1))) void*)                       \
              (B + (size_t)(n0 + row_) * ldk + kbase + (k0_) + col8_),          \
          (__attribute__((address_space(3))) void*)(&Bs[b_][it * 2048 + tid * 8]), 16, 0, 0); \
    }                                                                           \
  } while (0)

  GSTAGE(0, 0);
  int buf = 0;
  for (int k = 0; k < nk; ++k) {
    if (k + 1 < nk) {
      GSTAGE(buf ^ 1, (k + 1) << 6);
      if constexpr (BM == 128) asm volatile("s_waitcnt vmcnt(8)" ::: "memory");
      else                     asm volatile("s_waitcnt vmcnt(6)" ::: "memory");
    } else {
      asm volatile("s_waitcnt vmcnt(0)" ::: "memory");
    }
    __builtin_amdgcn_s_barrier();
    __builtin_amdgcn_sched_barrier(0);
#pragma unroll
    for (int kk = 0; kk < 2; ++kk) {
      bf16x8 af[MF], bfv[4];
#pragma unroll
      for (int m = 0; m < MF; ++m)
        af[m] = *reinterpret_cast<const bf16x8*>(
            &As[buf][(wr * (BM / 2) + m * 16 + lrow) * 64 + ((kk * 32 + lk * 8) ^ rswz)]);
#pragma unroll
      for (int n = 0; n < 4; ++n)
        bfv[n] = *reinterpret_cast<const bf16x8*>(
            &Bs[buf][(wc * 64 + n * 16 + lrow) * 64 + ((kk * 32 + lk * 8) ^ rswz)]);
#pragma unroll
      for (int m = 0; m < MF; ++m)
#pragma unroll
        for (int n = 0; n < 4; ++n)
          acc[m][n] = __builtin_amdgcn_mfma_f32_16x16x32_bf16(af[m], bfv[n], acc[m][n], 0, 0, 0);
    }
    __builtin_amdgcn_sched_barrier(0);
    __builtin_amdgcn_s_barrier();
    buf ^= 1;
  }
#undef GSTAGE
  if constexpr (BF16OUT) {
    __hip_bfloat16* Cz = (__hip_bfloat16*)Cv + (size_t)blockIdx.z * M * N;
#pragma unroll
    for (int m = 0; m < MF; ++m)
#pragma unroll
      for (int n = 0; n < 4; ++n)
#pragma unroll
        for (int r = 0; r < 4; ++r)
          Cz[(size_t)(m0 + wr * (BM / 2) + m * 16 + lk * 4 + r) * N + n0 + wc * 64 + n * 16 + lrow] =
              __float2bfloat16(acc[m][n][r]);
  } else {
    float* Cz = (float*)Cv + (size_t)blockIdx.z * M * N;
#pragma unroll
    for (int m = 0; m < MF; ++m)
#pragma unroll
      for (int n = 0; n < 4; ++n)
#pragma unroll
        for (int r = 0; r < 4; ++r)
          Cz[(size_t)(m0 + wr * (BM / 2) + m * 16 + lk * 4 + r) * N + n0 + wc * 64 + n * 16 + lrow] =
              acc[m][n][r];
  }
}

// -------- out = sum of 4 bf16 K-slice partials (fp32 accumulate) -------------
__global__ void add4(const __hip_bfloat16* __restrict__ P, float* __restrict__ out, int n) {
  const int i = (blockIdx.x * 256 + threadIdx.x) * 4;
  if (i < n) {
    float s[4] = {0.f, 0.f, 0.f, 0.f};
#pragma unroll
    for (int z = 0; z < 4; ++z) {
      const ushort4 v = *reinterpret_cast<const ushort4*>(P + (size_t)z * n + i);
      s[0] += __bfloat162float(__ushort_as_bfloat16(v.x));
      s[1] += __bfloat162float(__ushort_as_bfloat16(v.y));
      s[2] += __bfloat162float(__ushort_as_bfloat16(v.z));
      s[3] += __bfloat162float(__ushort_as_bfloat16(v.w));
    }
    *reinterpret_cast<float4*>(out + i) = make_float4(s[0], s[1], s[2], s[3]);
  }
}

// --- prep2: ba GEMM (0..511) + cast X (512..2559) + transpose (2560..8703) ---
__global__ __launch_bounds__(256) void prep2(const float* __restrict__ X,
                                             __hip_bfloat16* __restrict__ Xb,
                                             const float* __restrict__ Wq,
                                             __hip_bfloat16* __restrict__ Wqt,
                                             const float* __restrict__ Wba,
                                             float* __restrict__ P) {
  __shared__ __align__(16) float smem[64 * 65];  // 16.6 KB union
  const int bid = blockIdx.x;
  const int tid = threadIdx.x;
  if (bid < 512) {
    // split-K ba GEMM: X[1024,2048] @ Wba[2048,64] -> P[4][1024][64]
    float (*Xs)[256] = reinterpret_cast<float (*)[256]>(smem);
    const int tt = bid & 127, ks = bid >> 7;
    const int c = tid & 63, r4 = tid >> 6;
    float acc[2] = {};
#pragma unroll
    for (int h = 0; h < 2; ++h) {
      const float* xsrc = X + (size_t)(tt * 8) * 2048 + ks * 512 + h * 256;
#pragma unroll
      for (int u = 0; u < 2; ++u) {
        const int flat = (u * 256 + tid) * 4;
        const int r = flat >> 8, k = flat & 255;
        *reinterpret_cast<float4*>(&Xs[r][k]) =
            *reinterpret_cast<const float4*>(&xsrc[(size_t)r * 2048 + k]);
      }
      __syncthreads();
      const float* wp = Wba + (size_t)(ks * 512 + h * 256) * 64 + c;
      for (int k = 0; k < 256; k += 8) {
        float w[8];
#pragma unroll
        for (int u = 0; u < 8; ++u) w[u] = wp[(size_t)(k + u) * 64];
#pragma unroll
        for (int u = 0; u < 8; ++u)
#pragma unroll
          for (int i = 0; i < 2; ++i)
            acc[i] = fmaf(Xs[r4 * 2 + i][k + u], w[u], acc[i]);
      }
      __syncthreads();
    }
    float* pp = P + ((size_t)ks * 1024 + tt * 8 + r4 * 2) * 64 + c;
#pragma unroll
    for (int i = 0; i < 2; ++i) pp[(size_t)i * 64] = acc[i];
  } else if (bid < 2560) {
    const int i = ((bid - 512) * 256 + tid) * 4;
    const float4 v = *reinterpret_cast<const float4*>(X + i);
    ushort4 o;
    o.x = __bfloat16_as_ushort(__float2bfloat16(v.x));
    o.y = __bfloat16_as_ushort(__float2bfloat16(v.y));
    o.z = __bfloat16_as_ushort(__float2bfloat16(v.z));
    o.w = __bfloat16_as_ushort(__float2bfloat16(v.w));
    *reinterpret_cast<ushort4*>((void*)(Xb + i)) = o;
  } else {
    // transpose W_qkvz [2048, 12288] -> bf16 [12288, 2048], 64x64 tiles
    float (*tl)[65] = reinterpret_cast<float (*)[65]>(smem);
    const int b = bid - 2560;
    const int n0 = (b % 192) * 64, k0 = (b / 192) * 64;
    const int N = NQKVZ, K = 2048;
    const int rc = tid & 15, rr = tid >> 4;
#pragma unroll
    for (int i = 0; i < 4; ++i) {
      const int k = rr + 16 * i;
      const float4 v = *reinterpret_cast<const float4*>(&Wq[(size_t)(k0 + k) * N + n0 + rc * 4]);
      tl[k][rc * 4 + 0] = v.x;
      tl[k][rc * 4 + 1] = v.y;
      tl[k][rc * 4 + 2] = v.z;
      tl[k][rc * 4 + 3] = v.w;
    }
    __syncthreads();
    const int wcx = tid & 7, wry = tid >> 3;
#pragma unroll
    for (int i = 0; i < 2; ++i) {
      const int n = wry + 32 * i;
      uint u[8];
#pragma unroll
      for (int j = 0; j < 8; ++j)
        u[j] = __bfloat16_as_ushort(__float2bfloat16(tl[wcx * 8 + j][n]));
      uint4 o;
      o.x = u[0] | (u[1] << 16);
      o.y = u[2] | (u[3] << 16);
      o.z = u[4] | (u[5] << 16);
      o.w = u[6] | (u[7] << 16);
      *reinterpret_cast<uint4*>((void*)&Wqt[(size_t)(n0 + n) * K + k0 + wcx * 8]) = o;
    }
  }
}

// --- convs: conv_qk_norm (0..4095) + conv_v (4096..4607) + gb (4608..4735) ---
__global__ __launch_bounds__(256) void convs(const __hip_bfloat16* __restrict__ qkvz,
                                             const float* __restrict__ conv_w,
                                             float* __restrict__ QK,
                                             float* __restrict__ V,
                                             const float* __restrict__ P,
                                             const float* __restrict__ dt_bias,
                                             const float* __restrict__ A_log,
                                             float* __restrict__ gg,
                                             float* __restrict__ bet) {
  const int bid = blockIdx.x;
  const int tid = threadIdx.x;
  if (bid < 4096) {
    const int kh = bid & 15;
    const int t = (bid >> 4) * 4 + (tid >> 6);
    const int l = tid & 63;
    const int cols[4] = {kh * 768 + l, kh * 768 + l + 64,
                         kh * 768 + 128 + l, kh * 768 + 128 + l + 64};
    const int chs[4] = {kh * 128 + l, kh * 128 + l + 64,
                        2048 + kh * 128 + l, 2048 + kh * 128 + l + 64};
    float y[4];
#pragma unroll
    for (int j = 0; j < 4; ++j) {
      const float* wp = &conv_w[chs[j] * 4];
      float acc = 0.f;
#pragma unroll
      for (int s = 0; s < 4; ++s) {
        const int tt = t - 3 + s;
        if (tt >= 0)
          acc = fmaf(__bfloat162float(qkvz[(size_t)tt * NQKVZ + cols[j]]), wp[s], acc);
      }
      y[j] = acc / (1.f + expf(-acc));  // silu
    }
    float sq = y[0] * y[0] + y[1] * y[1];
    float sk = y[2] * y[2] + y[3] * y[3];
#pragma unroll
    for (int off = 32; off; off >>= 1) {
      sq += __shfl_xor(sq, off);
      sk += __shfl_xor(sk, off);
    }
    const float rq = rsqrtf(sq + 1e-6f) * 0.08838834764831845f;  // * DK^-0.5
    const float rk = rsqrtf(sk + 1e-6f);
    const size_t qb = (size_t)t * 4096 + kh * 128;
    QK[qb + l] = y[0] * rq;
    QK[qb + l + 64] = y[1] * rq;
    QK[qb + 2048 + l] = y[2] * rk;
    QK[qb + 2048 + l + 64] = y[3] * rk;
  } else if (bid < 4608) {
    const int b = bid - 4096;
    const int c2 = (b & 15) * 256 + tid;
    const int vh = c2 >> 7;
    const int col = (vh >> 1) * 768 + 256 + (vh & 1) * 128 + (c2 & 127);
    const int t0 = (b >> 4) * 32;
    const float4 w = *reinterpret_cast<const float4*>(&conv_w[(4096 + c2) * 4]);
    float x0, x1, x2;
    if (t0 == 0) {
      x0 = 0.f; x1 = 0.f; x2 = 0.f;
    } else {
      x0 = __bfloat162float(qkvz[(size_t)(t0 - 3) * NQKVZ + col]);
      x1 = __bfloat162float(qkvz[(size_t)(t0 - 2) * NQKVZ + col]);
      x2 = __bfloat162float(qkvz[(size_t)(t0 - 1) * NQKVZ + col]);
    }
#pragma unroll 4
    for (int tt = 0; tt < 32; ++tt) {
      const int t = t0 + tt;
      const float x3 = __bfloat162float(qkvz[(size_t)t * NQKVZ + col]);
      float acc = x0 * w.x;
      acc = fmaf(x1, w.y, acc);
      acc = fmaf(x2, w.z, acc);
      acc = fmaf(x3, w.w, acc);
      V[(size_t)t * 4096 + c2] = acc / (1.f + expf(-acc));
      x0 = x1; x1 = x2; x2 = x3;
    }
  } else {
    const int idx = (bid - 4608) * 256 + tid;  // t*32 + vh
    const int t = idx >> 5, vh = idx & 31;
    const int cb = (vh >> 1) * 4 + (vh & 1);
    float b = 0.f, a = 0.f;
#pragma unroll
    for (int s = 0; s < 4; ++s) {
      b += P[((size_t)s * 1024 + t) * 64 + cb];
      a += P[((size_t)s * 1024 + t) * 64 + cb + 2];
    }
    const float x = a + dt_bias[vh];
    const float sp = (x > 20.f) ? x : log1pf(expf(x));
    gg[idx] = -expf(A_log[vh]) * sp;
    bet[idx] = 1.f / (1.f + expf(-b));
  }
}

// ---------------- phase 1: per (chunk, v-head) intra-chunk precompute --------
__global__ __launch_bounds__(256, 2) void phase1(
    const float* __restrict__ QK, const float* __restrict__ V,
    const float* __restrict__ g, const float* __restrict__ bet,
    __hip_bfloat16* __restrict__ Ub, __hip_bfloat16* __restrict__ Wb,
    __hip_bfloat16* __restrict__ KTb, __hip_bfloat16* __restrict__ Qgb,
    __hip_bfloat16* __restrict__ Bb, float* __restrict__ gend) {
  const int vh = blockIdx.x, ch = blockIdx.y, kh = vh >> 1;
  const int tid = threadIdx.x;
  const int t0 = ch * CHUNK;
  __shared__ __align__(16) __hip_bfloat16 KbS[64][128];
  __shared__ __align__(16) __hip_bfloat16 QbS[64][128];
  __shared__ __align__(16) float Al[64][68];
  __shared__ float bs[64], gams[64], bets[64], lams[64];

  const int row = tid >> 2;
  const size_t hb = (size_t)ch * 32 + vh;
  {
    const int cc = (tid & 3) * 32;
    const float* ksrc = &QK[(size_t)(t0 + row) * 4096 + 2048 + kh * 128 + cc];
    const float* qsrc = &QK[(size_t)(t0 + row) * 4096 + kh * 128 + cc];
#pragma unroll
    for (int u = 0; u < 32; u += 4) {
      const float4 kv = *reinterpret_cast<const float4*>(ksrc + u);
      const float4 qv = *reinterpret_cast<const float4*>(qsrc + u);
      const int d0 = cc + u;
      const int sidx = (d0 & 7) | ((((d0 >> 3) ^ (row & 7)) & 15) << 3);
      ushort4 kk4, qq4;
      kk4.x = __bfloat16_as_ushort(__float2bfloat16(kv.x));
      kk4.y = __bfloat16_as_ushort(__float2bfloat16(kv.y));
      kk4.z = __bfloat16_as_ushort(__float2bfloat16(kv.z));
      kk4.w = __bfloat16_as_ushort(__float2bfloat16(kv.w));
      qq4.x = __bfloat16_as_ushort(__float2bfloat16(qv.x));
      qq4.y = __bfloat16_as_ushort(__float2bfloat16(qv.y));
      qq4.z = __bfloat16_as_ushort(__float2bfloat16(qv.z));
      qq4.w = __bfloat16_as_ushort(__float2bfloat16(qv.w));
      *reinterpret_cast<ushort4*>(&KbS[row][sidx]) = kk4;
      *reinterpret_cast<ushort4*>(&QbS[row][sidx]) = qq4;
    }
  }
  if (tid < 64) {
    float b = g[(size_t)(t0 + tid) * 32 + vh];
#pragma unroll
    for (int off = 1; off < 64; off <<= 1) {
      const float o = __shfl_up(b, off);
      if (tid >= off) b += o;
    }
    const float b63 = __shfl(b, 63);
    const float ga = expf(b);
    bs[tid] = b;
    gams[tid] = ga;
    lams[tid] = expf(b63 - b);
    bets[tid] = bet[(size_t)(t0 + tid) * 32 + vh];
    if (tid == 63) gend[ch * 32 + vh] = ga;
  }
  __syncthreads();
  {
    const int i = tid & 63;
    const float li = lams[i];
    __hip_bfloat16* kt = &KTb[hb * 128 * 64];
    const int dbase = (tid >> 6) * 32;
#pragma unroll
    for (int dd = 0; dd < 32; ++dd) {
      const int d = dbase + dd;
      const int sidx = (d & 7) | ((((d >> 3) ^ (i & 7)) & 15) << 3);
      kt[(size_t)d * 64 + (i ^ ((d & 7) << 3))] =
          __float2bfloat16(li * __bfloat162float(KbS[i][sidx]));
    }
  }
  {
    const float gai = gams[row];
    __hip_bfloat16* qg = &Qgb[(hb * 64 + row) * 128];
    const int cc = (tid & 3) * 32;
#pragma unroll
    for (int u = 0; u < 32; u += 4) {
      const int d0 = cc + u;
      const int sidx = (d0 & 7) | ((((d0 >> 3) ^ (row & 7)) & 15) << 3);
      ushort4 qq;
      qq.x = __bfloat16_as_ushort(__float2bfloat16(gai * __bfloat162float(QbS[row][sidx + 0])));
      qq.y = __bfloat16_as_ushort(__float2bfloat16(gai * __bfloat162float(QbS[row][sidx + 1])));
      qq.z = __bfloat16_as_ushort(__float2bfloat16(gai * __bfloat162float(QbS[row][sidx + 2])));
      qq.w = __bfloat16_as_ushort(__float2bfloat16(gai * __bfloat162float(QbS[row][sidx + 3])));
      *reinterpret_cast<ushort4*>(&qg[d0 ^ ((row & 7) << 3)]) = qq;
    }
  }
  {
    const int w = tid >> 6, lane = tid & 63;
    const int lrow = lane & 15, lk = lane >> 4;
    bf16x8 af[4], qf[4];
#pragma unroll
    for (int kk = 0; kk < 4; ++kk) {
      const int c = ((kk * 4 + lk) ^ (lrow & 7)) * 8;
      af[kk] = *reinterpret_cast<const bf16x8*>(&KbS[w * 16 + lrow][c]);
      qf[kk] = *reinterpret_cast<const bf16x8*>(&QbS[w * 16 + lrow][c]);
    }
#pragma unroll
    for (int n = 0; n < 4; ++n) {
      f32x4 aA = {}, aB = {};
#pragma unroll
      for (int kk = 0; kk < 4; ++kk) {
        const bf16x8 bf = *reinterpret_cast<const bf16x8*>(
            &KbS[n * 16 + lrow][((kk * 4 + lk) ^ (lrow & 7)) * 8]);
        aA = __builtin_amdgcn_mfma_f32_16x16x32_bf16(af[kk], bf, aA, 0, 0, 0);
        aB = __builtin_amdgcn_mfma_f32_16x16x32_bf16(qf[kk], bf, aB, 0, 0, 0);
      }
      __hip_bfloat16* Bout = &Bb[hb * 64 * 64];
#pragma unroll
      for (int r = 0; r < 4; ++r) {
        const int i = w * 16 + lk * 4 + r;
        const int j = n * 16 + lrow;
        const float dec = expf(bs[i] - bs[j]);
        Al[i][j] = (j < i) ? bets[i] * dec * aA[r] : 0.f;
        Bout[(size_t)i * 64 + (j ^ ((i & 7) << 3))] =
            __float2bfloat16((j <= i) ? dec * aB[r] : 0.f);
      }
    }
  }
  __syncthreads();
  {
    const int cc = tid;
    float x[64];
    const bool isV = cc < 128;
    const float* src = isV ? &V[(size_t)t0 * 4096 + vh * 128 + cc]
                           : &QK[(size_t)t0 * 4096 + 2048 + kh * 128 + (cc - 128)];
#pragma unroll
    for (int i = 0; i < 64; ++i) {
      const float sc = isV ? bets[i] : bets[i] * gams[i];
      x[i] = sc * src[(size_t)i * 4096];
    }
#pragma unroll
    for (int i = 1; i < 64; ++i) {
      float s0 = 0.f, s1 = 0.f, s2 = 0.f, s3 = 0.f;
      int j = 0;
#pragma unroll
      for (; j + 4 <= i; j += 4) {
        const float4 a = *reinterpret_cast<const float4*>(&Al[i][j]);
        s0 = fmaf(a.x, x[j], s0);
        s1 = fmaf(a.y, x[j + 1], s1);
        s2 = fmaf(a.z, x[j + 2], s2);
        s3 = fmaf(a.w, x[j + 3], s3);
      }
#pragma unroll
      for (; j < i; ++j) s0 = fmaf(Al[i][j], x[j], s0);
      x[i] -= (s0 + s1) + (s2 + s3);
    }
    if (isV) {
      __hip_bfloat16* dst = &Ub[hb * 64 * 128 + cc];
#pragma unroll
      for (int i = 0; i < 64; ++i) dst[(size_t)i * 128] = __float2bfloat16(x[i]);
    } else {
      const int d = cc - 128;
      __hip_bfloat16* dst = &Wb[hb * 64 * 128];
#pragma unroll
      for (int i = 0; i < 64; ++i)
        dst[(size_t)i * 128 + (d ^ ((i & 7) << 3))] = __float2bfloat16(-x[i]);
    }
  }
}

// ---------------- phaseB: serial MFMA state propagation ----------------------
__global__ __launch_bounds__(128) void phaseB(
    const __hip_bfloat16* __restrict__ Ug, const __hip_bfloat16* __restrict__ Wb,
    const __hip_bfloat16* __restrict__ KTb, const __hip_bfloat16* __restrict__ Qgb,
    const __hip_bfloat16* __restrict__ Bb, const float* __restrict__ gendg,
    float* __restrict__ Og) {
  const int vh = blockIdx.x, slice = blockIdx.y;
  const int tid = threadIdx.x, lane = tid & 63, w = tid >> 6;
  const int l15 = lane & 15, l4 = lane >> 4;
  const int cg = slice * 32 + w * 16;
  const int swz = (l15 & 7) << 3;

  __shared__ __hip_bfloat16 Wl[2][8192];
  __shared__ __hip_bfloat16 KTl[2][8192];
  __shared__ __hip_bfloat16 Qgl[2][8192];
  __shared__ __hip_bfloat16 Bl[2][4096];
  __shared__ __hip_bfloat16 Sop[2][2048];
  __shared__ __hip_bfloat16 dLs[2][1024];

  f32x4 accS[8] = {};
  for (int x = lane; x < 1024; x += 64) reinterpret_cast<uint*>(Sop[w])[x] = 0;

  float ubuf[4][4];
#define STAGE(b_, c_) do {                                                      \
    const size_t hb_ = ((size_t)(c_) * 32 + vh);                                \
    _Pragma("unroll") for (int it = 0; it < 8; ++it) {                          \
      __builtin_amdgcn_global_load_lds(                                         \
          (const __attribute__((address_space(1))) void*)(Wb + hb_ * 8192 + it * 1024 + tid * 8), \
          (__attribute__((address_space(3))) void*)(&Wl[b_][it * 1024 + tid * 8]), 16, 0, 0); \
      __builtin_amdgcn_global_load_lds(                                         \
          (const __attribute__((address_space(1))) void*)(KTb + hb_ * 8192 + it * 1024 + tid * 8), \
          (__attribute__((address_space(3))) void*)(&KTl[b_][it * 1024 + tid * 8]), 16, 0, 0); \
      __builtin_amdgcn_global_load_lds(                                         \
          (const __attribute__((address_space(1))) void*)(Qgb + hb_ * 8192 + it * 1024 + tid * 8), \
          (__attribute__((address_space(3))) void*)(&Qgl[b_][it * 1024 + tid * 8]), 16, 0, 0); \
      if (it < 4)                                                               \
        __builtin_amdgcn_global_load_lds(                                       \
            (const __attribute__((address_space(1))) void*)(Bb + hb_ * 4096 + it * 1024 + tid * 8), \
            (__attribute__((address_space(3))) void*)(&Bl[b_][it * 1024 + tid * 8]), 16, 0, 0); \
    }                                                                           \
  } while (0)
#define UPREF(c_) do {                                                          \
    const __hip_bfloat16* up_ = Ug + ((size_t)(c_) * 32 + vh) * 64 * 128 + cg + l15; \
    _Pragma("unroll") for (int m_ = 0; m_ < 4; ++m_)                            \
      _Pragma("unroll") for (int r_ = 0; r_ < 4; ++r_)                          \
        ubuf[m_][r_] = __bfloat162float(up_[(size_t)(m_ * 16 + l4 * 4 + r_) * 128]); \
  } while (0)

  STAGE(0, 0);
  UPREF(0);
  __syncthreads();
  int buf = 0;
  for (int ch = 0; ch < NCHUNK; ++ch) {
    if (ch + 1 < NCHUNK) STAGE(buf ^ 1, ch + 1);
    f32x4 acc_d[4];
#pragma unroll
    for (int m = 0; m < 4; ++m) {
      f32x4 t;
      t[0] = ubuf[m][0]; t[1] = ubuf[m][1]; t[2] = ubuf[m][2]; t[3] = ubuf[m][3];
      acc_d[m] = t;
    }
    if (ch + 1 < NCHUNK) UPREF(ch + 1);
    // op1: delta = U + (-W) @ S
#pragma unroll
    for (int t = 0; t < 4; ++t) {
      const bf16x8 bS = *reinterpret_cast<const bf16x8*>(
          &Sop[w][l15 * 128 + ((t * 32 + l4 * 8) ^ swz)]);
#pragma unroll
      for (int m = 0; m < 4; ++m) {
        const bf16x8 aW = *reinterpret_cast<const bf16x8*>(
            &Wl[buf][(m * 16 + l15) * 128 + ((t * 32 + l4 * 8) ^ swz)]);
        acc_d[m] = __builtin_amdgcn_mfma_f32_16x16x32_bf16(aW, bS, acc_d[m], 0, 0, 0);
      }
    }
#pragma unroll
    for (int m = 0; m < 4; ++m)
      *reinterpret_cast<ushort4*>(&dLs[w][l15 * 64 + ((m * 16 + l4 * 4) ^ swz)]) =
          pack4(acc_d[m]);
    // opO: o = γq @ S + B @ δ
    f32x4 acc_o[4] = {};
#pragma unroll
    for (int t = 0; t < 4; ++t) {
      const bf16x8 bS = *reinterpret_cast<const bf16x8*>(
          &Sop[w][l15 * 128 + ((t * 32 + l4 * 8) ^ swz)]);
#pragma unroll
      for (int m = 0; m < 4; ++m) {
        const bf16x8 aQ = *reinterpret_cast<const bf16x8*>(
            &Qgl[buf][(m * 16 + l15) * 128 + ((t * 32 + l4 * 8) ^ swz)]);
        acc_o[m] = __builtin_amdgcn_mfma_f32_16x16x32_bf16(aQ, bS, acc_o[m], 0, 0, 0);
      }
    }
#pragma unroll
    for (int t2 = 0; t2 < 2; ++t2) {
      const bf16x8 bD = *reinterpret_cast<const bf16x8*>(
          &dLs[w][l15 * 64 + ((t2 * 32 + l4 * 8) ^ swz)]);
#pragma unroll
      for (int m = 0; m < 4; ++m) {
        const bf16x8 aB = *reinterpret_cast<const bf16x8*>(
            &Bl[buf][(m * 16 + l15) * 64 + ((t2 * 32 + l4 * 8) ^ swz)]);
        acc_o[m] = __builtin_amdgcn_mfma_f32_16x16x32_bf16(aB, bD, acc_o[m], 0, 0, 0);
      }
    }
    float* ob = Og + (size_t)(ch * 64) * 4096 + (size_t)vh * 128 + cg + l15;
#pragma unroll
    for (int m = 0; m < 4; ++m)
#pragma unroll
      for (int r = 0; r < 4; ++r)
        ob[(size_t)(m * 16 + l4 * 4 + r) * 4096] = acc_o[m][r];
    // op3: S = ge*S + Kᵀλ @ δ
    const float ge = gendg[ch * 32 + vh];
#pragma unroll
    for (int f = 0; f < 8; ++f) {
      accS[f][0] *= ge; accS[f][1] *= ge; accS[f][2] *= ge; accS[f][3] *= ge;
    }
#pragma unroll
    for (int t2 = 0; t2 < 2; ++t2) {
      const bf16x8 bD = *reinterpret_cast<const bf16x8*>(
          &dLs[w][l15 * 64 + ((t2 * 32 + l4 * 8) ^ swz)]);
#pragma unroll
      for (int f = 0; f < 8; ++f) {
        const bf16x8 aK = *reinterpret_cast<const bf16x8*>(
            &KTl[buf][(f * 16 + l15) * 64 + ((t2 * 32 + l4 * 8) ^ swz)]);
        accS[f] = __builtin_amdgcn_mfma_f32_16x16x32_bf16(aK, bD, accS[f], 0, 0, 0);
      }
    }
#pragma unroll
    for (int f = 0; f < 8; ++f)
      *reinterpret_cast<ushort4*>(&Sop[w][l15 * 128 + ((f * 16 + l4 * 4) ^ swz)]) =
          pack4(accS[f]);
    __syncthreads();
    buf ^= 1;
  }
#undef STAGE
#undef UPREF
}

// --- gfuse: gate_norm (0..8191) + transpose W_out (8192..10239) --------------
__global__ __launch_bounds__(256) void gfuse(const float* __restrict__ O,
                                             const __hip_bfloat16* __restrict__ qkvz,
                                             const float* __restrict__ norm_w,
                                             __hip_bfloat16* __restrict__ G,
                                             const float* __restrict__ Wo,
                                             __hip_bfloat16* __restrict__ Wot) {
  __shared__ float tl[64][65];
  const int bid = blockIdx.x;
  const int tid = threadIdx.x;
  if (bid < 8192) {
    const int vh = (bid & 7) * 4 + (tid >> 6);
    const int t = bid >> 3, l = tid & 63;
    const size_t ob = (size_t)t * 4096 + vh * 128;
    const size_t zb = (size_t)t * NQKVZ + (vh >> 1) * 768 + 512 + (vh & 1) * 128;
    const float o0 = O[ob + l], o1 = O[ob + l + 64];
    const float z0 = __bfloat162float(qkvz[zb + l]);
    const float z1 = __bfloat162float(qkvz[zb + l + 64]);
    const float g0 = o0 * z0 / (1.f + expf(-z0));
    const float g1 = o1 * z1 / (1.f + expf(-z1));
    float ss = g0 * g0 + g1 * g1;
#pragma unroll
    for (int off = 32; off; off >>= 1) ss += __shfl_xor(ss, off);
    const float rr = rsqrtf(ss * (1.f / 128.f) + 1e-6f);
    G[ob + l] = __float2bfloat16(g0 * rr * norm_w[l]);
    G[ob + l + 64] = __float2bfloat16(g1 * rr * norm_w[l + 64]);
    return;
  }
  const int b = bid - 8192;
  const int n0 = (b & 31) * 64, k0 = (b >> 5) * 64;
  const int N = 2048, K = 4096;
  const int rc = tid & 15, rr2 = tid >> 4;
#pragma unroll
  for (int i = 0; i < 4; ++i) {
    const int k = rr2 + 16 * i;
    const float4 v = *reinterpret_cast<const float4*>(&Wo[(size_t)(k0 + k) * N + n0 + rc * 4]);
    tl[k][rc * 4 + 0] = v.x;
    tl[k][rc * 4 + 1] = v.y;
    tl[k][rc * 4 + 2] = v.z;
    tl[k][rc * 4 + 3] = v.w;
  }
  __syncthreads();
  const int wcx = tid & 7, wry = tid >> 3;
#pragma unroll
  for (int i = 0; i < 2; ++i) {
    const int n = wry + 32 * i;
    uint u[8];
#pragma unroll
    for (int j = 0; j < 8; ++j)
      u[j] = __bfloat16_as_ushort(__float2bfloat16(tl[wcx * 8 + j][n]));
    uint4 o;
    o.x = u[0] | (u[1] << 16);
    o.y = u[2] | (u[3] << 16);
    o.z = u[4] | (u[5] << 16);
    o.w = u[6] | (u[7] << 16);
    *reinterpret_cast<uint4*>((void*)&Wot[(size_t)(n0 + n) * K + k0 + wcx * 8]) = o;
  }
}

extern "C" void kernel_launch(void* const* d_in, const int* in_sizes, int n_in,
                              void* d_out, int out_size, void* d_ws, size_t ws_size,
                              hipStream_t stream) {
  const float* X = (const float*)d_in[0];
  const float* W_qkvz = (const float*)d_in[1];
  const float* W_ba = (const float*)d_in[2];
  const float* conv_w = (const float*)d_in[3];
  const float* dt_bias = (const float*)d_in[4];
  const float* A_log = (const float*)d_in[5];
  const float* norm_w = (const float*)d_in[6];
  const float* W_out = (const float*)d_in[7];
  float* out = (float*)d_out;

  float* ws = (float*)d_ws;
  float* qkvz = ws;                                // region sized 12,582,912 f (used as bf16)
  float* P = qkvz + (size_t)T_LEN * NQKVZ;         //    262,144 f (ba partials)
  float* QK = P + 262144;                          //  4,194,304 f
  float* V = QK + (size_t)T_LEN * 4096;            //  4,194,304 f
  float* U_f = V + (size_t)T_LEN * 4096;           //  4,194,304 f (bf16 U uses half)
  float* Wb_f = U_f + (size_t)NCHUNK * 32 * 64 * 128; // 2,097,152 f
  float* KT_f = Wb_f + 2097152;                    //  2,097,152 f
  float* Qg_f = KT_f + 2097152;                    //  2,097,152 f
  float* Bb_f = Qg_f + 2097152;                    //  1,048,576 f (bf16 x 2.10M)
  float* gg = Bb_f + 1048576;                      //     32,768 f
  float* bet = gg + 32768;                         //     32,768 f
  float* gend = bet + 32768;                       //        512 f

  __hip_bfloat16* qkvzb = (__hip_bfloat16*)qkvz;   // bf16 qkvz
  __hip_bfloat16* Ub = (__hip_bfloat16*)U_f;
  __hip_bfloat16* Wb = (__hip_bfloat16*)Wb_f;
  __hip_bfloat16* KTb = (__hip_bfloat16*)KT_f;
  __hip_bfloat16* Qgb = (__hip_bfloat16*)Qg_f;
  __hip_bfloat16* Bb = (__hip_bfloat16*)Bb_f;
  // lifetime aliases:
  __hip_bfloat16* Wqkvz_t = (__hip_bfloat16*)V;    // spans V+U+Wb+KT (dead after 1st gemm)
  __hip_bfloat16* Xb = (__hip_bfloat16*)Qg_f;      // dead after 1st gemm
  __hip_bfloat16* Gb = (__hip_bfloat16*)Bb_f;      // Bb dead after phaseB
  __hip_bfloat16* Wout_t = (__hip_bfloat16*)qkvz;  // qkvz dead after gfuse's gate part
  float* O = V;                                    // V dead after phase1
  __hip_bfloat16* Pout = (__hip_bfloat16*)U_f;     // U+Wb+KT dead after phaseB

  prep2<<<dim3(512 + 2048 + 6144), 256, 0, stream>>>(X, Xb, W_qkvz, Wqkvz_t, W_ba, P);
  gemm256<<<dim3(NQKVZ / 192, T_LEN / 256), 512, 0, stream>>>(
      Xb, Wqkvz_t, qkvzb, T_LEN, NQKVZ, 2048);
  convs<<<dim3(4096 + 512 + 128), 256, 0, stream>>>(qkvzb, conv_w, QK, V, P,
                                                    dt_bias, A_log, gg, bet);
  phase1<<<dim3(HV_N, NCHUNK), 256, 0, stream>>>(QK, V, gg, bet, Ub, Wb, KTb, Qgb, Bb, gend);
  phaseB<<<dim3(HV_N, 4), 128, 0, stream>>>(Ub, Wb, KTb, Qgb, Bb, gend, O);
  gfuse<<<dim3(8192 + 2048), 256, 0, stream>>>(O, qkvzb, norm_w, Gb, W_out, Wout_t);
  gemm_bf16<128, true><<<dim3(2048 / 128, T_LEN / 128, 4), 256, 0, stream>>>(
      Gb, Wout_t, Pout, T_LEN, 2048, 1024, 4096);
  add4<<<dim3(T_LEN * 2048 / 4 / 256), 256, 0, stream>>>(Pout, out, T_LEN * 2048);
}